// Round 9
// baseline (320.279 us; speedup 1.0000x reference)
//
#include <hip/hip_runtime.h>

typedef __attribute__((ext_vector_type(8))) short short8;
typedef __attribute__((ext_vector_type(4))) float f32x4;

#define DIMD 512
#define EE 1024
#define SSS 128
#define LLL 4096
#define NROW 16384   // B*L
#define NUV 2176     // 2E+S

__device__ __forceinline__ short f2bf(float f) {
  union { float f; unsigned u; } un; un.f = f;
  unsigned r = un.u + 0x7FFFu + ((un.u >> 16) & 1u);
  return (short)(r >> 16);
}
__device__ __forceinline__ float bf2f(short s) {
  union { unsigned u; float f; } un;
  un.u = ((unsigned)(unsigned short)s) << 16;
  return un.f;
}
__device__ __forceinline__ float silu_f(float x) {
  return x / (1.0f + __expf(-x));
}

__device__ __forceinline__ void gld16(const short* g, short* l) {
  __builtin_amdgcn_global_load_lds(
      (const __attribute__((address_space(1))) unsigned int*)g,
      (__attribute__((address_space(3))) unsigned int*)l, 16, 0, 0);
}

#define MFMA16(a, b, c) c = __builtin_amdgcn_mfma_f32_16x16x32_bf16(a, b, c, 0, 0, 0)
#define SBAR() asm volatile("s_barrier" ::: "memory")
#define VMCNT(n) asm volatile("s_waitcnt vmcnt(" #n ")" ::: "memory")
#define LGKM0() asm volatile("s_waitcnt lgkmcnt(0)" ::: "memory")

// ---------------- prep: transpose+cast weights to bf16 ----------------
__global__ void prep_kernel(const float* __restrict__ W_uv, const float* __restrict__ W_out,
                            short* __restrict__ W_uvT, short* __restrict__ W_outT) {
  int i = blockIdx.x * blockDim.x + threadIdx.x;
  if (i < NUV * DIMD) {
    int c = i >> 9, d = i & (DIMD - 1);
    W_uvT[i] = f2bf(W_uv[(size_t)d * NUV + c]);
  }
  if (i < DIMD * EE) {
    int d = i >> 10, e = i & (EE - 1);
    W_outT[i] = f2bf(W_out[(size_t)e * DIMD + d]);
  }
}

// ---------------- layernorm -> xn bf16 ----------------
__global__ __launch_bounds__(256) void ln_kernel(const float* __restrict__ x,
    const float* __restrict__ w, const float* __restrict__ bb, short* __restrict__ xn) {
  int row = blockIdx.x;
  int tid = threadIdx.x;
  const float2* xr = (const float2*)(x + (size_t)row * DIMD);
  float2 v = xr[tid];
  float s = v.x + v.y, ss = v.x * v.x + v.y * v.y;
  #pragma unroll
  for (int off = 32; off >= 1; off >>= 1) {
    s += __shfl_down(s, off);
    ss += __shfl_down(ss, off);
  }
  __shared__ float ps[8];
  if ((tid & 63) == 0) { ps[tid >> 6] = s; ps[4 + (tid >> 6)] = ss; }
  __syncthreads();
  s = ps[0] + ps[1] + ps[2] + ps[3];
  ss = ps[4] + ps[5] + ps[6] + ps[7];
  float mu = s * (1.0f / DIMD);
  float var = ss * (1.0f / DIMD) - mu * mu;
  float inv = rsqrtf(var + 1e-5f);
  float2 wv = ((const float2*)w)[tid];
  float2 bv = ((const float2*)bb)[tid];
  short2 o;
  o.x = f2bf((v.x - mu) * inv * wv.x + bv.x);
  o.y = f2bf((v.y - mu) * inv * wv.y + bv.y);
  *(short2*)&xn[(size_t)row * DIMD + tid * 2] = o;
}

// ---------------- m97-style GEMM core: 128x128 tile, 4 waves, BK=32 ----------------
__device__ __forceinline__ void gemm_core(const short* __restrict__ A, const short* __restrict__ B,
                                          int lda, int ldb, int K, size_t m0, size_t n0,
                                          int tid, short* sm, f32x4 acc[4][4]) {
  short* As = sm;
  short* Bs = sm + 4096;
  int wid = tid >> 6, lane = tid & 63;
  int wr = (wid >> 1) * 64, wc = (wid & 1) * 64;
  int lr = lane & 15, lk = (lane >> 4) * 8;
  int r0 = tid >> 2, c0 = (tid & 3) * 8;
  #pragma unroll
  for (int m = 0; m < 4; m++)
    #pragma unroll
    for (int n = 0; n < 4; n++) acc[m][n] = (f32x4){0.f, 0.f, 0.f, 0.f};
  for (int k0 = 0; k0 < K; k0 += 32) {
    gld16(&A[(m0 + r0) * lda + k0 + c0],      &As[wid * 512]);
    gld16(&A[(m0 + 64 + r0) * lda + k0 + c0], &As[2048 + wid * 512]);
    gld16(&B[(n0 + r0) * ldb + k0 + c0],      &Bs[wid * 512]);
    gld16(&B[(n0 + 64 + r0) * ldb + k0 + c0], &Bs[2048 + wid * 512]);
    __syncthreads();
    short8 af[4], bf[4];
    #pragma unroll
    for (int m = 0; m < 4; m++) af[m] = *(short8*)&As[(wr + m * 16 + lr) * 32 + lk];
    #pragma unroll
    for (int n = 0; n < 4; n++) bf[n] = *(short8*)&Bs[(wc + n * 16 + lr) * 32 + lk];
    #pragma unroll
    for (int m = 0; m < 4; m++)
      #pragma unroll
      for (int n = 0; n < 4; n++)
        MFMA16(af[m], bf[n], acc[m][n]);
    __syncthreads();
  }
}

// ============ 256x256 8-phase pipelined GEMM core v1 (proven R6) ============
template<int LD, int T>
__device__ __forceinline__ void core8(const short* __restrict__ A, const short* __restrict__ Bv,
                                      size_t m0, size_t n0, int tid, short* sm,
                                      f32x4 (&acc)[8][4]) {
  const int w = tid >> 6, l = tid & 63;
  const int lr = l & 15;
  const int colsrc = ((l & 7) * 8) ^ ((l >> 3) << 3);
  const short* srcA = A  + (m0 + w * 8 + (l >> 3)) * (size_t)LD + colsrc;
  const short* srcB = Bv + (n0 + w * 8 + (l >> 3)) * (size_t)LD + colsrc;
  const int csw0 = ((l >> 4) * 8) ^ ((l & 7) << 3);
  const int csw1 = (32 + (l >> 4) * 8) ^ ((l & 7) << 3);
  const int AhalfOff = (w >> 2) * 8192 + lr * 64;
  const int BhalfOff = 16384 + ((w & 3) >> 1) * 8192 + ((w & 1) * 64 + lr) * 64;

  #define STA8(bf_, h_, q_, kt_) gld16(srcA + ((h_) * 128 + (q_) * 64) * (size_t)LD + (kt_) * 64, \
                                       &sm[(bf_) * 32768 + (h_) * 8192 + (q_) * 4096 + w * 512])
  #define STB8(bf_, h_, q_, kt_) gld16(srcB + ((h_) * 128 + (q_) * 64) * (size_t)LD + (kt_) * 64, \
                                       &sm[(bf_) * 32768 + 16384 + (h_) * 8192 + (q_) * 4096 + w * 512])

  #pragma unroll
  for (int m = 0; m < 8; m++)
    #pragma unroll
    for (int n = 0; n < 4; n++) acc[m][n] = (f32x4){0.f, 0.f, 0.f, 0.f};
  short8 Af[4][2], Bf0[2][2], Bf1[2][2];

  STA8(0, 0, 0, 0); STA8(0, 1, 0, 0);
  STA8(0, 0, 1, 0); STA8(0, 1, 1, 0);
  STB8(0, 0, 0, 0); STB8(0, 1, 0, 0);
  STB8(0, 0, 1, 0); STB8(0, 1, 1, 0);
  STA8(1, 0, 0, 1); STA8(1, 1, 0, 1);
  STA8(1, 0, 1, 1); STA8(1, 1, 1, 1);
  VMCNT(6);
  SBAR();
  __builtin_amdgcn_sched_barrier(0);

  for (int t = 0; t < T; ++t) {
    const int buf = t & 1, nb = buf ^ 1;
    short* Ab = sm + buf * 32768 + AhalfOff;
    short* Bb = sm + buf * 32768 + BhalfOff;
    if (t + 1 < T) { STB8(nb, 0, 0, t + 1); STB8(nb, 1, 0, t + 1); }
    #pragma unroll
    for (int i = 0; i < 4; ++i) {
      Af[i][0] = *(const short8*)&Ab[i * 1024 + csw0];
      Af[i][1] = *(const short8*)&Ab[i * 1024 + csw1];
    }
    #pragma unroll
    for (int j = 0; j < 2; ++j) {
      Bf0[j][0] = *(const short8*)&Bb[j * 1024 + csw0];
      Bf0[j][1] = *(const short8*)&Bb[j * 1024 + csw1];
    }
    SBAR();
    __builtin_amdgcn_s_setprio(1);
    #pragma unroll
    for (int i = 0; i < 4; ++i)
      #pragma unroll
      for (int j = 0; j < 2; ++j) {
        MFMA16(Af[i][0], Bf0[j][0], acc[i][j]);
        MFMA16(Af[i][1], Bf0[j][1], acc[i][j]);
      }
    __builtin_amdgcn_s_setprio(0);
    if (t + 1 < T) { VMCNT(6); } else { VMCNT(0); }
    SBAR();
    if (t + 1 < T) { STB8(nb, 0, 1, t + 1); STB8(nb, 1, 1, t + 1); }
    #pragma unroll
    for (int j = 0; j < 2; ++j) {
      Bf1[j][0] = *(const short8*)&Bb[2048 + j * 1024 + csw0];
      Bf1[j][1] = *(const short8*)&Bb[2048 + j * 1024 + csw1];
    }
    SBAR();
    __builtin_amdgcn_s_setprio(1);
    #pragma unroll
    for (int i = 0; i < 4; ++i)
      #pragma unroll
      for (int j = 0; j < 2; ++j) {
        MFMA16(Af[i][0], Bf1[j][0], acc[i][2 + j]);
        MFMA16(Af[i][1], Bf1[j][1], acc[i][2 + j]);
      }
    __builtin_amdgcn_s_setprio(0);
    SBAR();
    #pragma unroll
    for (int i = 0; i < 4; ++i) {
      Af[i][0] = *(const short8*)&Ab[4096 + i * 1024 + csw0];
      Af[i][1] = *(const short8*)&Ab[4096 + i * 1024 + csw1];
    }
    SBAR();
    __builtin_amdgcn_s_setprio(1);
    #pragma unroll
    for (int i = 0; i < 4; ++i)
      #pragma unroll
      for (int j = 0; j < 2; ++j) {
        MFMA16(Af[i][0], Bf1[j][0], acc[4 + i][2 + j]);
        MFMA16(Af[i][1], Bf1[j][1], acc[4 + i][2 + j]);
      }
    __builtin_amdgcn_s_setprio(0);
    SBAR();
    if (t + 2 < T) { STA8(buf, 0, 0, t + 2); STA8(buf, 1, 0, t + 2);
                     STA8(buf, 0, 1, t + 2); STA8(buf, 1, 1, t + 2); }
    __builtin_amdgcn_s_setprio(1);
    #pragma unroll
    for (int i = 0; i < 4; ++i)
      #pragma unroll
      for (int j = 0; j < 2; ++j) {
        MFMA16(Af[i][0], Bf0[j][0], acc[4 + i][j]);
        MFMA16(Af[i][1], Bf0[j][1], acc[4 + i][j]);
      }
    __builtin_amdgcn_s_setprio(0);
    if (t + 2 < T) { VMCNT(6); } else if (t + 1 < T) { VMCNT(2); } else { VMCNT(0); }
    SBAR();
    __builtin_amdgcn_sched_barrier(0);
  }
  #undef STA8
  #undef STB8
}

// ---------------- GEMM1 main (cols 0..2047): 8-phase 256x256 ----------------
__global__ __launch_bounds__(512, 2) void guv8_kernel(
    const short* __restrict__ xn, const short* __restrict__ W_uvT,
    const float* __restrict__ b_uv,
    short* __restrict__ u_out, short* __restrict__ vT_out)
{
  extern __shared__ __align__(16) short sm[];
  const size_t m0 = (size_t)blockIdx.x * 256;
  const size_t n0 = (size_t)blockIdx.y * 256;
  const int tid = threadIdx.x, w = tid >> 6, l = tid & 63;
  const int lr = l & 15;
  f32x4 acc[8][4];
  core8<DIMD, DIMD / 64>(xn, W_uvT, m0, n0, tid, sm, acc);
  const int rowb0 = (int)m0 + (w >> 2) * 128 + (l >> 4) * 4;
  const int colb0 = (int)n0 + (w & 3) * 64 + lr;
  if (n0 < 1024) {
    #pragma unroll
    for (int mf = 0; mf < 8; ++mf) {
      #pragma unroll
      for (int nf = 0; nf < 4; ++nf) {
        int col = colb0 + nf * 16;
        float bias = b_uv[col];
        #pragma unroll
        for (int r = 0; r < 4; ++r)
          u_out[(size_t)(rowb0 + mf * 16 + r) * EE + col] = f2bf(silu_f(acc[mf][nf][r] + bias));
      }
    }
  } else {
    #pragma unroll
    for (int mf = 0; mf < 8; ++mf) {
      int row = rowb0 + mf * 16;
      int bb = row >> 12, lb = row & (LLL - 1);
      #pragma unroll
      for (int nf = 0; nf < 4; ++nf) {
        int e = colb0 + nf * 16 - 1024;
        float bias = b_uv[e + 1024];
        short4 o;
        o.x = f2bf(silu_f(acc[mf][nf][0] + bias));
        o.y = f2bf(silu_f(acc[mf][nf][1] + bias));
        o.z = f2bf(silu_f(acc[mf][nf][2] + bias));
        o.w = f2bf(silu_f(acc[mf][nf][3] + bias));
        *(short4*)&vT_out[((size_t)bb * EE + e) * LLL + lb] = o;
      }
    }
  }
}

// ---------------- GEMM1 strip (cols 2048..2175 -> q,k); q pre-scaled by 1/sqrt(S) ----------------
__global__ __launch_bounds__(256) void qkstrip_kernel(
    const short* __restrict__ xn, const short* __restrict__ Wqk,
    const float* __restrict__ b_uv, const float* __restrict__ gamma, const float* __restrict__ beta,
    short* __restrict__ q_out, short* __restrict__ k_out)
{
  __shared__ __align__(16) short sm[8192];
  int tid = threadIdx.x;
  size_t m0 = (size_t)blockIdx.x * 128;
  f32x4 acc[4][4];
  gemm_core(xn, Wqk, DIMD, DIMD, DIMD, m0, 0, tid, sm, acc);
  int wid = tid >> 6, lane = tid & 63;
  int wr = (wid >> 1) * 64, wc = (wid & 1) * 64;
  int lr = lane & 15;
  const float scale = 0.08838834764831845f;
  #pragma unroll
  for (int m = 0; m < 4; m++) {
    #pragma unroll
    for (int n = 0; n < 4; n++) {
      int s = wc + n * 16 + lr;
      float bias = b_uv[2048 + s];
      float g0 = gamma[s] * scale, g1 = gamma[SSS + s];
      float be0 = beta[s] * scale, be1 = beta[SSS + s];
      int rowb = (int)m0 + wr + m * 16 + (lane >> 4) * 4;
      #pragma unroll
      for (int r = 0; r < 4; r++) {
        float val = acc[m][n][r] + bias;
        q_out[(size_t)(rowb + r) * SSS + s] = f2bf(val * g0 + be0);
        k_out[(size_t)(rowb + r) * SSS + s] = f2bf(val * g1 + be1);
      }
    }
  }
}

// ---------------- QK^T swapped, tiled-P writer ----------------
// Computes P^T tiles via mfma(A=k, B=q): lane holds 4 consecutive kv for one
// q-row -> direct coalesced short4 stores into the fragment-tiled P layout:
// off(q,kv) = ((q>>4)*512 + (kv>>3))*128 + (q&15)*8 + (kv&7).
__global__ __launch_bounds__(256, 2) void gqk3_kernel(
    const short* __restrict__ q, const short* __restrict__ k, short* __restrict__ Pt)
{
  __shared__ __align__(16) short sm2[32768];
  const int b = blockIdx.z;
  const size_t q0 = (size_t)blockIdx.x * 128;
  const size_t kv0 = (size_t)blockIdx.y * 128;
  const short* qz = q + (size_t)b * LLL * SSS;
  const short* kz = k + (size_t)b * LLL * SSS;
  short* Pz = Pt + (size_t)b * LLL * LLL;
  const int tid = threadIdx.x, w = tid >> 6, l = tid & 63;
  const int lr = l & 15;
  const int srow = w * 4 + (l >> 4);
  const int scol = ((l & 15) * 8) ^ ((srow & 7) << 3);
  const short* sq = qz + (q0 + srow) * SSS + scol;
  const short* sk = kz + (kv0 + srow) * SSS + scol;
  #pragma unroll
  for (int u = 0; u < 8; ++u) {
    gld16(sq + u * 16 * SSS, &sm2[(u * 16 + w * 4) * 128]);
    gld16(sk + u * 16 * SSS, &sm2[16384 + (u * 16 + w * 4) * 128]);
  }
  f32x4 acc[4][4];
  #pragma unroll
  for (int m = 0; m < 4; m++)
    #pragma unroll
    for (int n = 0; n < 4; n++) acc[m][n] = (f32x4){0.f, 0.f, 0.f, 0.f};
  VMCNT(0);
  __syncthreads();
  const int wr = (w >> 1) * 64, wc = (w & 1) * 64;  // wr: kv-dim, wc: q-dim
  const short* Ak = &sm2[16384 + (wr + lr) * 128];
  const short* Bq = &sm2[(wc + lr) * 128];
  #pragma unroll
  for (int ks = 0; ks < 4; ++ks) {
    const int csw = (ks * 32 + (l >> 4) * 8) ^ ((l & 7) << 3);
    short8 af[4], bf[4];
    #pragma unroll
    for (int m = 0; m < 4; m++) af[m] = *(const short8*)&Ak[m * 16 * 128 + csw];
    #pragma unroll
    for (int n = 0; n < 4; n++) bf[n] = *(const short8*)&Bq[n * 16 * 128 + csw];
    #pragma unroll
    for (int m = 0; m < 4; m++)
      #pragma unroll
      for (int n = 0; n < 4; n++)
        MFMA16(af[m], bf[n], acc[m][n]);
  }
  // acc[i][j]: kv = kv0 + wr + i*16 + (l>>4)*4 + r ; q = q0 + wc + j*16 + lr
  const int kvb = (int)kv0 + wr + (l >> 4) * 4;
  const int qb16 = ((int)q0 + wc) >> 4;
  #pragma unroll
  for (int i = 0; i < 4; i++) {
    #pragma unroll
    for (int j = 0; j < 4; j++) {
      int kv = kvb + i * 16;
      short4 o;
      float v0 = fmaxf(acc[i][j][0], 0.f), v1 = fmaxf(acc[i][j][1], 0.f);
      float v2 = fmaxf(acc[i][j][2], 0.f), v3 = fmaxf(acc[i][j][3], 0.f);
      o.x = f2bf(v0 * v0); o.y = f2bf(v1 * v1); o.z = f2bf(v2 * v2); o.w = f2bf(v3 * v3);
      size_t off = ((size_t)(qb16 + j) * 512 + (kv >> 3)) * 128 + lr * 8 + (kv & 7);
      *(short4*)&Pz[off] = o;
    }
  }
}

// ---------------- PV v3: A-frags direct from tiled P (no LDS for A) ----------------
// B (vT) double-buffered in LDS (2x32KB). Per tile: 8 ds_read(B) -> lgkm0+SBAR ->
// stage B(t+2) -> vmcnt(12) -> 32 MFMA low -> issue Aa(t+1) -> vmcnt(4) ->
// 32 MFMA high -> issue Ah(t+1) -> SBAR.
__global__ __launch_bounds__(512, 2) void gpv9_kernel(
    const short* __restrict__ Ptg, const short* __restrict__ vTg,
    const short* __restrict__ ug, short* __restrict__ gg)
{
  extern __shared__ __align__(16) short sm[];
  const int b = blockIdx.z;
  const size_t m0 = (size_t)blockIdx.x * 256;   // q-row base
  const size_t n0 = (size_t)blockIdx.y * 256;   // e base
  const short* A  = Ptg + (size_t)b * LLL * LLL;
  const short* Bv = vTg + (size_t)b * EE * LLL;
  const int tid = threadIdx.x, w = tid >> 6, l = tid & 63;
  const int lr = l & 15;
  const int colsrc = ((l & 7) * 8) ^ ((l >> 3) << 3);
  const short* srcB = Bv + (n0 + w * 8 + (l >> 3)) * (size_t)LLL + colsrc;
  const int csw0 = ((l >> 4) * 8) ^ ((l & 7) << 3);
  const int csw1 = (32 + (l >> 4) * 8) ^ ((l & 7) << 3);
  const int BOff = ((w & 3) >> 1) * 8192 + ((w & 1) * 64 + lr) * 64;
  const int m16b = (int)(m0 >> 4) + (w >> 2) * 8;
  const short* srcA = A + (size_t)l * 8;        // lane term: l*16B

  #define STB9(bf_, h_, q_, kt_) gld16(srcB + ((h_) * 128 + (q_) * 64) * (size_t)LLL + (kt_) * 64, \
                                       &sm[(bf_) * 16384 + (h_) * 8192 + (q_) * 4096 + w * 512])
  #define LDA9(dst, i_, h_, s_, t_) dst = *(const short8*)(srcA + \
      ((size_t)(m16b + (h_) * 4 + (i_)) * 512 + (size_t)(t_) * 8 + (s_) * 4) * 128)

  f32x4 acc[8][4];
  #pragma unroll
  for (int m = 0; m < 8; m++)
    #pragma unroll
    for (int n = 0; n < 4; n++) acc[m][n] = (f32x4){0.f, 0.f, 0.f, 0.f};
  short8 Aa[4][2], Ah[4][2], Bf[4][2];

  // prologue: B0(4), B1(4), A0(16); drain B0 only
  STB9(0, 0, 0, 0); STB9(0, 1, 0, 0); STB9(0, 0, 1, 0); STB9(0, 1, 1, 0);
  STB9(1, 0, 0, 1); STB9(1, 1, 0, 1); STB9(1, 0, 1, 1); STB9(1, 1, 1, 1);
  #pragma unroll
  for (int i = 0; i < 4; ++i) { LDA9(Aa[i][0], i, 0, 0, 0); LDA9(Aa[i][1], i, 0, 1, 0); }
  #pragma unroll
  for (int i = 0; i < 4; ++i) { LDA9(Ah[i][0], i, 1, 0, 0); LDA9(Ah[i][1], i, 1, 1, 0); }
  VMCNT(20);
  SBAR();
  __builtin_amdgcn_sched_barrier(0);

  const int T = LLL / 64;
  for (int t = 0; t < T; ++t) {
    const int buf = t & 1;
    const short* Bb = sm + buf * 16384 + BOff;
    #pragma unroll
    for (int j = 0; j < 4; ++j) {
      Bf[j][0] = *(const short8*)&Bb[j * 1024 + csw0];
      Bf[j][1] = *(const short8*)&Bb[j * 1024 + csw1];
    }
    LGKM0();
    SBAR();
    if (t + 2 < T) { STB9(buf, 0, 0, t + 2); STB9(buf, 1, 0, t + 2);
                     STB9(buf, 0, 1, t + 2); STB9(buf, 1, 1, t + 2); }
    if (t + 2 < T) { VMCNT(12); } else { VMCNT(8); }   // drains B(t+1)+Aa(t)
    __builtin_amdgcn_s_setprio(1);
    #pragma unroll
    for (int i = 0; i < 4; ++i)
      #pragma unroll
      for (int j = 0; j < 4; ++j) {
        MFMA16(Aa[i][0], Bf[j][0], acc[i][j]);
        MFMA16(Aa[i][1], Bf[j][1], acc[i][j]);
      }
    __builtin_amdgcn_s_setprio(0);
    if (t + 1 < T) {
      #pragma unroll
      for (int i = 0; i < 4; ++i) { LDA9(Aa[i][0], i, 0, 0, t + 1); LDA9(Aa[i][1], i, 0, 1, t + 1); }
    }
    if (t + 2 < T) { VMCNT(4); } else if (t + 1 < T) { VMCNT(8); } else { VMCNT(0); }  // drains Ah(t)
    __builtin_amdgcn_s_setprio(1);
    #pragma unroll
    for (int i = 0; i < 4; ++i)
      #pragma unroll
      for (int j = 0; j < 4; ++j) {
        MFMA16(Ah[i][0], Bf[j][0], acc[4 + i][j]);
        MFMA16(Ah[i][1], Bf[j][1], acc[4 + i][j]);
      }
    __builtin_amdgcn_s_setprio(0);
    if (t + 1 < T) {
      #pragma unroll
      for (int i = 0; i < 4; ++i) { LDA9(Ah[i][0], i, 1, 0, t + 1); LDA9(Ah[i][1], i, 1, 1, t + 1); }
    }
    SBAR();
    __builtin_amdgcn_sched_barrier(0);
  }
  // epilogue: g = u * acc
  const short* ub_ = ug + (size_t)b * LLL * EE;
  short* gb_ = gg + (size_t)b * LLL * EE;
  const int rowb0 = (int)m0 + (w >> 2) * 128 + (l >> 4) * 4;
  const int colb0 = (int)n0 + (w & 3) * 64 + lr;
  #pragma unroll
  for (int mf = 0; mf < 8; ++mf) {
    #pragma unroll
    for (int nf = 0; nf < 4; ++nf) {
      int col = colb0 + nf * 16;
      #pragma unroll
      for (int r = 0; r < 4; ++r) {
        size_t idx = (size_t)(rowb0 + mf * 16 + r) * EE + col;
        gb_[idx] = f2bf(bf2f(ub_[idx]) * acc[mf][nf][r]);
      }
    }
  }
  #undef STB9
  #undef LDA9
}

// ---------------- legacy QK (fallback tiers; q pre-scaled; row-major P) ----------------
__global__ __launch_bounds__(256) void gqk_kernel(
    const short* __restrict__ q, const short* __restrict__ k, short* __restrict__ P,
    long sq, long sk, long sp)
{
  __shared__ __align__(16) short sm[8192];
  int tid = threadIdx.x;
  const short* qz = q + (size_t)blockIdx.z * sq;
  const short* kz = k + (size_t)blockIdx.z * sk;
  short* Pz = P + (size_t)blockIdx.z * sp;
  size_t m0 = (size_t)blockIdx.x * 128, n0 = (size_t)blockIdx.y * 128;
  f32x4 acc[4][4];
  gemm_core(qz, kz, SSS, SSS, SSS, m0, n0, tid, sm, acc);
  int wid = tid >> 6, lane = tid & 63;
  int wr = (wid >> 1) * 64, wc = (wid & 1) * 64;
  int lr = lane & 15;
  #pragma unroll
  for (int m = 0; m < 4; m++) {
    #pragma unroll
    for (int n = 0; n < 4; n++) {
      int col = (int)n0 + wc + n * 16 + lr;
      int rowb = (int)m0 + wr + m * 16 + (lane >> 4) * 4;
      #pragma unroll
      for (int r = 0; r < 4; r++) {
        float v = fmaxf(acc[m][n][r], 0.f);
        Pz[(size_t)(rowb + r) * LLL + col] = f2bf(v * v);
      }
    }
  }
}

// ---------------- legacy PV (fallback tiers): m97 core, row-major P ----------------
__global__ __launch_bounds__(256) void gpv_kernel(
    const short* __restrict__ P, const short* __restrict__ vT,
    const short* __restrict__ u, short* __restrict__ g,
    long sp, long sv, long su)
{
  __shared__ __align__(16) short sm[8192];
  int tid = threadIdx.x;
  const short* Pz = P + (size_t)blockIdx.z * sp;
  const short* vz = vT + (size_t)blockIdx.z * sv;
  const short* uz = u + (size_t)blockIdx.z * su;
  short* gz = g + (size_t)blockIdx.z * su;
  size_t m0 = (size_t)blockIdx.x * 128, n0 = (size_t)blockIdx.y * 128;
  f32x4 acc[4][4];
  gemm_core(Pz, vz, LLL, LLL, LLL, m0, n0, tid, sm, acc);
  int wid = tid >> 6, lane = tid & 63;
  int wr = (wid >> 1) * 64, wc = (wid & 1) * 64;
  int lr = lane & 15;
  #pragma unroll
  for (int m = 0; m < 4; m++) {
    #pragma unroll
    for (int n = 0; n < 4; n++) {
      int col = (int)n0 + wc + n * 16 + lr;
      int rowb = (int)m0 + wr + m * 16 + (lane >> 4) * 4;
      #pragma unroll
      for (int r = 0; r < 4; r++) {
        size_t idx = (size_t)(rowb + r) * EE + col;
        gz[idx] = f2bf(bf2f(uz[idx]) * acc[m][n][r]);
      }
    }
  }
}

// ---------------- GEMM2 legacy (m97, 512 blocks): g x W_outT + bias + residual ----------------
__global__ __launch_bounds__(256) void gout_kernel(
    const short* __restrict__ A, const short* __restrict__ Bw,
    const float* __restrict__ b_out, const float* __restrict__ x,
    float* __restrict__ out)
{
  __shared__ __align__(16) short sm[8192];
  int tid = threadIdx.x;
  size_t m0 = (size_t)blockIdx.x * 128, n0 = (size_t)blockIdx.y * 128;
  f32x4 acc[4][4];
  gemm_core(A, Bw, EE, EE, EE, m0, n0, tid, sm, acc);
  int wid = tid >> 6, lane = tid & 63;
  int wr = (wid >> 1) * 64, wc = (wid & 1) * 64;
  int lr = lane & 15;
  #pragma unroll
  for (int m = 0; m < 4; m++) {
    #pragma unroll
    for (int n = 0; n < 4; n++) {
      int col = (int)n0 + wc + n * 16 + lr;
      float bias = b_out[col];
      int rowb = (int)m0 + wr + m * 16 + (lane >> 4) * 4;
      #pragma unroll
      for (int r = 0; r < 4; r++) {
        size_t idx = (size_t)(rowb + r) * DIMD + col;
        out[idx] = acc[m][n][r] + bias + x[idx];
      }
    }
  }
}

extern "C" void kernel_launch(void* const* d_in, const int* in_sizes, int n_in,
                              void* d_out, int out_size, void* d_ws, size_t ws_size,
                              hipStream_t stream) {
  const float* x     = (const float*)d_in[0];
  const float* W_uv  = (const float*)d_in[1];
  const float* b_uv  = (const float*)d_in[2];
  const float* gamma = (const float*)d_in[3];
  const float* beta  = (const float*)d_in[4];
  const float* W_out = (const float*)d_in[5];
  const float* b_out = (const float*)d_in[6];
  const float* ln_w  = (const float*)d_in[7];
  const float* ln_b  = (const float*)d_in[8];
  float* out = (float*)d_out;

  char* ws = (char*)d_ws;
  short* W_uvT  = (short*)(ws);
  short* W_outT = (short*)(ws + 2228224);
  short* xn     = (short*)(ws + 3276800);
  short* qb     = (short*)(ws + 20054016);
  short* kb     = (short*)(ws + 24248320);
  short* ub     = (short*)(ws + 28442624);
  short* vTb    = (short*)(ws + 61997056);
  short* gb     = (short*)(ws + 95551488);
  short* Pb     = (short*)(ws + 129105920);

  prep_kernel<<<dim3((NUV * DIMD + 255) / 256), 256, 0, stream>>>(W_uv, W_out, W_uvT, W_outT);
  ln_kernel<<<dim3(NROW), 256, 0, stream>>>(x, ln_w, ln_b, xn);
  guv8_kernel<<<dim3(NROW / 256, 8), 512, 131072, stream>>>(xn, W_uvT, b_uv, ub, vTb);
  qkstrip_kernel<<<dim3(NROW / 128), 256, 0, stream>>>(xn, W_uvT + (size_t)2048 * DIMD, b_uv, gamma, beta, qb, kb);

  const long SQ = (long)LLL * SSS;
  const long SP = (long)LLL * LLL;
  const long SV = (long)EE * LLL;
  const long SU = (long)LLL * EE;

  if (ws_size >= 129105920ull + 134217728ull) {
    gqk3_kernel<<<dim3(32, 32, 4), 256, 0, stream>>>(qb, kb, Pb);
    gpv9_kernel<<<dim3(16, 4, 4), 512, 65536, stream>>>(Pb, vTb, ub, gb);
  } else if (ws_size >= 129105920ull + 33554432ull) {
    for (int b = 0; b < 4; b++) {
      gqk_kernel<<<dim3(32, 32, 1), 256, 0, stream>>>(qb + (size_t)b * SQ, kb + (size_t)b * SQ, Pb, 0, 0, 0);
      gpv_kernel<<<dim3(32, 8, 1), 256, 0, stream>>>(Pb, vTb + (size_t)b * SV, ub + (size_t)b * SU, gb + (size_t)b * SU, 0, 0, 0);
    }
  } else {
    short* Pc = xn;
    for (int b = 0; b < 4; b++) {
      for (int h = 0; h < 2; h++) {
        size_t rowoff = (size_t)b * LLL + (size_t)h * 2048;
        gqk_kernel<<<dim3(16, 32, 1), 256, 0, stream>>>(qb + rowoff * SSS, kb + (size_t)b * SQ, Pc, 0, 0, 0);
        gpv_kernel<<<dim3(16, 8, 1), 256, 0, stream>>>(Pc, vTb + (size_t)b * SV, ub + rowoff * EE, gb + rowoff * EE, 0, 0, 0);
      }
    }
  }

  gout_kernel<<<dim3(NROW / 128, DIMD / 128), 256, 0, stream>>>(gb, W_outT, b_out, x, out);
}

// Round 10
// 299.991 us; speedup vs baseline: 1.0676x; 1.0676x over previous
//
#include <hip/hip_runtime.h>

typedef __attribute__((ext_vector_type(8))) short short8;
typedef __attribute__((ext_vector_type(4))) float f32x4;

#define DIMD 512
#define EE 1024
#define SSS 128
#define LLL 4096
#define NROW 16384   // B*L
#define NUV 2176     // 2E+S

__device__ __forceinline__ short f2bf(float f) {
  union { float f; unsigned u; } un; un.f = f;
  unsigned r = un.u + 0x7FFFu + ((un.u >> 16) & 1u);
  return (short)(r >> 16);
}
__device__ __forceinline__ float bf2f(short s) {
  union { unsigned u; float f; } un;
  un.u = ((unsigned)(unsigned short)s) << 16;
  return un.f;
}
__device__ __forceinline__ float silu_f(float x) {
  return x / (1.0f + __expf(-x));
}

__device__ __forceinline__ void gld16(const short* g, short* l) {
  __builtin_amdgcn_global_load_lds(
      (const __attribute__((address_space(1))) unsigned int*)g,
      (__attribute__((address_space(3))) unsigned int*)l, 16, 0, 0);
}

#define MFMA16(a, b, c) c = __builtin_amdgcn_mfma_f32_16x16x32_bf16(a, b, c, 0, 0, 0)
#define SBAR() asm volatile("s_barrier" ::: "memory")
#define VMCNT(n) asm volatile("s_waitcnt vmcnt(" #n ")" ::: "memory")

// ---------------- prep: transpose+cast weights to bf16 ----------------
__global__ void prep_kernel(const float* __restrict__ W_uv, const float* __restrict__ W_out,
                            short* __restrict__ W_uvT, short* __restrict__ W_outT) {
  int i = blockIdx.x * blockDim.x + threadIdx.x;
  if (i < NUV * DIMD) {
    int c = i >> 9, d = i & (DIMD - 1);
    W_uvT[i] = f2bf(W_uv[(size_t)d * NUV + c]);
  }
  if (i < DIMD * EE) {
    int d = i >> 10, e = i & (EE - 1);
    W_outT[i] = f2bf(W_out[(size_t)e * DIMD + d]);
  }
}

// ---------------- layernorm -> xn bf16 ----------------
__global__ __launch_bounds__(256) void ln_kernel(const float* __restrict__ x,
    const float* __restrict__ w, const float* __restrict__ bb, short* __restrict__ xn) {
  int row = blockIdx.x;
  int tid = threadIdx.x;
  const float2* xr = (const float2*)(x + (size_t)row * DIMD);
  float2 v = xr[tid];
  float s = v.x + v.y, ss = v.x * v.x + v.y * v.y;
  #pragma unroll
  for (int off = 32; off >= 1; off >>= 1) {
    s += __shfl_down(s, off);
    ss += __shfl_down(ss, off);
  }
  __shared__ float ps[8];
  if ((tid & 63) == 0) { ps[tid >> 6] = s; ps[4 + (tid >> 6)] = ss; }
  __syncthreads();
  s = ps[0] + ps[1] + ps[2] + ps[3];
  ss = ps[4] + ps[5] + ps[6] + ps[7];
  float mu = s * (1.0f / DIMD);
  float var = ss * (1.0f / DIMD) - mu * mu;
  float inv = rsqrtf(var + 1e-5f);
  float2 wv = ((const float2*)w)[tid];
  float2 bv = ((const float2*)bb)[tid];
  short2 o;
  o.x = f2bf((v.x - mu) * inv * wv.x + bv.x);
  o.y = f2bf((v.y - mu) * inv * wv.y + bv.y);
  *(short2*)&xn[(size_t)row * DIMD + tid * 2] = o;
}

// ---------------- m97-style GEMM core: 128x128 tile, 4 waves, BK=32 ----------------
__device__ __forceinline__ void gemm_core(const short* __restrict__ A, const short* __restrict__ B,
                                          int lda, int ldb, int K, size_t m0, size_t n0,
                                          int tid, short* sm, f32x4 acc[4][4]) {
  short* As = sm;
  short* Bs = sm + 4096;
  int wid = tid >> 6, lane = tid & 63;
  int wr = (wid >> 1) * 64, wc = (wid & 1) * 64;
  int lr = lane & 15, lk = (lane >> 4) * 8;
  int r0 = tid >> 2, c0 = (tid & 3) * 8;
  #pragma unroll
  for (int m = 0; m < 4; m++)
    #pragma unroll
    for (int n = 0; n < 4; n++) acc[m][n] = (f32x4){0.f, 0.f, 0.f, 0.f};
  for (int k0 = 0; k0 < K; k0 += 32) {
    gld16(&A[(m0 + r0) * lda + k0 + c0],      &As[wid * 512]);
    gld16(&A[(m0 + 64 + r0) * lda + k0 + c0], &As[2048 + wid * 512]);
    gld16(&B[(n0 + r0) * ldb + k0 + c0],      &Bs[wid * 512]);
    gld16(&B[(n0 + 64 + r0) * ldb + k0 + c0], &Bs[2048 + wid * 512]);
    __syncthreads();
    short8 af[4], bf[4];
    #pragma unroll
    for (int m = 0; m < 4; m++) af[m] = *(short8*)&As[(wr + m * 16 + lr) * 32 + lk];
    #pragma unroll
    for (int n = 0; n < 4; n++) bf[n] = *(short8*)&Bs[(wc + n * 16 + lr) * 32 + lk];
    #pragma unroll
    for (int m = 0; m < 4; m++)
      #pragma unroll
      for (int n = 0; n < 4; n++)
        MFMA16(af[m], bf[n], acc[m][n]);
    __syncthreads();
  }
}

// ============ 256x256 8-phase pipelined GEMM core v3 ============
// Template-cadence waits: stage B(t+1) at q1 (4 loads), A(t+2) at q4 (4 loads),
// ONE vmcnt(4) at q4-end. FIFO: q4(t-1)-end leaves A(t+1); q1(t) +B(t+1)=8;
// q4(t) +A(t+2)=12; vmcnt(4) drains A(t+1)+B(t+1) = exactly next tile's reads.
template<int LD, int T>
__device__ __forceinline__ void core8(const short* __restrict__ A, const short* __restrict__ Bv,
                                      size_t m0, size_t n0, int tid, short* sm,
                                      f32x4 (&acc)[8][4]) {
  const int w = tid >> 6, l = tid & 63;
  const int lr = l & 15;
  const int colsrc = ((l & 7) * 8) ^ ((l >> 3) << 3);
  const short* srcA = A  + (m0 + w * 8 + (l >> 3)) * (size_t)LD + colsrc;
  const short* srcB = Bv + (n0 + w * 8 + (l >> 3)) * (size_t)LD + colsrc;
  const int csw0 = ((l >> 4) * 8) ^ ((l & 7) << 3);
  const int csw1 = (32 + (l >> 4) * 8) ^ ((l & 7) << 3);
  const int AhalfOff = (w >> 2) * 8192 + lr * 64;
  const int BhalfOff = 16384 + ((w & 3) >> 1) * 8192 + ((w & 1) * 64 + lr) * 64;

  #define STA8(bf_, h_, q_, kt_) gld16(srcA + ((h_) * 128 + (q_) * 64) * (size_t)LD + (kt_) * 64, \
                                       &sm[(bf_) * 32768 + (h_) * 8192 + (q_) * 4096 + w * 512])
  #define STB8(bf_, h_, q_, kt_) gld16(srcB + ((h_) * 128 + (q_) * 64) * (size_t)LD + (kt_) * 64, \
                                       &sm[(bf_) * 32768 + 16384 + (h_) * 8192 + (q_) * 4096 + w * 512])

  #pragma unroll
  for (int m = 0; m < 8; m++)
    #pragma unroll
    for (int n = 0; n < 4; n++) acc[m][n] = (f32x4){0.f, 0.f, 0.f, 0.f};
  short8 Af[4][2], Bf0[2][2], Bf1[2][2];

  // prologue: A(0)x4, B(0)x4, A(1)x4; vmcnt(4) keeps A(1) in flight
  STA8(0, 0, 0, 0); STA8(0, 1, 0, 0); STA8(0, 0, 1, 0); STA8(0, 1, 1, 0);
  STB8(0, 0, 0, 0); STB8(0, 1, 0, 0); STB8(0, 0, 1, 0); STB8(0, 1, 1, 0);
  STA8(1, 0, 0, 1); STA8(1, 1, 0, 1); STA8(1, 0, 1, 1); STA8(1, 1, 1, 1);
  VMCNT(4);
  SBAR();
  __builtin_amdgcn_sched_barrier(0);

  for (int t = 0; t < T; ++t) {
    const int buf = t & 1, nb = buf ^ 1;
    short* Ab = sm + buf * 32768 + AhalfOff;
    short* Bb = sm + buf * 32768 + BhalfOff;
    // ---- q1: quadrant (mh0,nh0); stage all B(t+1); reads A-low + B-low
    if (t + 1 < T) { STB8(nb, 0, 0, t + 1); STB8(nb, 1, 0, t + 1);
                     STB8(nb, 0, 1, t + 1); STB8(nb, 1, 1, t + 1); }
    #pragma unroll
    for (int i = 0; i < 4; ++i) {
      Af[i][0] = *(const short8*)&Ab[i * 1024 + csw0];
      Af[i][1] = *(const short8*)&Ab[i * 1024 + csw1];
    }
    #pragma unroll
    for (int j = 0; j < 2; ++j) {
      Bf0[j][0] = *(const short8*)&Bb[j * 1024 + csw0];
      Bf0[j][1] = *(const short8*)&Bb[j * 1024 + csw1];
    }
    SBAR();
    __builtin_amdgcn_s_setprio(1);
    #pragma unroll
    for (int i = 0; i < 4; ++i)
      #pragma unroll
      for (int j = 0; j < 2; ++j) {
        MFMA16(Af[i][0], Bf0[j][0], acc[i][j]);
        MFMA16(Af[i][1], Bf0[j][1], acc[i][j]);
      }
    __builtin_amdgcn_s_setprio(0);
    SBAR();
    // ---- q2: quadrant (mh0,nh1); reads B-high
    #pragma unroll
    for (int j = 0; j < 2; ++j) {
      Bf1[j][0] = *(const short8*)&Bb[2048 + j * 1024 + csw0];
      Bf1[j][1] = *(const short8*)&Bb[2048 + j * 1024 + csw1];
    }
    SBAR();
    __builtin_amdgcn_s_setprio(1);
    #pragma unroll
    for (int i = 0; i < 4; ++i)
      #pragma unroll
      for (int j = 0; j < 2; ++j) {
        MFMA16(Af[i][0], Bf1[j][0], acc[i][2 + j]);
        MFMA16(Af[i][1], Bf1[j][1], acc[i][2 + j]);
      }
    __builtin_amdgcn_s_setprio(0);
    SBAR();
    // ---- q3: quadrant (mh1,nh1); reads A-high
    #pragma unroll
    for (int i = 0; i < 4; ++i) {
      Af[i][0] = *(const short8*)&Ab[4096 + i * 1024 + csw0];
      Af[i][1] = *(const short8*)&Ab[4096 + i * 1024 + csw1];
    }
    SBAR();
    __builtin_amdgcn_s_setprio(1);
    #pragma unroll
    for (int i = 0; i < 4; ++i)
      #pragma unroll
      for (int j = 0; j < 2; ++j) {
        MFMA16(Af[i][0], Bf1[j][0], acc[4 + i][2 + j]);
        MFMA16(Af[i][1], Bf1[j][1], acc[4 + i][2 + j]);
      }
    __builtin_amdgcn_s_setprio(0);
    SBAR();
    // ---- q4: quadrant (mh1,nh0); stage all A(t+2) into cur buf; single wait
    if (t + 2 < T) { STA8(buf, 0, 0, t + 2); STA8(buf, 1, 0, t + 2);
                     STA8(buf, 0, 1, t + 2); STA8(buf, 1, 1, t + 2); }
    __builtin_amdgcn_s_setprio(1);
    #pragma unroll
    for (int i = 0; i < 4; ++i)
      #pragma unroll
      for (int j = 0; j < 2; ++j) {
        MFMA16(Af[i][0], Bf0[j][0], acc[4 + i][j]);
        MFMA16(Af[i][1], Bf0[j][1], acc[4 + i][j]);
      }
    __builtin_amdgcn_s_setprio(0);
    if (t + 2 < T) { VMCNT(4); } else { VMCNT(0); }
    SBAR();
    __builtin_amdgcn_sched_barrier(0);
  }
  #undef STA8
  #undef STB8
}

// ---------------- GEMM1 main (cols 0..2047): 8-phase 256x256 ----------------
__global__ __launch_bounds__(512, 2) void guv8_kernel(
    const short* __restrict__ xn, const short* __restrict__ W_uvT,
    const float* __restrict__ b_uv,
    short* __restrict__ u_out, short* __restrict__ vT_out)
{
  extern __shared__ __align__(16) short sm[];
  const size_t m0 = (size_t)blockIdx.x * 256;
  const size_t n0 = (size_t)blockIdx.y * 256;
  const int tid = threadIdx.x, w = tid >> 6, l = tid & 63;
  const int lr = l & 15;
  f32x4 acc[8][4];
  core8<DIMD, DIMD / 64>(xn, W_uvT, m0, n0, tid, sm, acc);
  const int rowb0 = (int)m0 + (w >> 2) * 128 + (l >> 4) * 4;
  const int colb0 = (int)n0 + (w & 3) * 64 + lr;
  if (n0 < 1024) {
    #pragma unroll
    for (int mf = 0; mf < 8; ++mf) {
      #pragma unroll
      for (int nf = 0; nf < 4; ++nf) {
        int col = colb0 + nf * 16;
        float bias = b_uv[col];
        #pragma unroll
        for (int r = 0; r < 4; ++r)
          u_out[(size_t)(rowb0 + mf * 16 + r) * EE + col] = f2bf(silu_f(acc[mf][nf][r] + bias));
      }
    }
  } else {
    #pragma unroll
    for (int mf = 0; mf < 8; ++mf) {
      int row = rowb0 + mf * 16;
      int bb = row >> 12, lb = row & (LLL - 1);
      #pragma unroll
      for (int nf = 0; nf < 4; ++nf) {
        int e = colb0 + nf * 16 - 1024;
        float bias = b_uv[e + 1024];
        short4 o;
        o.x = f2bf(silu_f(acc[mf][nf][0] + bias));
        o.y = f2bf(silu_f(acc[mf][nf][1] + bias));
        o.z = f2bf(silu_f(acc[mf][nf][2] + bias));
        o.w = f2bf(silu_f(acc[mf][nf][3] + bias));
        *(short4*)&vT_out[((size_t)bb * EE + e) * LLL + lb] = o;
      }
    }
  }
}

// ---------------- GEMM1 strip (cols 2048..2175 -> q,k); q pre-scaled by 1/sqrt(S) ----------------
__global__ __launch_bounds__(256) void qkstrip_kernel(
    const short* __restrict__ xn, const short* __restrict__ Wqk,
    const float* __restrict__ b_uv, const float* __restrict__ gamma, const float* __restrict__ beta,
    short* __restrict__ q_out, short* __restrict__ k_out)
{
  __shared__ __align__(16) short sm[8192];
  int tid = threadIdx.x;
  size_t m0 = (size_t)blockIdx.x * 128;
  f32x4 acc[4][4];
  gemm_core(xn, Wqk, DIMD, DIMD, DIMD, m0, 0, tid, sm, acc);
  int wid = tid >> 6, lane = tid & 63;
  int wr = (wid >> 1) * 64, wc = (wid & 1) * 64;
  int lr = lane & 15;
  const float scale = 0.08838834764831845f;
  #pragma unroll
  for (int m = 0; m < 4; m++) {
    #pragma unroll
    for (int n = 0; n < 4; n++) {
      int s = wc + n * 16 + lr;
      float bias = b_uv[2048 + s];
      float g0 = gamma[s] * scale, g1 = gamma[SSS + s];
      float be0 = beta[s] * scale, be1 = beta[SSS + s];
      int rowb = (int)m0 + wr + m * 16 + (lane >> 4) * 4;
      #pragma unroll
      for (int r = 0; r < 4; r++) {
        float val = acc[m][n][r] + bias;
        q_out[(size_t)(rowb + r) * SSS + s] = f2bf(val * g0 + be0);
        k_out[(size_t)(rowb + r) * SSS + s] = f2bf(val * g1 + be1);
      }
    }
  }
}

// ---------------- QK^T resident-LDS: 128x128 P-tile, whole K=128 in LDS ----------------
__global__ __launch_bounds__(256, 2) void gqk2_kernel(
    const short* __restrict__ q, const short* __restrict__ k, short* __restrict__ P)
{
  __shared__ __align__(16) short sm2[32768];
  const int b = blockIdx.z;
  const size_t m0 = (size_t)blockIdx.x * 128;
  const size_t n0 = (size_t)blockIdx.y * 128;
  const short* qz = q + (size_t)b * LLL * SSS;
  const short* kz = k + (size_t)b * LLL * SSS;
  short* Pz = P + (size_t)b * LLL * LLL;
  const int tid = threadIdx.x, w = tid >> 6, l = tid & 63;
  const int lr = l & 15;
  const int srow = w * 4 + (l >> 4);
  const int scol = ((l & 15) * 8) ^ ((srow & 7) << 3);
  const short* sq = qz + (m0 + srow) * SSS + scol;
  const short* sk = kz + (n0 + srow) * SSS + scol;
  #pragma unroll
  for (int u = 0; u < 8; ++u) {
    gld16(sq + u * 16 * SSS, &sm2[(u * 16 + w * 4) * 128]);
    gld16(sk + u * 16 * SSS, &sm2[16384 + (u * 16 + w * 4) * 128]);
  }
  f32x4 acc[4][4];
  #pragma unroll
  for (int m = 0; m < 4; m++)
    #pragma unroll
    for (int n = 0; n < 4; n++) acc[m][n] = (f32x4){0.f, 0.f, 0.f, 0.f};
  VMCNT(0);
  __syncthreads();
  const int wr = (w >> 1) * 64, wc = (w & 1) * 64;
  const short* Aq = &sm2[(wr + lr) * 128];
  const short* Bk = &sm2[16384 + (wc + lr) * 128];
  #pragma unroll
  for (int ks = 0; ks < 4; ++ks) {
    const int csw = (ks * 32 + (l >> 4) * 8) ^ ((l & 7) << 3);
    short8 af[4], bf[4];
    #pragma unroll
    for (int m = 0; m < 4; m++) af[m] = *(const short8*)&Aq[m * 16 * 128 + csw];
    #pragma unroll
    for (int n = 0; n < 4; n++) bf[n] = *(const short8*)&Bk[n * 16 * 128 + csw];
    #pragma unroll
    for (int m = 0; m < 4; m++)
      #pragma unroll
      for (int n = 0; n < 4; n++)
        MFMA16(af[m], bf[n], acc[m][n]);
  }
  #pragma unroll
  for (int m = 0; m < 4; m++) {
    #pragma unroll
    for (int n = 0; n < 4; n++) {
      int col = (int)n0 + wc + n * 16 + lr;
      int rowb = (int)m0 + wr + m * 16 + (l >> 4) * 4;
      #pragma unroll
      for (int r = 0; r < 4; r++) {
        float v = fmaxf(acc[m][n][r], 0.f);
        Pz[(size_t)(rowb + r) * LLL + col] = f2bf(v * v);
      }
    }
  }
}

// ---------------- legacy QK (fallback tiers; q pre-scaled; row-major P) ----------------
__global__ __launch_bounds__(256) void gqk_kernel(
    const short* __restrict__ q, const short* __restrict__ k, short* __restrict__ P,
    long sq, long sk, long sp)
{
  __shared__ __align__(16) short sm[8192];
  int tid = threadIdx.x;
  const short* qz = q + (size_t)blockIdx.z * sq;
  const short* kz = k + (size_t)blockIdx.z * sk;
  short* Pz = P + (size_t)blockIdx.z * sp;
  size_t m0 = (size_t)blockIdx.x * 128, n0 = (size_t)blockIdx.y * 128;
  f32x4 acc[4][4];
  gemm_core(qz, kz, SSS, SSS, SSS, m0, n0, tid, sm, acc);
  int wid = tid >> 6, lane = tid & 63;
  int wr = (wid >> 1) * 64, wc = (wid & 1) * 64;
  int lr = lane & 15;
  #pragma unroll
  for (int m = 0; m < 4; m++) {
    #pragma unroll
    for (int n = 0; n < 4; n++) {
      int col = (int)n0 + wc + n * 16 + lr;
      int rowb = (int)m0 + wr + m * 16 + (lane >> 4) * 4;
      #pragma unroll
      for (int r = 0; r < 4; r++) {
        float v = fmaxf(acc[m][n][r], 0.f);
        Pz[(size_t)(rowb + r) * LLL + col] = f2bf(v * v);
      }
    }
  }
}

// ---------------- legacy PV (fallback tiers): m97 core, row-major P ----------------
__global__ __launch_bounds__(256) void gpv_kernel(
    const short* __restrict__ P, const short* __restrict__ vT,
    const short* __restrict__ u, short* __restrict__ g,
    long sp, long sv, long su)
{
  __shared__ __align__(16) short sm[8192];
  int tid = threadIdx.x;
  const short* Pz = P + (size_t)blockIdx.z * sp;
  const short* vz = vT + (size_t)blockIdx.z * sv;
  const short* uz = u + (size_t)blockIdx.z * su;
  short* gz = g + (size_t)blockIdx.z * su;
  size_t m0 = (size_t)blockIdx.x * 128, n0 = (size_t)blockIdx.y * 128;
  f32x4 acc[4][4];
  gemm_core(Pz, vz, LLL, LLL, LLL, m0, n0, tid, sm, acc);
  int wid = tid >> 6, lane = tid & 63;
  int wr = (wid >> 1) * 64, wc = (wid & 1) * 64;
  int lr = lane & 15;
  #pragma unroll
  for (int m = 0; m < 4; m++) {
    #pragma unroll
    for (int n = 0; n < 4; n++) {
      int col = (int)n0 + wc + n * 16 + lr;
      int rowb = (int)m0 + wr + m * 16 + (lane >> 4) * 4;
      #pragma unroll
      for (int r = 0; r < 4; r++) {
        size_t idx = (size_t)(rowb + r) * EE + col;
        gz[idx] = f2bf(bf2f(uz[idx]) * acc[m][n][r]);
      }
    }
  }
}

// ---------------- PV, 256x256 (core v3) ----------------
__global__ __launch_bounds__(512, 2) void gpv8_kernel(
    const short* __restrict__ Pg, const short* __restrict__ vTg,
    const short* __restrict__ ug, short* __restrict__ gg)
{
  extern __shared__ __align__(16) short sm[];
  const int b = blockIdx.z;
  const size_t m0 = (size_t)blockIdx.x * 256;
  const size_t n0 = (size_t)blockIdx.y * 256;
  const short* A  = Pg  + (size_t)b * LLL * LLL;
  const short* Bv = vTg + (size_t)b * EE * LLL;
  const int tid = threadIdx.x, w = tid >> 6, l = tid & 63;
  const int lr = l & 15;
  f32x4 acc[8][4];
  core8<LLL, LLL / 64>(A, Bv, m0, n0, tid, sm, acc);
  const short* ub_ = ug + (size_t)b * LLL * EE;
  short* gb_ = gg + (size_t)b * LLL * EE;
  const int rowb0 = (int)m0 + (w >> 2) * 128 + (l >> 4) * 4;
  const int colb0 = (int)n0 + (w & 3) * 64 + lr;
  #pragma unroll
  for (int mf = 0; mf < 8; ++mf) {
    #pragma unroll
    for (int nf = 0; nf < 4; ++nf) {
      int col = colb0 + nf * 16;
      #pragma unroll
      for (int r = 0; r < 4; ++r) {
        size_t idx = (size_t)(rowb0 + mf * 16 + r) * EE + col;
        gb_[idx] = f2bf(bf2f(ub_[idx]) * acc[mf][nf][r]);
      }
    }
  }
}

// ---------------- GEMM2 legacy (m97, 512 blocks): g x W_outT + bias + residual ----------------
__global__ __launch_bounds__(256) void gout_kernel(
    const short* __restrict__ A, const short* __restrict__ Bw,
    const float* __restrict__ b_out, const float* __restrict__ x,
    float* __restrict__ out)
{
  __shared__ __align__(16) short sm[8192];
  int tid = threadIdx.x;
  size_t m0 = (size_t)blockIdx.x * 128, n0 = (size_t)blockIdx.y * 128;
  f32x4 acc[4][4];
  gemm_core(A, Bw, EE, EE, EE, m0, n0, tid, sm, acc);
  int wid = tid >> 6, lane = tid & 63;
  int wr = (wid >> 1) * 64, wc = (wid & 1) * 64;
  int lr = lane & 15;
  #pragma unroll
  for (int m = 0; m < 4; m++) {
    #pragma unroll
    for (int n = 0; n < 4; n++) {
      int col = (int)n0 + wc + n * 16 + lr;
      float bias = b_out[col];
      int rowb = (int)m0 + wr + m * 16 + (lane >> 4) * 4;
      #pragma unroll
      for (int r = 0; r < 4; r++) {
        size_t idx = (size_t)(rowb + r) * DIMD + col;
        out[idx] = acc[m][n][r] + bias + x[idx];
      }
    }
  }
}

extern "C" void kernel_launch(void* const* d_in, const int* in_sizes, int n_in,
                              void* d_out, int out_size, void* d_ws, size_t ws_size,
                              hipStream_t stream) {
  const float* x     = (const float*)d_in[0];
  const float* W_uv  = (const float*)d_in[1];
  const float* b_uv  = (const float*)d_in[2];
  const float* gamma = (const float*)d_in[3];
  const float* beta  = (const float*)d_in[4];
  const float* W_out = (const float*)d_in[5];
  const float* b_out = (const float*)d_in[6];
  const float* ln_w  = (const float*)d_in[7];
  const float* ln_b  = (const float*)d_in[8];
  float* out = (float*)d_out;

  char* ws = (char*)d_ws;
  short* W_uvT  = (short*)(ws);
  short* W_outT = (short*)(ws + 2228224);
  short* xn     = (short*)(ws + 3276800);
  short* qb     = (short*)(ws + 20054016);
  short* kb     = (short*)(ws + 24248320);
  short* ub     = (short*)(ws + 28442624);
  short* vTb    = (short*)(ws + 61997056);
  short* gb     = (short*)(ws + 95551488);
  short* Pb     = (short*)(ws + 129105920);

  prep_kernel<<<dim3((NUV * DIMD + 255) / 256), 256, 0, stream>>>(W_uv, W_out, W_uvT, W_outT);
  ln_kernel<<<dim3(NROW), 256, 0, stream>>>(x, ln_w, ln_b, xn);
  guv8_kernel<<<dim3(NROW / 256, 8), 512, 131072, stream>>>(xn, W_uvT, b_uv, ub, vTb);
  qkstrip_kernel<<<dim3(NROW / 128), 256, 0, stream>>>(xn, W_uvT + (size_t)2048 * DIMD, b_uv, gamma, beta, qb, kb);

  const long SQ = (long)LLL * SSS;
  const long SP = (long)LLL * LLL;
  const long SV = (long)EE * LLL;
  const long SU = (long)LLL * EE;

  if (ws_size >= 129105920ull + 134217728ull) {
    gqk2_kernel<<<dim3(32, 32, 4), 256, 0, stream>>>(qb, kb, Pb);
    gpv8_kernel<<<dim3(16, 4, 4), 512, 131072, stream>>>(Pb, vTb, ub, gb);
  } else if (ws_size >= 129105920ull + 33554432ull) {
    for (int b = 0; b < 4; b++) {
      gqk_kernel<<<dim3(32, 32, 1), 256, 0, stream>>>(qb + (size_t)b * SQ, kb + (size_t)b * SQ, Pb, 0, 0, 0);
      gpv_kernel<<<dim3(32, 8, 1), 256, 0, stream>>>(Pb, vTb + (size_t)b * SV, ub + (size_t)b * SU, gb + (size_t)b * SU, 0, 0, 0);
    }
  } else {
    short* Pc = xn;
    for (int b = 0; b < 4; b++) {
      for (int h = 0; h < 2; h++) {
        size_t rowoff = (size_t)b * LLL + (size_t)h * 2048;
        gqk_kernel<<<dim3(16, 32, 1), 256, 0, stream>>>(qb + rowoff * SSS, kb + (size_t)b * SQ, Pc, 0, 0, 0);
        gpv_kernel<<<dim3(16, 8, 1), 256, 0, stream>>>(Pc, vTb + (size_t)b * SV, ub + rowoff * EE, gb + rowoff * EE, 0, 0, 0);
      }
    }
  }

  gout_kernel<<<dim3(NROW / 128, DIMD / 128), 256, 0, stream>>>(gb, W_outT, b_out, x, out);
}

// Round 11
// 280.942 us; speedup vs baseline: 1.1400x; 1.0678x over previous
//
#include <hip/hip_runtime.h>

typedef __attribute__((ext_vector_type(8))) short short8;
typedef __attribute__((ext_vector_type(4))) float f32x4;

#define DIMD 512
#define EE 1024
#define SSS 128
#define LLL 4096
#define NROW 16384   // B*L
#define NUV 2176     // 2E+S

__device__ __forceinline__ short f2bf(float f) {
  union { float f; unsigned u; } un; un.f = f;
  unsigned r = un.u + 0x7FFFu + ((un.u >> 16) & 1u);
  return (short)(r >> 16);
}
__device__ __forceinline__ float bf2f(short s) {
  union { unsigned u; float f; } un;
  un.u = ((unsigned)(unsigned short)s) << 16;
  return un.f;
}
__device__ __forceinline__ float silu_f(float x) {
  return x / (1.0f + __expf(-x));
}

__device__ __forceinline__ void gld16(const short* g, short* l) {
  __builtin_amdgcn_global_load_lds(
      (const __attribute__((address_space(1))) unsigned int*)g,
      (__attribute__((address_space(3))) unsigned int*)l, 16, 0, 0);
}

#define MFMA16(a, b, c) c = __builtin_amdgcn_mfma_f32_16x16x32_bf16(a, b, c, 0, 0, 0)
#define SBAR() asm volatile("s_barrier" ::: "memory")
#define VMCNT(n) asm volatile("s_waitcnt vmcnt(" #n ")" ::: "memory")

// ---------------- fused prep+layernorm ----------------
// blocks [0, NROW): layernorm row; blocks [NROW, NROW+4352): weight transpose.
__global__ __launch_bounds__(256) void prepln_kernel(
    const float* __restrict__ x, const float* __restrict__ w, const float* __restrict__ bb,
    short* __restrict__ xn,
    const float* __restrict__ W_uv, const float* __restrict__ W_out,
    short* __restrict__ W_uvT, short* __restrict__ W_outT) {
  int tid = threadIdx.x;
  if (blockIdx.x >= NROW) {
    int i = (blockIdx.x - NROW) * 256 + tid;
    if (i < NUV * DIMD) {            // W_uvT[c][d] = W_uv[d][c]
      int c = i >> 9, d = i & (DIMD - 1);
      W_uvT[i] = f2bf(W_uv[(size_t)d * NUV + c]);
    }
    if (i < DIMD * EE) {             // W_outT[d][e] = W_out[e][d]
      int d = i >> 10, e = i & (EE - 1);
      W_outT[i] = f2bf(W_out[(size_t)e * DIMD + d]);
    }
    return;
  }
  int row = blockIdx.x;
  const float2* xr = (const float2*)(x + (size_t)row * DIMD);
  float2 v = xr[tid];
  float s = v.x + v.y, ss = v.x * v.x + v.y * v.y;
  #pragma unroll
  for (int off = 32; off >= 1; off >>= 1) {
    s += __shfl_down(s, off);
    ss += __shfl_down(ss, off);
  }
  __shared__ float ps[8];
  if ((tid & 63) == 0) { ps[tid >> 6] = s; ps[4 + (tid >> 6)] = ss; }
  __syncthreads();
  s = ps[0] + ps[1] + ps[2] + ps[3];
  ss = ps[4] + ps[5] + ps[6] + ps[7];
  float mu = s * (1.0f / DIMD);
  float var = ss * (1.0f / DIMD) - mu * mu;
  float inv = rsqrtf(var + 1e-5f);
  float2 wv = ((const float2*)w)[tid];
  float2 bv = ((const float2*)bb)[tid];
  short2 o;
  o.x = f2bf((v.x - mu) * inv * wv.x + bv.x);
  o.y = f2bf((v.y - mu) * inv * wv.y + bv.y);
  *(short2*)&xn[(size_t)row * DIMD + tid * 2] = o;
}

// ---------------- m97-style GEMM core: 128x128 tile, 4 waves, BK=32 ----------------
__device__ __forceinline__ void gemm_core(const short* __restrict__ A, const short* __restrict__ B,
                                          int lda, int ldb, int K, size_t m0, size_t n0,
                                          int tid, short* sm, f32x4 acc[4][4]) {
  short* As = sm;
  short* Bs = sm + 4096;
  int wid = tid >> 6, lane = tid & 63;
  int wr = (wid >> 1) * 64, wc = (wid & 1) * 64;
  int lr = lane & 15, lk = (lane >> 4) * 8;
  int r0 = tid >> 2, c0 = (tid & 3) * 8;
  #pragma unroll
  for (int m = 0; m < 4; m++)
    #pragma unroll
    for (int n = 0; n < 4; n++) acc[m][n] = (f32x4){0.f, 0.f, 0.f, 0.f};
  for (int k0 = 0; k0 < K; k0 += 32) {
    gld16(&A[(m0 + r0) * lda + k0 + c0],      &As[wid * 512]);
    gld16(&A[(m0 + 64 + r0) * lda + k0 + c0], &As[2048 + wid * 512]);
    gld16(&B[(n0 + r0) * ldb + k0 + c0],      &Bs[wid * 512]);
    gld16(&B[(n0 + 64 + r0) * ldb + k0 + c0], &Bs[2048 + wid * 512]);
    __syncthreads();
    short8 af[4], bf[4];
    #pragma unroll
    for (int m = 0; m < 4; m++) af[m] = *(short8*)&As[(wr + m * 16 + lr) * 32 + lk];
    #pragma unroll
    for (int n = 0; n < 4; n++) bf[n] = *(short8*)&Bs[(wc + n * 16 + lr) * 32 + lk];
    #pragma unroll
    for (int m = 0; m < 4; m++)
      #pragma unroll
      for (int n = 0; n < 4; n++)
        MFMA16(af[m], bf[n], acc[m][n]);
    __syncthreads();
  }
}

// ============ 256x256 8-phase pipelined GEMM core — R5 schedule (best: 128.5us) ============
// Uniform stage cadence, 2 loads/phase, vmcnt(6) at every phase end:
// q1: Bl(t+1), q2: Bh(t+1), q3: Ah(t+1), q4: Al(t+2) into cur buf.
template<int LD, int T>
__device__ __forceinline__ void core8(const short* __restrict__ A, const short* __restrict__ Bv,
                                      size_t m0, size_t n0, int tid, short* sm,
                                      f32x4 (&acc)[8][4]) {
  const int w = tid >> 6, l = tid & 63;
  const int lr = l & 15;
  const int colsrc = ((l & 7) * 8) ^ ((l >> 3) << 3);
  const short* srcA = A  + (m0 + w * 8 + (l >> 3)) * (size_t)LD + colsrc;
  const short* srcB = Bv + (n0 + w * 8 + (l >> 3)) * (size_t)LD + colsrc;
  const int csw0 = ((l >> 4) * 8) ^ ((l & 7) << 3);
  const int csw1 = (32 + (l >> 4) * 8) ^ ((l & 7) << 3);
  const int AhalfOff = (w >> 2) * 8192 + lr * 64;
  const int BhalfOff = 16384 + ((w & 3) >> 1) * 8192 + ((w & 1) * 64 + lr) * 64;

  #define STA8(bf_, h_, q_, kt_) gld16(srcA + ((h_) * 128 + (q_) * 64) * (size_t)LD + (kt_) * 64, \
                                       &sm[(bf_) * 32768 + (h_) * 8192 + (q_) * 4096 + w * 512])
  #define STB8(bf_, h_, q_, kt_) gld16(srcB + ((h_) * 128 + (q_) * 64) * (size_t)LD + (kt_) * 64, \
                                       &sm[(bf_) * 32768 + 16384 + (h_) * 8192 + (q_) * 4096 + w * 512])

  #pragma unroll
  for (int m = 0; m < 8; m++)
    #pragma unroll
    for (int n = 0; n < 4; n++) acc[m][n] = (f32x4){0.f, 0.f, 0.f, 0.f};
  short8 Af[4][2], Bf0[2][2], Bf1[2][2];

  // prologue: tile0 all 8 units, then tile1 A-lows (kept in flight)
  STA8(0, 0, 0, 0); STA8(0, 1, 0, 0);   // Al0
  STB8(0, 0, 0, 0); STB8(0, 1, 0, 0);   // Bl0
  STB8(0, 0, 1, 0); STB8(0, 1, 1, 0);   // Bh0
  STA8(0, 0, 1, 0); STA8(0, 1, 1, 0);   // Ah0
  STA8(1, 0, 0, 1); STA8(1, 1, 0, 1);   // Al1
  VMCNT(2);
  SBAR();
  __builtin_amdgcn_sched_barrier(0);

  for (int t = 0; t < T; ++t) {
    const int buf = t & 1, nb = buf ^ 1;
    short* Ab = sm + buf * 32768 + AhalfOff;
    short* Bb = sm + buf * 32768 + BhalfOff;
    // ---- q1: quadrant (mh0, nh0); stage Bl(t+1); reads A-lows + B-lows
    if (t + 1 < T) { STB8(nb, 0, 0, t + 1); STB8(nb, 1, 0, t + 1); }
    #pragma unroll
    for (int i = 0; i < 4; ++i) {
      Af[i][0] = *(const short8*)&Ab[i * 1024 + csw0];
      Af[i][1] = *(const short8*)&Ab[i * 1024 + csw1];
    }
    #pragma unroll
    for (int j = 0; j < 2; ++j) {
      Bf0[j][0] = *(const short8*)&Bb[j * 1024 + csw0];
      Bf0[j][1] = *(const short8*)&Bb[j * 1024 + csw1];
    }
    SBAR();
    __builtin_amdgcn_s_setprio(1);
    #pragma unroll
    for (int i = 0; i < 4; ++i)
      #pragma unroll
      for (int j = 0; j < 2; ++j) {
        MFMA16(Af[i][0], Bf0[j][0], acc[i][j]);
        MFMA16(Af[i][1], Bf0[j][1], acc[i][j]);
      }
    __builtin_amdgcn_s_setprio(0);
    if (t + 1 < T) { VMCNT(6); } else { VMCNT(2); }
    SBAR();
    // ---- q2: quadrant (mh0, nh1); stage Bh(t+1); reads B-highs
    if (t + 1 < T) { STB8(nb, 0, 1, t + 1); STB8(nb, 1, 1, t + 1); }
    #pragma unroll
    for (int j = 0; j < 2; ++j) {
      Bf1[j][0] = *(const short8*)&Bb[2048 + j * 1024 + csw0];
      Bf1[j][1] = *(const short8*)&Bb[2048 + j * 1024 + csw1];
    }
    SBAR();
    __builtin_amdgcn_s_setprio(1);
    #pragma unroll
    for (int i = 0; i < 4; ++i)
      #pragma unroll
      for (int j = 0; j < 2; ++j) {
        MFMA16(Af[i][0], Bf1[j][0], acc[i][2 + j]);
        MFMA16(Af[i][1], Bf1[j][1], acc[i][2 + j]);
      }
    __builtin_amdgcn_s_setprio(0);
    if (t + 1 < T) { VMCNT(6); } else { VMCNT(0); }
    SBAR();
    // ---- q3: quadrant (mh1, nh1); stage Ah(t+1); reads A-highs
    if (t + 1 < T) { STA8(nb, 0, 1, t + 1); STA8(nb, 1, 1, t + 1); }
    #pragma unroll
    for (int i = 0; i < 4; ++i) {
      Af[i][0] = *(const short8*)&Ab[4096 + i * 1024 + csw0];
      Af[i][1] = *(const short8*)&Ab[4096 + i * 1024 + csw1];
    }
    SBAR();
    __builtin_amdgcn_s_setprio(1);
    #pragma unroll
    for (int i = 0; i < 4; ++i)
      #pragma unroll
      for (int j = 0; j < 2; ++j) {
        MFMA16(Af[i][0], Bf1[j][0], acc[4 + i][2 + j]);
        MFMA16(Af[i][1], Bf1[j][1], acc[4 + i][2 + j]);
      }
    __builtin_amdgcn_s_setprio(0);
    if (t + 1 < T) { VMCNT(6); } else { VMCNT(0); }
    SBAR();
    // ---- q4: quadrant (mh1, nh0); stage Al(t+2) into cur buf; register-only MFMA
    if (t + 2 < T) { STA8(buf, 0, 0, t + 2); STA8(buf, 1, 0, t + 2); }
    __builtin_amdgcn_s_setprio(1);
    #pragma unroll
    for (int i = 0; i < 4; ++i)
      #pragma unroll
      for (int j = 0; j < 2; ++j) {
        MFMA16(Af[i][0], Bf0[j][0], acc[4 + i][j]);
        MFMA16(Af[i][1], Bf0[j][1], acc[4 + i][j]);
      }
    __builtin_amdgcn_s_setprio(0);
    if (t + 2 < T) { VMCNT(6); } else if (t + 1 < T) { VMCNT(4); } else { VMCNT(0); }
    SBAR();
    __builtin_amdgcn_sched_barrier(0);
  }
  #undef STA8
  #undef STB8
}

// ---------------- GEMM1 main (cols 0..2047): 8-phase 256x256 ----------------
__global__ __launch_bounds__(512, 2) void guv8_kernel(
    const short* __restrict__ xn, const short* __restrict__ W_uvT,
    const float* __restrict__ b_uv,
    short* __restrict__ u_out, short* __restrict__ vT_out)
{
  extern __shared__ __align__(16) short sm[];
  const size_t m0 = (size_t)blockIdx.x * 256;
  const size_t n0 = (size_t)blockIdx.y * 256;
  const int tid = threadIdx.x, w = tid >> 6, l = tid & 63;
  const int lr = l & 15;
  f32x4 acc[8][4];
  core8<DIMD, DIMD / 64>(xn, W_uvT, m0, n0, tid, sm, acc);
  const int rowb0 = (int)m0 + (w >> 2) * 128 + (l >> 4) * 4;
  const int colb0 = (int)n0 + (w & 3) * 64 + lr;
  if (n0 < 1024) {
    #pragma unroll
    for (int mf = 0; mf < 8; ++mf) {
      #pragma unroll
      for (int nf = 0; nf < 4; ++nf) {
        int col = colb0 + nf * 16;
        float bias = b_uv[col];
        #pragma unroll
        for (int r = 0; r < 4; ++r)
          u_out[(size_t)(rowb0 + mf * 16 + r) * EE + col] = f2bf(silu_f(acc[mf][nf][r] + bias));
      }
    }
  } else {
    #pragma unroll
    for (int mf = 0; mf < 8; ++mf) {
      int row = rowb0 + mf * 16;
      int bb = row >> 12, lb = row & (LLL - 1);
      #pragma unroll
      for (int nf = 0; nf < 4; ++nf) {
        int e = colb0 + nf * 16 - 1024;
        float bias = b_uv[e + 1024];
        short4 o;
        o.x = f2bf(silu_f(acc[mf][nf][0] + bias));
        o.y = f2bf(silu_f(acc[mf][nf][1] + bias));
        o.z = f2bf(silu_f(acc[mf][nf][2] + bias));
        o.w = f2bf(silu_f(acc[mf][nf][3] + bias));
        *(short4*)&vT_out[((size_t)bb * EE + e) * LLL + lb] = o;
      }
    }
  }
}

// ---------------- GEMM1 strip (cols 2048..2175 -> q,k); q pre-scaled by 1/sqrt(S) ----------------
__global__ __launch_bounds__(256) void qkstrip_kernel(
    const short* __restrict__ xn, const short* __restrict__ Wqk,
    const float* __restrict__ b_uv, const float* __restrict__ gamma, const float* __restrict__ beta,
    short* __restrict__ q_out, short* __restrict__ k_out)
{
  __shared__ __align__(16) short sm[8192];
  int tid = threadIdx.x;
  size_t m0 = (size_t)blockIdx.x * 128;
  f32x4 acc[4][4];
  gemm_core(xn, Wqk, DIMD, DIMD, DIMD, m0, 0, tid, sm, acc);
  int wid = tid >> 6, lane = tid & 63;
  int wr = (wid >> 1) * 64, wc = (wid & 1) * 64;
  int lr = lane & 15;
  const float scale = 0.08838834764831845f;
  #pragma unroll
  for (int m = 0; m < 4; m++) {
    #pragma unroll
    for (int n = 0; n < 4; n++) {
      int s = wc + n * 16 + lr;
      float bias = b_uv[2048 + s];
      float g0 = gamma[s] * scale, g1 = gamma[SSS + s];
      float be0 = beta[s] * scale, be1 = beta[SSS + s];
      int rowb = (int)m0 + wr + m * 16 + (lane >> 4) * 4;
      #pragma unroll
      for (int r = 0; r < 4; r++) {
        float val = acc[m][n][r] + bias;
        q_out[(size_t)(rowb + r) * SSS + s] = f2bf(val * g0 + be0);
        k_out[(size_t)(rowb + r) * SSS + s] = f2bf(val * g1 + be1);
      }
    }
  }
}

// ---------------- QK (q pre-scaled; row-major P): m97 core ----------------
__global__ __launch_bounds__(256) void gqk_kernel(
    const short* __restrict__ q, const short* __restrict__ k, short* __restrict__ P,
    long sq, long sk, long sp)
{
  __shared__ __align__(16) short sm[8192];
  int tid = threadIdx.x;
  const short* qz = q + (size_t)blockIdx.z * sq;
  const short* kz = k + (size_t)blockIdx.z * sk;
  short* Pz = P + (size_t)blockIdx.z * sp;
  size_t m0 = (size_t)blockIdx.x * 128, n0 = (size_t)blockIdx.y * 128;
  f32x4 acc[4][4];
  gemm_core(qz, kz, SSS, SSS, SSS, m0, n0, tid, sm, acc);
  int wid = tid >> 6, lane = tid & 63;
  int wr = (wid >> 1) * 64, wc = (wid & 1) * 64;
  int lr = lane & 15;
  #pragma unroll
  for (int m = 0; m < 4; m++) {
    #pragma unroll
    for (int n = 0; n < 4; n++) {
      int col = (int)n0 + wc + n * 16 + lr;
      int rowb = (int)m0 + wr + m * 16 + (lane >> 4) * 4;
      #pragma unroll
      for (int r = 0; r < 4; r++) {
        float v = fmaxf(acc[m][n][r], 0.f);
        Pz[(size_t)(rowb + r) * LLL + col] = f2bf(v * v);
      }
    }
  }
}

// ---------------- legacy PV (fallback tiers): m97 core, row-major P ----------------
__global__ __launch_bounds__(256) void gpv_kernel(
    const short* __restrict__ P, const short* __restrict__ vT,
    const short* __restrict__ u, short* __restrict__ g,
    long sp, long sv, long su)
{
  __shared__ __align__(16) short sm[8192];
  int tid = threadIdx.x;
  const short* Pz = P + (size_t)blockIdx.z * sp;
  const short* vz = vT + (size_t)blockIdx.z * sv;
  const short* uz = u + (size_t)blockIdx.z * su;
  short* gz = g + (size_t)blockIdx.z * su;
  size_t m0 = (size_t)blockIdx.x * 128, n0 = (size_t)blockIdx.y * 128;
  f32x4 acc[4][4];
  gemm_core(Pz, vz, LLL, LLL, LLL, m0, n0, tid, sm, acc);
  int wid = tid >> 6, lane = tid & 63;
  int wr = (wid >> 1) * 64, wc = (wid & 1) * 64;
  int lr = lane & 15;
  #pragma unroll
  for (int m = 0; m < 4; m++) {
    #pragma unroll
    for (int n = 0; n < 4; n++) {
      int col = (int)n0 + wc + n * 16 + lr;
      int rowb = (int)m0 + wr + m * 16 + (lane >> 4) * 4;
      #pragma unroll
      for (int r = 0; r < 4; r++) {
        size_t idx = (size_t)(rowb + r) * EE + col;
        gz[idx] = f2bf(bf2f(uz[idx]) * acc[m][n][r]);
      }
    }
  }
}

// ---------------- PV, 256x256 (core8 R5 schedule) ----------------
__global__ __launch_bounds__(512, 2) void gpv8_kernel(
    const short* __restrict__ Pg, const short* __restrict__ vTg,
    const short* __restrict__ ug, short* __restrict__ gg)
{
  extern __shared__ __align__(16) short sm[];
  const int b = blockIdx.z;
  const size_t m0 = (size_t)blockIdx.x * 256;
  const size_t n0 = (size_t)blockIdx.y * 256;
  const short* A  = Pg  + (size_t)b * LLL * LLL;
  const short* Bv = vTg + (size_t)b * EE * LLL;
  const int tid = threadIdx.x, w = tid >> 6, l = tid & 63;
  const int lr = l & 15;
  f32x4 acc[8][4];
  core8<LLL, LLL / 64>(A, Bv, m0, n0, tid, sm, acc);
  const short* ub_ = ug + (size_t)b * LLL * EE;
  short* gb_ = gg + (size_t)b * LLL * EE;
  const int rowb0 = (int)m0 + (w >> 2) * 128 + (l >> 4) * 4;
  const int colb0 = (int)n0 + (w & 3) * 64 + lr;
  #pragma unroll
  for (int mf = 0; mf < 8; ++mf) {
    #pragma unroll
    for (int nf = 0; nf < 4; ++nf) {
      int col = colb0 + nf * 16;
      #pragma unroll
      for (int r = 0; r < 4; ++r) {
        size_t idx = (size_t)(rowb0 + mf * 16 + r) * EE + col;
        gb_[idx] = f2bf(bf2f(ub_[idx]) * acc[mf][nf][r]);
      }
    }
  }
}

// ---------------- GEMM2 legacy (m97, 512 blocks): g x W_outT + bias + residual ----------------
__global__ __launch_bounds__(256) void gout_kernel(
    const short* __restrict__ A, const short* __restrict__ Bw,
    const float* __restrict__ b_out, const float* __restrict__ x,
    float* __restrict__ out)
{
  __shared__ __align__(16) short sm[8192];
  int tid = threadIdx.x;
  size_t m0 = (size_t)blockIdx.x * 128, n0 = (size_t)blockIdx.y * 128;
  f32x4 acc[4][4];
  gemm_core(A, Bw, EE, EE, EE, m0, n0, tid, sm, acc);
  int wid = tid >> 6, lane = tid & 63;
  int wr = (wid >> 1) * 64, wc = (wid & 1) * 64;
  int lr = lane & 15;
  #pragma unroll
  for (int m = 0; m < 4; m++) {
    #pragma unroll
    for (int n = 0; n < 4; n++) {
      int col = (int)n0 + wc + n * 16 + lr;
      float bias = b_out[col];
      int rowb = (int)m0 + wr + m * 16 + (lane >> 4) * 4;
      #pragma unroll
      for (int r = 0; r < 4; r++) {
        size_t idx = (size_t)(rowb + r) * DIMD + col;
        out[idx] = acc[m][n][r] + bias + x[idx];
      }
    }
  }
}

extern "C" void kernel_launch(void* const* d_in, const int* in_sizes, int n_in,
                              void* d_out, int out_size, void* d_ws, size_t ws_size,
                              hipStream_t stream) {
  const float* x     = (const float*)d_in[0];
  const float* W_uv  = (const float*)d_in[1];
  const float* b_uv  = (const float*)d_in[2];
  const float* gamma = (const float*)d_in[3];
  const float* beta  = (const float*)d_in[4];
  const float* W_out = (const float*)d_in[5];
  const float* b_out = (const float*)d_in[6];
  const float* ln_w  = (const float*)d_in[7];
  const float* ln_b  = (const float*)d_in[8];
  float* out = (float*)d_out;

  char* ws = (char*)d_ws;
  short* W_uvT  = (short*)(ws);
  short* W_outT = (short*)(ws + 2228224);
  short* xn     = (short*)(ws + 3276800);
  short* qb     = (short*)(ws + 20054016);
  short* kb     = (short*)(ws + 24248320);
  short* ub     = (short*)(ws + 28442624);
  short* vTb    = (short*)(ws + 61997056);
  short* gb     = (short*)(ws + 95551488);
  short* Pb     = (short*)(ws + 129105920);

  prepln_kernel<<<dim3(NROW + (NUV * DIMD + 255) / 256), 256, 0, stream>>>(
      x, ln_w, ln_b, xn, W_uv, W_out, W_uvT, W_outT);
  guv8_kernel<<<dim3(NROW / 256, 8), 512, 131072, stream>>>(xn, W_uvT, b_uv, ub, vTb);
  qkstrip_kernel<<<dim3(NROW / 128), 256, 0, stream>>>(xn, W_uvT + (size_t)2048 * DIMD, b_uv, gamma, beta, qb, kb);

  const long SQ = (long)LLL * SSS;
  const long SP = (long)LLL * LLL;
  const long SV = (long)EE * LLL;
  const long SU = (long)LLL * EE;

  if (ws_size >= 129105920ull + 134217728ull) {
    gqk_kernel<<<dim3(32, 32, 4), 256, 0, stream>>>(qb, kb, Pb, SQ, SQ, SP);
    gpv8_kernel<<<dim3(16, 4, 4), 512, 131072, stream>>>(Pb, vTb, ub, gb);
  } else if (ws_size >= 129105920ull + 33554432ull) {
    for (int b = 0; b < 4; b++) {
      gqk_kernel<<<dim3(32, 32, 1), 256, 0, stream>>>(qb + (size_t)b * SQ, kb + (size_t)b * SQ, Pb, 0, 0, 0);
      gpv_kernel<<<dim3(32, 8, 1), 256, 0, stream>>>(Pb, vTb + (size_t)b * SV, ub + (size_t)b * SU, gb + (size_t)b * SU, 0, 0, 0);
    }
  } else {
    short* Pc = xn;
    for (int b = 0; b < 4; b++) {
      for (int h = 0; h < 2; h++) {
        size_t rowoff = (size_t)b * LLL + (size_t)h * 2048;
        gqk_kernel<<<dim3(16, 32, 1), 256, 0, stream>>>(qb + rowoff * SSS, kb + (size_t)b * SQ, Pc, 0, 0, 0);
        gpv_kernel<<<dim3(16, 8, 1), 256, 0, stream>>>(Pc, vTb + (size_t)b * SV, ub + rowoff * EE, gb + rowoff * EE, 0, 0, 0);
      }
    }
  }

  gout_kernel<<<dim3(NROW / 128, DIMD / 128), 256, 0, stream>>>(gb, W_outT, b_out, x, out);
}

// Round 12
// 276.128 us; speedup vs baseline: 1.1599x; 1.0174x over previous
//
#include <hip/hip_runtime.h>

typedef __attribute__((ext_vector_type(8))) short short8;
typedef __attribute__((ext_vector_type(4))) float f32x4;

#define DIMD 512
#define EE 1024
#define SSS 128
#define LLL 4096
#define NROW 16384   // B*L
#define NUV 2176     // 2E+S

__device__ __forceinline__ short f2bf(float f) {
  union { float f; unsigned u; } un; un.f = f;
  unsigned r = un.u + 0x7FFFu + ((un.u >> 16) & 1u);
  return (short)(r >> 16);
}
__device__ __forceinline__ float bf2f(short s) {
  union { unsigned u; float f; } un;
  un.u = ((unsigned)(unsigned short)s) << 16;
  return un.f;
}
__device__ __forceinline__ float silu_f(float x) {
  return x / (1.0f + __expf(-x));
}

__device__ __forceinline__ void gld16(const short* g, short* l) {
  __builtin_amdgcn_global_load_lds(
      (const __attribute__((address_space(1))) unsigned int*)g,
      (__attribute__((address_space(3))) unsigned int*)l, 16, 0, 0);
}

#define MFMA16(a, b, c) c = __builtin_amdgcn_mfma_f32_16x16x32_bf16(a, b, c, 0, 0, 0)
#define SBAR() asm volatile("s_barrier" ::: "memory")
#define VMCNT(n) asm volatile("s_waitcnt vmcnt(" #n ")" ::: "memory")

// ---------------- fused prep+layernorm ----------------
// blocks [0, NROW): layernorm row.
// blocks [NROW, NROW+272): W_uv 64x64 transpose tiles (8 x 34).
// blocks [NROW+272, NROW+400): W_out 64x64 transpose tiles (16 x 8).
__global__ __launch_bounds__(256) void prepln_kernel(
    const float* __restrict__ x, const float* __restrict__ w, const float* __restrict__ bb,
    short* __restrict__ xn,
    const float* __restrict__ W_uv, const float* __restrict__ W_out,
    short* __restrict__ W_uvT, short* __restrict__ W_outT) {
  int tid = threadIdx.x;
  int bx = blockIdx.x;
  if (bx >= NROW) {
    __shared__ float tile[64][65];
    int wb = bx - NROW;
    const float* src; short* dst; int s0, c0, ldS, ldD;
    if (wb < 272) {            // W_uv [512][2176] -> W_uvT [2176][512]
      int dt = wb / 34, ct = wb - dt * 34;
      s0 = dt * 64; c0 = ct * 64; ldS = NUV; ldD = DIMD;
      src = W_uv; dst = W_uvT;
    } else {                   // W_out [1024][512] -> W_outT [512][1024]
      int wb2 = wb - 272;
      int et = wb2 >> 3, dt = wb2 & 7;
      s0 = et * 64; c0 = dt * 64; ldS = DIMD; ldD = EE;
      src = W_out; dst = W_outT;
    }
    int r0 = tid >> 6, c = tid & 63;
    #pragma unroll
    for (int rr = 0; rr < 16; ++rr) {
      int row = rr * 4 + r0;
      tile[row][c] = src[(size_t)(s0 + row) * ldS + c0 + c];
    }
    __syncthreads();
    #pragma unroll
    for (int rr = 0; rr < 16; ++rr) {
      int row = rr * 4 + r0;
      dst[(size_t)(c0 + row) * ldD + s0 + c] = f2bf(tile[c][row]);
    }
    return;
  }
  int row = bx;
  const float2* xr = (const float2*)(x + (size_t)row * DIMD);
  float2 v = xr[tid];
  float s = v.x + v.y, ss = v.x * v.x + v.y * v.y;
  #pragma unroll
  for (int off = 32; off >= 1; off >>= 1) {
    s += __shfl_down(s, off);
    ss += __shfl_down(ss, off);
  }
  __shared__ float ps[8];
  if ((tid & 63) == 0) { ps[tid >> 6] = s; ps[4 + (tid >> 6)] = ss; }
  __syncthreads();
  s = ps[0] + ps[1] + ps[2] + ps[3];
  ss = ps[4] + ps[5] + ps[6] + ps[7];
  float mu = s * (1.0f / DIMD);
  float var = ss * (1.0f / DIMD) - mu * mu;
  float inv = rsqrtf(var + 1e-5f);
  float2 wv = ((const float2*)w)[tid];
  float2 bv = ((const float2*)bb)[tid];
  short2 o;
  o.x = f2bf((v.x - mu) * inv * wv.x + bv.x);
  o.y = f2bf((v.y - mu) * inv * wv.y + bv.y);
  *(short2*)&xn[(size_t)row * DIMD + tid * 2] = o;
}

// ---------------- m97-style GEMM core: 128x128 tile, 4 waves, BK=32 ----------------
// Dual-side XOR swizzle (16B granule over 2 row bits): staging source col
// slot' = slot ^ (row&3); read slot' = (lane>>4) ^ (lane&3). 8-way -> 4-way.
__device__ __forceinline__ void gemm_core(const short* __restrict__ A, const short* __restrict__ B,
                                          int lda, int ldb, int K, size_t m0, size_t n0,
                                          int tid, short* sm, f32x4 acc[4][4]) {
  short* As = sm;
  short* Bs = sm + 4096;
  int wid = tid >> 6, lane = tid & 63;
  int wr = (wid >> 1) * 64, wc = (wid & 1) * 64;
  int lr = lane & 15;
  int lk = ((lane >> 4) ^ (lane & 3)) * 8;               // swizzled read slot
  int r0 = tid >> 2;
  int c0 = (((tid & 3) ^ ((tid >> 2) & 3)) & 3) * 8;     // swizzled source slot
  #pragma unroll
  for (int m = 0; m < 4; m++)
    #pragma unroll
    for (int n = 0; n < 4; n++) acc[m][n] = (f32x4){0.f, 0.f, 0.f, 0.f};
  for (int k0 = 0; k0 < K; k0 += 32) {
    gld16(&A[(m0 + r0) * lda + k0 + c0],      &As[wid * 512]);
    gld16(&A[(m0 + 64 + r0) * lda + k0 + c0], &As[2048 + wid * 512]);
    gld16(&B[(n0 + r0) * ldb + k0 + c0],      &Bs[wid * 512]);
    gld16(&B[(n0 + 64 + r0) * ldb + k0 + c0], &Bs[2048 + wid * 512]);
    __syncthreads();
    short8 af[4], bf[4];
    #pragma unroll
    for (int m = 0; m < 4; m++) af[m] = *(short8*)&As[(wr + m * 16 + lr) * 32 + lk];
    #pragma unroll
    for (int n = 0; n < 4; n++) bf[n] = *(short8*)&Bs[(wc + n * 16 + lr) * 32 + lk];
    #pragma unroll
    for (int m = 0; m < 4; m++)
      #pragma unroll
      for (int n = 0; n < 4; n++)
        MFMA16(af[m], bf[n], acc[m][n]);
    __syncthreads();
  }
}

// ============ 256x256 8-phase pipelined GEMM core — R5 schedule (best: 126.5us) ============
template<int LD, int T>
__device__ __forceinline__ void core8(const short* __restrict__ A, const short* __restrict__ Bv,
                                      size_t m0, size_t n0, int tid, short* sm,
                                      f32x4 (&acc)[8][4]) {
  const int w = tid >> 6, l = tid & 63;
  const int lr = l & 15;
  const int colsrc = ((l & 7) * 8) ^ ((l >> 3) << 3);
  const short* srcA = A  + (m0 + w * 8 + (l >> 3)) * (size_t)LD + colsrc;
  const short* srcB = Bv + (n0 + w * 8 + (l >> 3)) * (size_t)LD + colsrc;
  const int csw0 = ((l >> 4) * 8) ^ ((l & 7) << 3);
  const int csw1 = (32 + (l >> 4) * 8) ^ ((l & 7) << 3);
  const int AhalfOff = (w >> 2) * 8192 + lr * 64;
  const int BhalfOff = 16384 + ((w & 3) >> 1) * 8192 + ((w & 1) * 64 + lr) * 64;

  #define STA8(bf_, h_, q_, kt_) gld16(srcA + ((h_) * 128 + (q_) * 64) * (size_t)LD + (kt_) * 64, \
                                       &sm[(bf_) * 32768 + (h_) * 8192 + (q_) * 4096 + w * 512])
  #define STB8(bf_, h_, q_, kt_) gld16(srcB + ((h_) * 128 + (q_) * 64) * (size_t)LD + (kt_) * 64, \
                                       &sm[(bf_) * 32768 + 16384 + (h_) * 8192 + (q_) * 4096 + w * 512])

  #pragma unroll
  for (int m = 0; m < 8; m++)
    #pragma unroll
    for (int n = 0; n < 4; n++) acc[m][n] = (f32x4){0.f, 0.f, 0.f, 0.f};
  short8 Af[4][2], Bf0[2][2], Bf1[2][2];

  // prologue: tile0 all 8 units, then tile1 A-lows (kept in flight)
  STA8(0, 0, 0, 0); STA8(0, 1, 0, 0);
  STB8(0, 0, 0, 0); STB8(0, 1, 0, 0);
  STB8(0, 0, 1, 0); STB8(0, 1, 1, 0);
  STA8(0, 0, 1, 0); STA8(0, 1, 1, 0);
  STA8(1, 0, 0, 1); STA8(1, 1, 0, 1);
  VMCNT(2);
  SBAR();
  __builtin_amdgcn_sched_barrier(0);

  for (int t = 0; t < T; ++t) {
    const int buf = t & 1, nb = buf ^ 1;
    short* Ab = sm + buf * 32768 + AhalfOff;
    short* Bb = sm + buf * 32768 + BhalfOff;
    // q1: (mh0,nh0); stage Bl(t+1)
    if (t + 1 < T) { STB8(nb, 0, 0, t + 1); STB8(nb, 1, 0, t + 1); }
    #pragma unroll
    for (int i = 0; i < 4; ++i) {
      Af[i][0] = *(const short8*)&Ab[i * 1024 + csw0];
      Af[i][1] = *(const short8*)&Ab[i * 1024 + csw1];
    }
    #pragma unroll
    for (int j = 0; j < 2; ++j) {
      Bf0[j][0] = *(const short8*)&Bb[j * 1024 + csw0];
      Bf0[j][1] = *(const short8*)&Bb[j * 1024 + csw1];
    }
    SBAR();
    __builtin_amdgcn_s_setprio(1);
    #pragma unroll
    for (int i = 0; i < 4; ++i)
      #pragma unroll
      for (int j = 0; j < 2; ++j) {
        MFMA16(Af[i][0], Bf0[j][0], acc[i][j]);
        MFMA16(Af[i][1], Bf0[j][1], acc[i][j]);
      }
    __builtin_amdgcn_s_setprio(0);
    if (t + 1 < T) { VMCNT(6); } else { VMCNT(2); }
    SBAR();
    // q2: (mh0,nh1); stage Bh(t+1)
    if (t + 1 < T) { STB8(nb, 0, 1, t + 1); STB8(nb, 1, 1, t + 1); }
    #pragma unroll
    for (int j = 0; j < 2; ++j) {
      Bf1[j][0] = *(const short8*)&Bb[2048 + j * 1024 + csw0];
      Bf1[j][1] = *(const short8*)&Bb[2048 + j * 1024 + csw1];
    }
    SBAR();
    __builtin_amdgcn_s_setprio(1);
    #pragma unroll
    for (int i = 0; i < 4; ++i)
      #pragma unroll
      for (int j = 0; j < 2; ++j) {
        MFMA16(Af[i][0], Bf1[j][0], acc[i][2 + j]);
        MFMA16(Af[i][1], Bf1[j][1], acc[i][2 + j]);
      }
    __builtin_amdgcn_s_setprio(0);
    if (t + 1 < T) { VMCNT(6); } else { VMCNT(0); }
    SBAR();
    // q3: (mh1,nh1); stage Ah(t+1)
    if (t + 1 < T) { STA8(nb, 0, 1, t + 1); STA8(nb, 1, 1, t + 1); }
    #pragma unroll
    for (int i = 0; i < 4; ++i) {
      Af[i][0] = *(const short8*)&Ab[4096 + i * 1024 + csw0];
      Af[i][1] = *(const short8*)&Ab[4096 + i * 1024 + csw1];
    }
    SBAR();
    __builtin_amdgcn_s_setprio(1);
    #pragma unroll
    for (int i = 0; i < 4; ++i)
      #pragma unroll
      for (int j = 0; j < 2; ++j) {
        MFMA16(Af[i][0], Bf1[j][0], acc[4 + i][2 + j]);
        MFMA16(Af[i][1], Bf1[j][1], acc[4 + i][2 + j]);
      }
    __builtin_amdgcn_s_setprio(0);
    if (t + 1 < T) { VMCNT(6); } else { VMCNT(0); }
    SBAR();
    // q4: (mh1,nh0); stage Al(t+2) into cur buf
    if (t + 2 < T) { STA8(buf, 0, 0, t + 2); STA8(buf, 1, 0, t + 2); }
    __builtin_amdgcn_s_setprio(1);
    #pragma unroll
    for (int i = 0; i < 4; ++i)
      #pragma unroll
      for (int j = 0; j < 2; ++j) {
        MFMA16(Af[i][0], Bf0[j][0], acc[4 + i][j]);
        MFMA16(Af[i][1], Bf0[j][1], acc[4 + i][j]);
      }
    __builtin_amdgcn_s_setprio(0);
    if (t + 2 < T) { VMCNT(6); } else if (t + 1 < T) { VMCNT(4); } else { VMCNT(0); }
    SBAR();
    __builtin_amdgcn_sched_barrier(0);
  }
  #undef STA8
  #undef STB8
}

// ---------------- GEMM1 main (cols 0..2047): 8-phase 256x256 ----------------
__global__ __launch_bounds__(512, 2) void guv8_kernel(
    const short* __restrict__ xn, const short* __restrict__ W_uvT,
    const float* __restrict__ b_uv,
    short* __restrict__ u_out, short* __restrict__ vT_out)
{
  extern __shared__ __align__(16) short sm[];
  const size_t m0 = (size_t)blockIdx.x * 256;
  const size_t n0 = (size_t)blockIdx.y * 256;
  const int tid = threadIdx.x, w = tid >> 6, l = tid & 63;
  const int lr = l & 15;
  f32x4 acc[8][4];
  core8<DIMD, DIMD / 64>(xn, W_uvT, m0, n0, tid, sm, acc);
  const int rowb0 = (int)m0 + (w >> 2) * 128 + (l >> 4) * 4;
  const int colb0 = (int)n0 + (w & 3) * 64 + lr;
  if (n0 < 1024) {
    #pragma unroll
    for (int mf = 0; mf < 8; ++mf) {
      #pragma unroll
      for (int nf = 0; nf < 4; ++nf) {
        int col = colb0 + nf * 16;
        float bias = b_uv[col];
        #pragma unroll
        for (int r = 0; r < 4; ++r)
          u_out[(size_t)(rowb0 + mf * 16 + r) * EE + col] = f2bf(silu_f(acc[mf][nf][r] + bias));
      }
    }
  } else {
    #pragma unroll
    for (int mf = 0; mf < 8; ++mf) {
      int row = rowb0 + mf * 16;
      int bb = row >> 12, lb = row & (LLL - 1);
      #pragma unroll
      for (int nf = 0; nf < 4; ++nf) {
        int e = colb0 + nf * 16 - 1024;
        float bias = b_uv[e + 1024];
        short4 o;
        o.x = f2bf(silu_f(acc[mf][nf][0] + bias));
        o.y = f2bf(silu_f(acc[mf][nf][1] + bias));
        o.z = f2bf(silu_f(acc[mf][nf][2] + bias));
        o.w = f2bf(silu_f(acc[mf][nf][3] + bias));
        *(short4*)&vT_out[((size_t)bb * EE + e) * LLL + lb] = o;
      }
    }
  }
}

// ---------------- GEMM1 strip (cols 2048..2175 -> q,k); q pre-scaled by 1/sqrt(S) ----------------
__global__ __launch_bounds__(256) void qkstrip_kernel(
    const short* __restrict__ xn, const short* __restrict__ Wqk,
    const float* __restrict__ b_uv, const float* __restrict__ gamma, const float* __restrict__ beta,
    short* __restrict__ q_out, short* __restrict__ k_out)
{
  __shared__ __align__(16) short sm[8192];
  int tid = threadIdx.x;
  size_t m0 = (size_t)blockIdx.x * 128;
  f32x4 acc[4][4];
  gemm_core(xn, Wqk, DIMD, DIMD, DIMD, m0, 0, tid, sm, acc);
  int wid = tid >> 6, lane = tid & 63;
  int wr = (wid >> 1) * 64, wc = (wid & 1) * 64;
  int lr = lane & 15;
  const float scale = 0.08838834764831845f;
  #pragma unroll
  for (int m = 0; m < 4; m++) {
    #pragma unroll
    for (int n = 0; n < 4; n++) {
      int s = wc + n * 16 + lr;
      float bias = b_uv[2048 + s];
      float g0 = gamma[s] * scale, g1 = gamma[SSS + s];
      float be0 = beta[s] * scale, be1 = beta[SSS + s];
      int rowb = (int)m0 + wr + m * 16 + (lane >> 4) * 4;
      #pragma unroll
      for (int r = 0; r < 4; r++) {
        float val = acc[m][n][r] + bias;
        q_out[(size_t)(rowb + r) * SSS + s] = f2bf(val * g0 + be0);
        k_out[(size_t)(rowb + r) * SSS + s] = f2bf(val * g1 + be1);
      }
    }
  }
}

// ---------------- QK (q pre-scaled; row-major P): m97 core ----------------
__global__ __launch_bounds__(256) void gqk_kernel(
    const short* __restrict__ q, const short* __restrict__ k, short* __restrict__ P,
    long sq, long sk, long sp)
{
  __shared__ __align__(16) short sm[8192];
  int tid = threadIdx.x;
  const short* qz = q + (size_t)blockIdx.z * sq;
  const short* kz = k + (size_t)blockIdx.z * sk;
  short* Pz = P + (size_t)blockIdx.z * sp;
  size_t m0 = (size_t)blockIdx.x * 128, n0 = (size_t)blockIdx.y * 128;
  f32x4 acc[4][4];
  gemm_core(qz, kz, SSS, SSS, SSS, m0, n0, tid, sm, acc);
  int wid = tid >> 6, lane = tid & 63;
  int wr = (wid >> 1) * 64, wc = (wid & 1) * 64;
  int lr = lane & 15;
  #pragma unroll
  for (int m = 0; m < 4; m++) {
    #pragma unroll
    for (int n = 0; n < 4; n++) {
      int col = (int)n0 + wc + n * 16 + lr;
      int rowb = (int)m0 + wr + m * 16 + (lane >> 4) * 4;
      #pragma unroll
      for (int r = 0; r < 4; r++) {
        float v = fmaxf(acc[m][n][r], 0.f);
        Pz[(size_t)(rowb + r) * LLL + col] = f2bf(v * v);
      }
    }
  }
}

// ---------------- legacy PV (fallback tiers): m97 core, row-major P ----------------
__global__ __launch_bounds__(256) void gpv_kernel(
    const short* __restrict__ P, const short* __restrict__ vT,
    const short* __restrict__ u, short* __restrict__ g,
    long sp, long sv, long su)
{
  __shared__ __align__(16) short sm[8192];
  int tid = threadIdx.x;
  const short* Pz = P + (size_t)blockIdx.z * sp;
  const short* vz = vT + (size_t)blockIdx.z * sv;
  const short* uz = u + (size_t)blockIdx.z * su;
  short* gz = g + (size_t)blockIdx.z * su;
  size_t m0 = (size_t)blockIdx.x * 128, n0 = (size_t)blockIdx.y * 128;
  f32x4 acc[4][4];
  gemm_core(Pz, vz, LLL, LLL, LLL, m0, n0, tid, sm, acc);
  int wid = tid >> 6, lane = tid & 63;
  int wr = (wid >> 1) * 64, wc = (wid & 1) * 64;
  int lr = lane & 15;
  #pragma unroll
  for (int m = 0; m < 4; m++) {
    #pragma unroll
    for (int n = 0; n < 4; n++) {
      int col = (int)n0 + wc + n * 16 + lr;
      int rowb = (int)m0 + wr + m * 16 + (lane >> 4) * 4;
      #pragma unroll
      for (int r = 0; r < 4; r++) {
        size_t idx = (size_t)(rowb + r) * EE + col;
        gz[idx] = f2bf(bf2f(uz[idx]) * acc[m][n][r]);
      }
    }
  }
}

// ---------------- PV, 256x256 (core8 R5 schedule) ----------------
__global__ __launch_bounds__(512, 2) void gpv8_kernel(
    const short* __restrict__ Pg, const short* __restrict__ vTg,
    const short* __restrict__ ug, short* __restrict__ gg)
{
  extern __shared__ __align__(16) short sm[];
  const int b = blockIdx.z;
  const size_t m0 = (size_t)blockIdx.x * 256;
  const size_t n0 = (size_t)blockIdx.y * 256;
  const short* A  = Pg  + (size_t)b * LLL * LLL;
  const short* Bv = vTg + (size_t)b * EE * LLL;
  const int tid = threadIdx.x, w = tid >> 6, l = tid & 63;
  const int lr = l & 15;
  f32x4 acc[8][4];
  core8<LLL, LLL / 64>(A, Bv, m0, n0, tid, sm, acc);
  const short* ub_ = ug + (size_t)b * LLL * EE;
  short* gb_ = gg + (size_t)b * LLL * EE;
  const int rowb0 = (int)m0 + (w >> 2) * 128 + (l >> 4) * 4;
  const int colb0 = (int)n0 + (w & 3) * 64 + lr;
  #pragma unroll
  for (int mf = 0; mf < 8; ++mf) {
    #pragma unroll
    for (int nf = 0; nf < 4; ++nf) {
      int col = colb0 + nf * 16;
      #pragma unroll
      for (int r = 0; r < 4; ++r) {
        size_t idx = (size_t)(rowb0 + mf * 16 + r) * EE + col;
        gb_[idx] = f2bf(bf2f(ub_[idx]) * acc[mf][nf][r]);
      }
    }
  }
}

// ---------------- GEMM2 (m97, 512 blocks): g x W_outT + bias + residual ----------------
__global__ __launch_bounds__(256) void gout_kernel(
    const short* __restrict__ A, const short* __restrict__ Bw,
    const float* __restrict__ b_out, const float* __restrict__ x,
    float* __restrict__ out)
{
  __shared__ __align__(16) short sm[8192];
  int tid = threadIdx.x;
  size_t m0 = (size_t)blockIdx.x * 128, n0 = (size_t)blockIdx.y * 128;
  f32x4 acc[4][4];
  gemm_core(A, Bw, EE, EE, EE, m0, n0, tid, sm, acc);
  int wid = tid >> 6, lane = tid & 63;
  int wr = (wid >> 1) * 64, wc = (wid & 1) * 64;
  int lr = lane & 15;
  #pragma unroll
  for (int m = 0; m < 4; m++) {
    #pragma unroll
    for (int n = 0; n < 4; n++) {
      int col = (int)n0 + wc + n * 16 + lr;
      float bias = b_out[col];
      int rowb = (int)m0 + wr + m * 16 + (lane >> 4) * 4;
      #pragma unroll
      for (int r = 0; r < 4; r++) {
        size_t idx = (size_t)(rowb + r) * DIMD + col;
        out[idx] = acc[m][n][r] + bias + x[idx];
      }
    }
  }
}

extern "C" void kernel_launch(void* const* d_in, const int* in_sizes, int n_in,
                              void* d_out, int out_size, void* d_ws, size_t ws_size,
                              hipStream_t stream) {
  const float* x     = (const float*)d_in[0];
  const float* W_uv  = (const float*)d_in[1];
  const float* b_uv  = (const float*)d_in[2];
  const float* gamma = (const float*)d_in[3];
  const float* beta  = (const float*)d_in[4];
  const float* W_out = (const float*)d_in[5];
  const float* b_out = (const float*)d_in[6];
  const float* ln_w  = (const float*)d_in[7];
  const float* ln_b  = (const float*)d_in[8];
  float* out = (float*)d_out;

  char* ws = (char*)d_ws;
  short* W_uvT  = (short*)(ws);
  short* W_outT = (short*)(ws + 2228224);
  short* xn     = (short*)(ws + 3276800);
  short* qb     = (short*)(ws + 20054016);
  short* kb     = (short*)(ws + 24248320);
  short* ub     = (short*)(ws + 28442624);
  short* vTb    = (short*)(ws + 61997056);
  short* gb     = (short*)(ws + 95551488);
  short* Pb     = (short*)(ws + 129105920);

  prepln_kernel<<<dim3(NROW + 400), 256, 0, stream>>>(
      x, ln_w, ln_b, xn, W_uv, W_out, W_uvT, W_outT);
  guv8_kernel<<<dim3(NROW / 256, 8), 512, 131072, stream>>>(xn, W_uvT, b_uv, ub, vTb);
  qkstrip_kernel<<<dim3(NROW / 128), 256, 0, stream>>>(xn, W_uvT + (size_t)2048 * DIMD, b_uv, gamma, beta, qb, kb);

  const long SQ = (long)LLL * SSS;
  const long SP = (long)LLL * LLL;
  const long SV = (long)EE * LLL;
  const long SU = (long)LLL * EE;

  if (ws_size >= 129105920ull + 134217728ull) {
    gqk_kernel<<<dim3(32, 32, 4), 256, 0, stream>>>(qb, kb, Pb, SQ, SQ, SP);
    gpv8_kernel<<<dim3(16, 4, 4), 512, 131072, stream>>>(Pb, vTb, ub, gb);
  } else if (ws_size >= 129105920ull + 33554432ull) {
    for (int b = 0; b < 4; b++) {
      gqk_kernel<<<dim3(32, 32, 1), 256, 0, stream>>>(qb + (size_t)b * SQ, kb + (size_t)b * SQ, Pb, 0, 0, 0);
      gpv_kernel<<<dim3(32, 8, 1), 256, 0, stream>>>(Pb, vTb + (size_t)b * SV, ub + (size_t)b * SU, gb + (size_t)b * SU, 0, 0, 0);
    }
  } else {
    short* Pc = xn;
    for (int b = 0; b < 4; b++) {
      for (int h = 0; h < 2; h++) {
        size_t rowoff = (size_t)b * LLL + (size_t)h * 2048;
        gqk_kernel<<<dim3(16, 32, 1), 256, 0, stream>>>(qb + rowoff * SSS, kb + (size_t)b * SQ, Pc, 0, 0, 0);
        gpv_kernel<<<dim3(16, 8, 1), 256, 0, stream>>>(Pc, vTb + (size_t)b * SV, ub + rowoff * EE, gb + rowoff * EE, 0, 0, 0);
      }
    }
  }

  gout_kernel<<<dim3(NROW / 128, DIMD / 128), 256, 0, stream>>>(gb, W_outT, b_out, x, out);
}

// Round 13
// 274.996 us; speedup vs baseline: 1.1647x; 1.0041x over previous
//
#include <hip/hip_runtime.h>

typedef __attribute__((ext_vector_type(8))) short short8;
typedef __attribute__((ext_vector_type(4))) float f32x4;

#define DIMD 512
#define EE 1024
#define SSS 128
#define LLL 4096
#define NROW 16384   // B*L
#define NUV 2176     // 2E+S

__device__ __forceinline__ short f2bf(float f) {
  union { float f; unsigned u; } un; un.f = f;
  unsigned r = un.u + 0x7FFFu + ((un.u >> 16) & 1u);
  return (short)(r >> 16);
}
__device__ __forceinline__ float bf2f(short s) {
  union { unsigned u; float f; } un;
  un.u = ((unsigned)(unsigned short)s) << 16;
  return un.f;
}
__device__ __forceinline__ float silu_f(float x) {
  return x / (1.0f + __expf(-x));
}

__device__ __forceinline__ void gld16(const short* g, short* l) {
  __builtin_amdgcn_global_load_lds(
      (const __attribute__((address_space(1))) unsigned int*)g,
      (__attribute__((address_space(3))) unsigned int*)l, 16, 0, 0);
}

#define MFMA16(a, b, c) c = __builtin_amdgcn_mfma_f32_16x16x32_bf16(a, b, c, 0, 0, 0)
#define SBAR() asm volatile("s_barrier" ::: "memory")
#define VMCNT(n) asm volatile("s_waitcnt vmcnt(" #n ")" ::: "memory")

// ---------------- fused prep+layernorm ----------------
__global__ __launch_bounds__(256) void prepln_kernel(
    const float* __restrict__ x, const float* __restrict__ w, const float* __restrict__ bb,
    short* __restrict__ xn,
    const float* __restrict__ W_uv, const float* __restrict__ W_out,
    short* __restrict__ W_uvT, short* __restrict__ W_outT) {
  int tid = threadIdx.x;
  int bx = blockIdx.x;
  if (bx >= NROW) {
    __shared__ float tile[64][65];
    int wb = bx - NROW;
    const float* src; short* dst; int s0, c0, ldS, ldD;
    if (wb < 272) {            // W_uv [512][2176] -> W_uvT [2176][512]
      int dt = wb / 34, ct = wb - dt * 34;
      s0 = dt * 64; c0 = ct * 64; ldS = NUV; ldD = DIMD;
      src = W_uv; dst = W_uvT;
    } else {                   // W_out [1024][512] -> W_outT [512][1024]
      int wb2 = wb - 272;
      int et = wb2 >> 3, dt = wb2 & 7;
      s0 = et * 64; c0 = dt * 64; ldS = DIMD; ldD = EE;
      src = W_out; dst = W_outT;
    }
    int r0 = tid >> 6, c = tid & 63;
    #pragma unroll
    for (int rr = 0; rr < 16; ++rr) {
      int row = rr * 4 + r0;
      tile[row][c] = src[(size_t)(s0 + row) * ldS + c0 + c];
    }
    __syncthreads();
    #pragma unroll
    for (int rr = 0; rr < 16; ++rr) {
      int row = rr * 4 + r0;
      dst[(size_t)(c0 + row) * ldD + s0 + c] = f2bf(tile[c][row]);
    }
    return;
  }
  int row = bx;
  const float2* xr = (const float2*)(x + (size_t)row * DIMD);
  float2 v = xr[tid];
  float s = v.x + v.y, ss = v.x * v.x + v.y * v.y;
  #pragma unroll
  for (int off = 32; off >= 1; off >>= 1) {
    s += __shfl_down(s, off);
    ss += __shfl_down(ss, off);
  }
  __shared__ float ps[8];
  if ((tid & 63) == 0) { ps[tid >> 6] = s; ps[4 + (tid >> 6)] = ss; }
  __syncthreads();
  s = ps[0] + ps[1] + ps[2] + ps[3];
  ss = ps[4] + ps[5] + ps[6] + ps[7];
  float mu = s * (1.0f / DIMD);
  float var = ss * (1.0f / DIMD) - mu * mu;
  float inv = rsqrtf(var + 1e-5f);
  float2 wv = ((const float2*)w)[tid];
  float2 bv = ((const float2*)bb)[tid];
  short2 o;
  o.x = f2bf((v.x - mu) * inv * wv.x + bv.x);
  o.y = f2bf((v.y - mu) * inv * wv.y + bv.y);
  *(short2*)&xn[(size_t)row * DIMD + tid * 2] = o;
}

// ---------------- m97-style GEMM core (swizzled): 128x128 tile, 4 waves, BK=32 ----------------
__device__ __forceinline__ void gemm_core(const short* __restrict__ A, const short* __restrict__ B,
                                          int lda, int ldb, int K, size_t m0, size_t n0,
                                          int tid, short* sm, f32x4 acc[4][4]) {
  short* As = sm;
  short* Bs = sm + 4096;
  int wid = tid >> 6, lane = tid & 63;
  int wr = (wid >> 1) * 64, wc = (wid & 1) * 64;
  int lr = lane & 15;
  int lk = ((lane >> 4) ^ (lane & 3)) * 8;               // swizzled read slot
  int r0 = tid >> 2;
  int c0 = (((tid & 3) ^ ((tid >> 2) & 3)) & 3) * 8;     // swizzled source slot
  #pragma unroll
  for (int m = 0; m < 4; m++)
    #pragma unroll
    for (int n = 0; n < 4; n++) acc[m][n] = (f32x4){0.f, 0.f, 0.f, 0.f};
  for (int k0 = 0; k0 < K; k0 += 32) {
    gld16(&A[(m0 + r0) * lda + k0 + c0],      &As[wid * 512]);
    gld16(&A[(m0 + 64 + r0) * lda + k0 + c0], &As[2048 + wid * 512]);
    gld16(&B[(n0 + r0) * ldb + k0 + c0],      &Bs[wid * 512]);
    gld16(&B[(n0 + 64 + r0) * ldb + k0 + c0], &Bs[2048 + wid * 512]);
    __syncthreads();
    short8 af[4], bf[4];
    #pragma unroll
    for (int m = 0; m < 4; m++) af[m] = *(short8*)&As[(wr + m * 16 + lr) * 32 + lk];
    #pragma unroll
    for (int n = 0; n < 4; n++) bf[n] = *(short8*)&Bs[(wc + n * 16 + lr) * 32 + lk];
    #pragma unroll
    for (int m = 0; m < 4; m++)
      #pragma unroll
      for (int n = 0; n < 4; n++)
        MFMA16(af[m], bf[n], acc[m][n]);
    __syncthreads();
  }
}

// ============ 256x256 8-phase pipelined GEMM core — R5 schedule ============
template<int LD, int T>
__device__ __forceinline__ void core8(const short* __restrict__ A, const short* __restrict__ Bv,
                                      size_t m0, size_t n0, int tid, short* sm,
                                      f32x4 (&acc)[8][4]) {
  const int w = tid >> 6, l = tid & 63;
  const int lr = l & 15;
  const int colsrc = ((l & 7) * 8) ^ ((l >> 3) << 3);
  const short* srcA = A  + (m0 + w * 8 + (l >> 3)) * (size_t)LD + colsrc;
  const short* srcB = Bv + (n0 + w * 8 + (l >> 3)) * (size_t)LD + colsrc;
  const int csw0 = ((l >> 4) * 8) ^ ((l & 7) << 3);
  const int csw1 = (32 + (l >> 4) * 8) ^ ((l & 7) << 3);
  const int AhalfOff = (w >> 2) * 8192 + lr * 64;
  const int BhalfOff = 16384 + ((w & 3) >> 1) * 8192 + ((w & 1) * 64 + lr) * 64;

  #define STA8(bf_, h_, q_, kt_) gld16(srcA + ((h_) * 128 + (q_) * 64) * (size_t)LD + (kt_) * 64, \
                                       &sm[(bf_) * 32768 + (h_) * 8192 + (q_) * 4096 + w * 512])
  #define STB8(bf_, h_, q_, kt_) gld16(srcB + ((h_) * 128 + (q_) * 64) * (size_t)LD + (kt_) * 64, \
                                       &sm[(bf_) * 32768 + 16384 + (h_) * 8192 + (q_) * 4096 + w * 512])

  #pragma unroll
  for (int m = 0; m < 8; m++)
    #pragma unroll
    for (int n = 0; n < 4; n++) acc[m][n] = (f32x4){0.f, 0.f, 0.f, 0.f};
  short8 Af[4][2], Bf0[2][2], Bf1[2][2];

  STA8(0, 0, 0, 0); STA8(0, 1, 0, 0);
  STB8(0, 0, 0, 0); STB8(0, 1, 0, 0);
  STB8(0, 0, 1, 0); STB8(0, 1, 1, 0);
  STA8(0, 0, 1, 0); STA8(0, 1, 1, 0);
  STA8(1, 0, 0, 1); STA8(1, 1, 0, 1);
  VMCNT(2);
  SBAR();
  __builtin_amdgcn_sched_barrier(0);

  for (int t = 0; t < T; ++t) {
    const int buf = t & 1, nb = buf ^ 1;
    short* Ab = sm + buf * 32768 + AhalfOff;
    short* Bb = sm + buf * 32768 + BhalfOff;
    // q1: (mh0,nh0); stage Bl(t+1)
    if (t + 1 < T) { STB8(nb, 0, 0, t + 1); STB8(nb, 1, 0, t + 1); }
    #pragma unroll
    for (int i = 0; i < 4; ++i) {
      Af[i][0] = *(const short8*)&Ab[i * 1024 + csw0];
      Af[i][1] = *(const short8*)&Ab[i * 1024 + csw1];
    }
    #pragma unroll
    for (int j = 0; j < 2; ++j) {
      Bf0[j][0] = *(const short8*)&Bb[j * 1024 + csw0];
      Bf0[j][1] = *(const short8*)&Bb[j * 1024 + csw1];
    }
    SBAR();
    __builtin_amdgcn_s_setprio(1);
    #pragma unroll
    for (int i = 0; i < 4; ++i)
      #pragma unroll
      for (int j = 0; j < 2; ++j) {
        MFMA16(Af[i][0], Bf0[j][0], acc[i][j]);
        MFMA16(Af[i][1], Bf0[j][1], acc[i][j]);
      }
    __builtin_amdgcn_s_setprio(0);
    if (t + 1 < T) { VMCNT(6); } else { VMCNT(2); }
    SBAR();
    // q2: (mh0,nh1); stage Bh(t+1)
    if (t + 1 < T) { STB8(nb, 0, 1, t + 1); STB8(nb, 1, 1, t + 1); }
    #pragma unroll
    for (int j = 0; j < 2; ++j) {
      Bf1[j][0] = *(const short8*)&Bb[2048 + j * 1024 + csw0];
      Bf1[j][1] = *(const short8*)&Bb[2048 + j * 1024 + csw1];
    }
    SBAR();
    __builtin_amdgcn_s_setprio(1);
    #pragma unroll
    for (int i = 0; i < 4; ++i)
      #pragma unroll
      for (int j = 0; j < 2; ++j) {
        MFMA16(Af[i][0], Bf1[j][0], acc[i][2 + j]);
        MFMA16(Af[i][1], Bf1[j][1], acc[i][2 + j]);
      }
    __builtin_amdgcn_s_setprio(0);
    if (t + 1 < T) { VMCNT(6); } else { VMCNT(0); }
    SBAR();
    // q3: (mh1,nh1); stage Ah(t+1)
    if (t + 1 < T) { STA8(nb, 0, 1, t + 1); STA8(nb, 1, 1, t + 1); }
    #pragma unroll
    for (int i = 0; i < 4; ++i) {
      Af[i][0] = *(const short8*)&Ab[4096 + i * 1024 + csw0];
      Af[i][1] = *(const short8*)&Ab[4096 + i * 1024 + csw1];
    }
    SBAR();
    __builtin_amdgcn_s_setprio(1);
    #pragma unroll
    for (int i = 0; i < 4; ++i)
      #pragma unroll
      for (int j = 0; j < 2; ++j) {
        MFMA16(Af[i][0], Bf1[j][0], acc[4 + i][2 + j]);
        MFMA16(Af[i][1], Bf1[j][1], acc[4 + i][2 + j]);
      }
    __builtin_amdgcn_s_setprio(0);
    if (t + 1 < T) { VMCNT(6); } else { VMCNT(0); }
    SBAR();
    // q4: (mh1,nh0); stage Al(t+2) into cur buf
    if (t + 2 < T) { STA8(buf, 0, 0, t + 2); STA8(buf, 1, 0, t + 2); }
    __builtin_amdgcn_s_setprio(1);
    #pragma unroll
    for (int i = 0; i < 4; ++i)
      #pragma unroll
      for (int j = 0; j < 2; ++j) {
        MFMA16(Af[i][0], Bf0[j][0], acc[4 + i][j]);
        MFMA16(Af[i][1], Bf0[j][1], acc[4 + i][j]);
      }
    __builtin_amdgcn_s_setprio(0);
    if (t + 2 < T) { VMCNT(6); } else if (t + 1 < T) { VMCNT(4); } else { VMCNT(0); }
    SBAR();
    __builtin_amdgcn_sched_barrier(0);
  }
  #undef STA8
  #undef STB8
}

// ---------------- GEMM1: 8-phase 256x256; y==8 is the q/k strip tile ----------------
// Strip tile (n0=2048) reads B rows 2048..2303: rows 2176+ physically overlap
// W_outT (valid finite bf16) -- results for those cols are never stored.
__global__ __launch_bounds__(512, 2) void guv8_kernel(
    const short* __restrict__ xn, const short* __restrict__ W_uvT,
    const float* __restrict__ b_uv,
    const float* __restrict__ gamma, const float* __restrict__ beta,
    short* __restrict__ u_out, short* __restrict__ vT_out,
    short* __restrict__ q_out, short* __restrict__ k_out)
{
  extern __shared__ __align__(16) short sm[];
  const size_t m0 = (size_t)blockIdx.x * 256;
  const size_t n0 = (size_t)blockIdx.y * 256;
  const int tid = threadIdx.x, w = tid >> 6, l = tid & 63;
  const int lr = l & 15;
  f32x4 acc[8][4];
  core8<DIMD, DIMD / 64>(xn, W_uvT, m0, n0, tid, sm, acc);
  const int rowb0 = (int)m0 + (w >> 2) * 128 + (l >> 4) * 4;
  const int colb0 = (int)n0 + (w & 3) * 64 + lr;
  if (n0 < 1024) {
    #pragma unroll
    for (int mf = 0; mf < 8; ++mf) {
      #pragma unroll
      for (int nf = 0; nf < 4; ++nf) {
        int col = colb0 + nf * 16;
        float bias = b_uv[col];
        #pragma unroll
        for (int r = 0; r < 4; ++r)
          u_out[(size_t)(rowb0 + mf * 16 + r) * EE + col] = f2bf(silu_f(acc[mf][nf][r] + bias));
      }
    }
  } else if (n0 < 2048) {
    #pragma unroll
    for (int mf = 0; mf < 8; ++mf) {
      int row = rowb0 + mf * 16;
      int bb = row >> 12, lb = row & (LLL - 1);
      #pragma unroll
      for (int nf = 0; nf < 4; ++nf) {
        int e = colb0 + nf * 16 - 1024;
        float bias = b_uv[e + 1024];
        short4 o;
        o.x = f2bf(silu_f(acc[mf][nf][0] + bias));
        o.y = f2bf(silu_f(acc[mf][nf][1] + bias));
        o.z = f2bf(silu_f(acc[mf][nf][2] + bias));
        o.w = f2bf(silu_f(acc[mf][nf][3] + bias));
        *(short4*)&vT_out[((size_t)bb * EE + e) * LLL + lb] = o;
      }
    }
  } else {
    // strip: cols 2048..2303; store q,k only for s<128 (q pre-scaled by 1/sqrt(S))
    if ((w & 3) < 2) {
      const float scale = 0.08838834764831845f;
      #pragma unroll
      for (int mf = 0; mf < 8; ++mf) {
        int rowb = rowb0 + mf * 16;
        #pragma unroll
        for (int nf = 0; nf < 4; ++nf) {
          int s = (w & 3) * 64 + nf * 16 + lr;
          float bias = b_uv[2048 + s];
          float g0 = gamma[s] * scale, g1 = gamma[SSS + s];
          float be0 = beta[s] * scale, be1 = beta[SSS + s];
          #pragma unroll
          for (int r = 0; r < 4; ++r) {
            float val = acc[mf][nf][r] + bias;
            q_out[(size_t)(rowb + r) * SSS + s] = f2bf(val * g0 + be0);
            k_out[(size_t)(rowb + r) * SSS + s] = f2bf(val * g1 + be1);
          }
        }
      }
    }
  }
}

// ---------------- QK^T 256x256 single-stage: whole K=128 resident in LDS ----------------
// Stage q[256][128] + k[256][128] (128 KB, dual-side XOR swizzle), one barrier,
// then 128 MFMAs/wave with zero further syncs. q pre-scaled -> P = relu(qk)^2.
__global__ __launch_bounds__(512, 2) void gqk4_kernel(
    const short* __restrict__ q, const short* __restrict__ k, short* __restrict__ P)
{
  extern __shared__ __align__(16) short sm[];
  const int b = blockIdx.z;
  const size_t m0 = (size_t)blockIdx.x * 256;
  const size_t n0 = (size_t)blockIdx.y * 256;
  const short* qz = q + (size_t)b * LLL * SSS;
  const short* kz = k + (size_t)b * LLL * SSS;
  short* Pz = P + (size_t)b * LLL * LLL;
  const int tid = threadIdx.x, w = tid >> 6, l = tid & 63;
  const int lr = l & 15;
  const int srow4 = w * 4 + (l >> 4);                 // row within each 32-row group
  #pragma unroll
  for (int u = 0; u < 8; ++u) {
    int row = u * 32 + srow4;
    int scol = ((l & 15) * 8) ^ ((row & 7) << 3);     // pre-swizzled global col
    gld16(qz + (m0 + row) * SSS + scol, &sm[(u * 32 + w * 4) * 128]);
    gld16(kz + (n0 + row) * SSS + scol, &sm[32768 + (u * 32 + w * 4) * 128]);
  }
  f32x4 acc[8][4];
  #pragma unroll
  for (int m = 0; m < 8; m++)
    #pragma unroll
    for (int n = 0; n < 4; n++) acc[m][n] = (f32x4){0.f, 0.f, 0.f, 0.f};
  VMCNT(0);
  __syncthreads();
  const int wr = (w >> 2) * 128, wc = (w & 3) * 64;
  #pragma unroll
  for (int ks = 0; ks < 4; ++ks) {
    const int csw = (ks * 32 + (l >> 4) * 8) ^ ((l & 7) << 3);
    short8 af[8], bf[4];
    #pragma unroll
    for (int m = 0; m < 8; m++) af[m] = *(const short8*)&sm[(wr + m * 16 + lr) * 128 + csw];
    #pragma unroll
    for (int n = 0; n < 4; n++) bf[n] = *(const short8*)&sm[32768 + (wc + n * 16 + lr) * 128 + csw];
    #pragma unroll
    for (int m = 0; m < 8; m++)
      #pragma unroll
      for (int n = 0; n < 4; n++)
        MFMA16(af[m], bf[n], acc[m][n]);
  }
  const int rowb0 = (int)m0 + wr + (l >> 4) * 4;
  const int colb0 = (int)n0 + wc + lr;
  #pragma unroll
  for (int mf = 0; mf < 8; mf++) {
    #pragma unroll
    for (int nf = 0; nf < 4; nf++) {
      int col = colb0 + nf * 16;
      #pragma unroll
      for (int r = 0; r < 4; r++) {
        float v = fmaxf(acc[mf][nf][r], 0.f);
        Pz[(size_t)(rowb0 + mf * 16 + r) * LLL + col] = f2bf(v * v);
      }
    }
  }
}

// ---------------- legacy QK (fallback tiers; q pre-scaled; row-major P) ----------------
__global__ __launch_bounds__(256) void gqk_kernel(
    const short* __restrict__ q, const short* __restrict__ k, short* __restrict__ P,
    long sq, long sk, long sp)
{
  __shared__ __align__(16) short sm[8192];
  int tid = threadIdx.x;
  const short* qz = q + (size_t)blockIdx.z * sq;
  const short* kz = k + (size_t)blockIdx.z * sk;
  short* Pz = P + (size_t)blockIdx.z * sp;
  size_t m0 = (size_t)blockIdx.x * 128, n0 = (size_t)blockIdx.y * 128;
  f32x4 acc[4][4];
  gemm_core(qz, kz, SSS, SSS, SSS, m0, n0, tid, sm, acc);
  int wid = tid >> 6, lane = tid & 63;
  int wr = (wid >> 1) * 64, wc = (wid & 1) * 64;
  int lr = lane & 15;
  #pragma unroll
  for (int m = 0; m < 4; m++) {
    #pragma unroll
    for (int n = 0; n < 4; n++) {
      int col = (int)n0 + wc + n * 16 + lr;
      int rowb = (int)m0 + wr + m * 16 + (lane >> 4) * 4;
      #pragma unroll
      for (int r = 0; r < 4; r++) {
        float v = fmaxf(acc[m][n][r], 0.f);
        Pz[(size_t)(rowb + r) * LLL + col] = f2bf(v * v);
      }
    }
  }
}

// ---------------- legacy PV (fallback tiers): m97 core, row-major P ----------------
__global__ __launch_bounds__(256) void gpv_kernel(
    const short* __restrict__ P, const short* __restrict__ vT,
    const short* __restrict__ u, short* __restrict__ g,
    long sp, long sv, long su)
{
  __shared__ __align__(16) short sm[8192];
  int tid = threadIdx.x;
  const short* Pz = P + (size_t)blockIdx.z * sp;
  const short* vz = vT + (size_t)blockIdx.z * sv;
  const short* uz = u + (size_t)blockIdx.z * su;
  short* gz = g + (size_t)blockIdx.z * su;
  size_t m0 = (size_t)blockIdx.x * 128, n0 = (size_t)blockIdx.y * 128;
  f32x4 acc[4][4];
  gemm_core(Pz, vz, LLL, LLL, LLL, m0, n0, tid, sm, acc);
  int wid = tid >> 6, lane = tid & 63;
  int wr = (wid >> 1) * 64, wc = (wid & 1) * 64;
  int lr = lane & 15;
  #pragma unroll
  for (int m = 0; m < 4; m++) {
    #pragma unroll
    for (int n = 0; n < 4; n++) {
      int col = (int)n0 + wc + n * 16 + lr;
      int rowb = (int)m0 + wr + m * 16 + (lane >> 4) * 4;
      #pragma unroll
      for (int r = 0; r < 4; r++) {
        size_t idx = (size_t)(rowb + r) * EE + col;
        gz[idx] = f2bf(bf2f(uz[idx]) * acc[m][n][r]);
      }
    }
  }
}

// ---------------- PV, 256x256 (core8 R5 schedule) ----------------
__global__ __launch_bounds__(512, 2) void gpv8_kernel(
    const short* __restrict__ Pg, const short* __restrict__ vTg,
    const short* __restrict__ ug, short* __restrict__ gg)
{
  extern __shared__ __align__(16) short sm[];
  const int b = blockIdx.z;
  const size_t m0 = (size_t)blockIdx.x * 256;
  const size_t n0 = (size_t)blockIdx.y * 256;
  const short* A  = Pg  + (size_t)b * LLL * LLL;
  const short* Bv = vTg + (size_t)b * EE * LLL;
  const int tid = threadIdx.x, w = tid >> 6, l = tid & 63;
  const int lr = l & 15;
  f32x4 acc[8][4];
  core8<LLL, LLL / 64>(A, Bv, m0, n0, tid, sm, acc);
  const short* ub_ = ug + (size_t)b * LLL * EE;
  short* gb_ = gg + (size_t)b * LLL * EE;
  const int rowb0 = (int)m0 + (w >> 2) * 128 + (l >> 4) * 4;
  const int colb0 = (int)n0 + (w & 3) * 64 + lr;
  #pragma unroll
  for (int mf = 0; mf < 8; ++mf) {
    #pragma unroll
    for (int nf = 0; nf < 4; ++nf) {
      int col = colb0 + nf * 16;
      #pragma unroll
      for (int r = 0; r < 4; ++r) {
        size_t idx = (size_t)(rowb0 + mf * 16 + r) * EE + col;
        gb_[idx] = f2bf(bf2f(ub_[idx]) * acc[mf][nf][r]);
      }
    }
  }
}

// ---------------- GEMM2 (m97, 512 blocks): g x W_outT + bias + residual ----------------
__global__ __launch_bounds__(256) void gout_kernel(
    const short* __restrict__ A, const short* __restrict__ Bw,
    const float* __restrict__ b_out, const float* __restrict__ x,
    float* __restrict__ out)
{
  __shared__ __align__(16) short sm[8192];
  int tid = threadIdx.x;
  size_t m0 = (size_t)blockIdx.x * 128, n0 = (size_t)blockIdx.y * 128;
  f32x4 acc[4][4];
  gemm_core(A, Bw, EE, EE, EE, m0, n0, tid, sm, acc);
  int wid = tid >> 6, lane = tid & 63;
  int wr = (wid >> 1) * 64, wc = (wid & 1) * 64;
  int lr = lane & 15;
  #pragma unroll
  for (int m = 0; m < 4; m++) {
    #pragma unroll
    for (int n = 0; n < 4; n++) {
      int col = (int)n0 + wc + n * 16 + lr;
      float bias = b_out[col];
      int rowb = (int)m0 + wr + m * 16 + (lane >> 4) * 4;
      #pragma unroll
      for (int r = 0; r < 4; r++) {
        size_t idx = (size_t)(rowb + r) * DIMD + col;
        out[idx] = acc[m][n][r] + bias + x[idx];
      }
    }
  }
}

extern "C" void kernel_launch(void* const* d_in, const int* in_sizes, int n_in,
                              void* d_out, int out_size, void* d_ws, size_t ws_size,
                              hipStream_t stream) {
  const float* x     = (const float*)d_in[0];
  const float* W_uv  = (const float*)d_in[1];
  const float* b_uv  = (const float*)d_in[2];
  const float* gamma = (const float*)d_in[3];
  const float* beta  = (const float*)d_in[4];
  const float* W_out = (const float*)d_in[5];
  const float* b_out = (const float*)d_in[6];
  const float* ln_w  = (const float*)d_in[7];
  const float* ln_b  = (const float*)d_in[8];
  float* out = (float*)d_out;

  char* ws = (char*)d_ws;
  short* W_uvT  = (short*)(ws);
  short* W_outT = (short*)(ws + 2228224);
  short* xn     = (short*)(ws + 3276800);
  short* qb     = (short*)(ws + 20054016);
  short* kb     = (short*)(ws + 24248320);
  short* ub     = (short*)(ws + 28442624);
  short* vTb    = (short*)(ws + 61997056);
  short* gb     = (short*)(ws + 95551488);
  short* Pb     = (short*)(ws + 129105920);

  prepln_kernel<<<dim3(NROW + 400), 256, 0, stream>>>(
      x, ln_w, ln_b, xn, W_uv, W_out, W_uvT, W_outT);
  guv8_kernel<<<dim3(NROW / 256, 9), 512, 131072, stream>>>(
      xn, W_uvT, b_uv, gamma, beta, ub, vTb, qb, kb);

  const long SQ = (long)LLL * SSS;
  const long SP = (long)LLL * LLL;
  const long SV = (long)EE * LLL;
  const long SU = (long)LLL * EE;

  if (ws_size >= 129105920ull + 134217728ull) {
    gqk4_kernel<<<dim3(16, 16, 4), 512, 131072, stream>>>(qb, kb, Pb);
    gpv8_kernel<<<dim3(16, 4, 4), 512, 131072, stream>>>(Pb, vTb, ub, gb);
  } else if (ws_size >= 129105920ull + 33554432ull) {
    for (int b = 0; b < 4; b++) {
      gqk_kernel<<<dim3(32, 32, 1), 256, 0, stream>>>(qb + (size_t)b * SQ, kb + (size_t)b * SQ, Pb, 0, 0, 0);
      gpv_kernel<<<dim3(32, 8, 1), 256, 0, stream>>>(Pb, vTb + (size_t)b * SV, ub + (size_t)b * SU, gb + (size_t)b * SU, 0, 0, 0);
    }
  } else {
    short* Pc = xn;
    for (int b = 0; b < 4; b++) {
      for (int h = 0; h < 2; h++) {
        size_t rowoff = (size_t)b * LLL + (size_t)h * 2048;
        gqk_kernel<<<dim3(16, 32, 1), 256, 0, stream>>>(qb + rowoff * SSS, kb + (size_t)b * SQ, Pc, 0, 0, 0);
        gpv_kernel<<<dim3(16, 8, 1), 256, 0, stream>>>(Pc, vTb + (size_t)b * SV, ub + rowoff * EE, gb + rowoff * EE, 0, 0, 0);
      }
    }
  }

  gout_kernel<<<dim3(NROW / 128, DIMD / 128), 256, 0, stream>>>(gb, W_outT, b_out, x, out);
}

// Round 14
// 273.366 us; speedup vs baseline: 1.1716x; 1.0060x over previous
//
#include <hip/hip_runtime.h>

typedef __attribute__((ext_vector_type(8))) short short8;
typedef __attribute__((ext_vector_type(4))) float f32x4;

#define DIMD 512
#define EE 1024
#define SSS 128
#define LLL 4096
#define NROW 16384   // B*L
#define NUV 2176     // 2E+S

__device__ __forceinline__ short f2bf(float f) {
  union { float f; unsigned u; } un; un.f = f;
  unsigned r = un.u + 0x7FFFu + ((un.u >> 16) & 1u);
  return (short)(r >> 16);
}
__device__ __forceinline__ float bf2f(short s) {
  union { unsigned u; float f; } un;
  un.u = ((unsigned)(unsigned short)s) << 16;
  return un.f;
}
__device__ __forceinline__ float silu_f(float x) {
  return x / (1.0f + __expf(-x));
}

__device__ __forceinline__ void gld16(const short* g, short* l) {
  __builtin_amdgcn_global_load_lds(
      (const __attribute__((address_space(1))) unsigned int*)g,
      (__attribute__((address_space(3))) unsigned int*)l, 16, 0, 0);
}

#define MFMA16(a, b, c) c = __builtin_amdgcn_mfma_f32_16x16x32_bf16(a, b, c, 0, 0, 0)
#define SBAR() asm volatile("s_barrier" ::: "memory")
#define VMCNT(n) asm volatile("s_waitcnt vmcnt(" #n ")" ::: "memory")

// ---------------- fused prep+layernorm ----------------
__global__ __launch_bounds__(256) void prepln_kernel(
    const float* __restrict__ x, const float* __restrict__ w, const float* __restrict__ bb,
    short* __restrict__ xn,
    const float* __restrict__ W_uv, const float* __restrict__ W_out,
    short* __restrict__ W_uvT, short* __restrict__ W_outT) {
  int tid = threadIdx.x;
  int bx = blockIdx.x;
  if (bx >= NROW) {
    __shared__ float tile[64][65];
    int wb = bx - NROW;
    const float* src; short* dst; int s0, c0, ldS, ldD;
    if (wb < 272) {            // W_uv [512][2176] -> W_uvT [2176][512]
      int dt = wb / 34, ct = wb - dt * 34;
      s0 = dt * 64; c0 = ct * 64; ldS = NUV; ldD = DIMD;
      src = W_uv; dst = W_uvT;
    } else {                   // W_out [1024][512] -> W_outT [512][1024]
      int wb2 = wb - 272;
      int et = wb2 >> 3, dt = wb2 & 7;
      s0 = et * 64; c0 = dt * 64; ldS = DIMD; ldD = EE;
      src = W_out; dst = W_outT;
    }
    int r0 = tid >> 6, c = tid & 63;
    #pragma unroll
    for (int rr = 0; rr < 16; ++rr) {
      int row = rr * 4 + r0;
      tile[row][c] = src[(size_t)(s0 + row) * ldS + c0 + c];
    }
    __syncthreads();
    #pragma unroll
    for (int rr = 0; rr < 16; ++rr) {
      int row = rr * 4 + r0;
      dst[(size_t)(c0 + row) * ldD + s0 + c] = f2bf(tile[c][row]);
    }
    return;
  }
  int row = bx;
  const float2* xr = (const float2*)(x + (size_t)row * DIMD);
  float2 v = xr[tid];
  float s = v.x + v.y, ss = v.x * v.x + v.y * v.y;
  #pragma unroll
  for (int off = 32; off >= 1; off >>= 1) {
    s += __shfl_down(s, off);
    ss += __shfl_down(ss, off);
  }
  __shared__ float ps[8];
  if ((tid & 63) == 0) { ps[tid >> 6] = s; ps[4 + (tid >> 6)] = ss; }
  __syncthreads();
  s = ps[0] + ps[1] + ps[2] + ps[3];
  ss = ps[4] + ps[5] + ps[6] + ps[7];
  float mu = s * (1.0f / DIMD);
  float var = ss * (1.0f / DIMD) - mu * mu;
  float inv = rsqrtf(var + 1e-5f);
  float2 wv = ((const float2*)w)[tid];
  float2 bv = ((const float2*)bb)[tid];
  short2 o;
  o.x = f2bf((v.x - mu) * inv * wv.x + bv.x);
  o.y = f2bf((v.y - mu) * inv * wv.y + bv.y);
  *(short2*)&xn[(size_t)row * DIMD + tid * 2] = o;
}

// ---------------- m97-style GEMM core (swizzled): 128x128 tile, 4 waves, BK=32 ----------------
__device__ __forceinline__ void gemm_core(const short* __restrict__ A, const short* __restrict__ B,
                                          int lda, int ldb, int K, size_t m0, size_t n0,
                                          int tid, short* sm, f32x4 acc[4][4]) {
  short* As = sm;
  short* Bs = sm + 4096;
  int wid = tid >> 6, lane = tid & 63;
  int wr = (wid >> 1) * 64, wc = (wid & 1) * 64;
  int lr = lane & 15;
  int lk = ((lane >> 4) ^ (lane & 3)) * 8;               // swizzled read slot
  int r0 = tid >> 2;
  int c0 = (((tid & 3) ^ ((tid >> 2) & 3)) & 3) * 8;     // swizzled source slot
  #pragma unroll
  for (int m = 0; m < 4; m++)
    #pragma unroll
    for (int n = 0; n < 4; n++) acc[m][n] = (f32x4){0.f, 0.f, 0.f, 0.f};
  for (int k0 = 0; k0 < K; k0 += 32) {
    gld16(&A[(m0 + r0) * lda + k0 + c0],      &As[wid * 512]);
    gld16(&A[(m0 + 64 + r0) * lda + k0 + c0], &As[2048 + wid * 512]);
    gld16(&B[(n0 + r0) * ldb + k0 + c0],      &Bs[wid * 512]);
    gld16(&B[(n0 + 64 + r0) * ldb + k0 + c0], &Bs[2048 + wid * 512]);
    __syncthreads();
    short8 af[4], bf[4];
    #pragma unroll
    for (int m = 0; m < 4; m++) af[m] = *(short8*)&As[(wr + m * 16 + lr) * 32 + lk];
    #pragma unroll
    for (int n = 0; n < 4; n++) bf[n] = *(short8*)&Bs[(wc + n * 16 + lr) * 32 + lk];
    #pragma unroll
    for (int m = 0; m < 4; m++)
      #pragma unroll
      for (int n = 0; n < 4; n++)
        MFMA16(af[m], bf[n], acc[m][n]);
    __syncthreads();
  }
}

// ============ 256x256 8-phase pipelined GEMM core — R5 schedule, 4 barriers/tile ============
// Pre-MFMA barriers removed (correctness-safe: all within-tile reads are of data
// staged >=1 tile ago; q4's store-to-buf is still separated from q1's A-low reads
// by the q1/q2/q3 phase-end vmcnt+SBAR chain).
template<int LD, int T>
__device__ __forceinline__ void core8(const short* __restrict__ A, const short* __restrict__ Bv,
                                      size_t m0, size_t n0, int tid, short* sm,
                                      f32x4 (&acc)[8][4]) {
  const int w = tid >> 6, l = tid & 63;
  const int lr = l & 15;
  const int colsrc = ((l & 7) * 8) ^ ((l >> 3) << 3);
  const short* srcA = A  + (m0 + w * 8 + (l >> 3)) * (size_t)LD + colsrc;
  const short* srcB = Bv + (n0 + w * 8 + (l >> 3)) * (size_t)LD + colsrc;
  const int csw0 = ((l >> 4) * 8) ^ ((l & 7) << 3);
  const int csw1 = (32 + (l >> 4) * 8) ^ ((l & 7) << 3);
  const int AhalfOff = (w >> 2) * 8192 + lr * 64;
  const int BhalfOff = 16384 + ((w & 3) >> 1) * 8192 + ((w & 1) * 64 + lr) * 64;

  #define STA8(bf_, h_, q_, kt_) gld16(srcA + ((h_) * 128 + (q_) * 64) * (size_t)LD + (kt_) * 64, \
                                       &sm[(bf_) * 32768 + (h_) * 8192 + (q_) * 4096 + w * 512])
  #define STB8(bf_, h_, q_, kt_) gld16(srcB + ((h_) * 128 + (q_) * 64) * (size_t)LD + (kt_) * 64, \
                                       &sm[(bf_) * 32768 + 16384 + (h_) * 8192 + (q_) * 4096 + w * 512])

  #pragma unroll
  for (int m = 0; m < 8; m++)
    #pragma unroll
    for (int n = 0; n < 4; n++) acc[m][n] = (f32x4){0.f, 0.f, 0.f, 0.f};
  short8 Af[4][2], Bf0[2][2], Bf1[2][2];

  STA8(0, 0, 0, 0); STA8(0, 1, 0, 0);
  STB8(0, 0, 0, 0); STB8(0, 1, 0, 0);
  STB8(0, 0, 1, 0); STB8(0, 1, 1, 0);
  STA8(0, 0, 1, 0); STA8(0, 1, 1, 0);
  STA8(1, 0, 0, 1); STA8(1, 1, 0, 1);
  VMCNT(2);
  SBAR();
  __builtin_amdgcn_sched_barrier(0);

  for (int t = 0; t < T; ++t) {
    const int buf = t & 1, nb = buf ^ 1;
    short* Ab = sm + buf * 32768 + AhalfOff;
    short* Bb = sm + buf * 32768 + BhalfOff;
    // q1: (mh0,nh0); stage Bl(t+1)
    if (t + 1 < T) { STB8(nb, 0, 0, t + 1); STB8(nb, 1, 0, t + 1); }
    #pragma unroll
    for (int i = 0; i < 4; ++i) {
      Af[i][0] = *(const short8*)&Ab[i * 1024 + csw0];
      Af[i][1] = *(const short8*)&Ab[i * 1024 + csw1];
    }
    #pragma unroll
    for (int j = 0; j < 2; ++j) {
      Bf0[j][0] = *(const short8*)&Bb[j * 1024 + csw0];
      Bf0[j][1] = *(const short8*)&Bb[j * 1024 + csw1];
    }
    __builtin_amdgcn_s_setprio(1);
    #pragma unroll
    for (int i = 0; i < 4; ++i)
      #pragma unroll
      for (int j = 0; j < 2; ++j) {
        MFMA16(Af[i][0], Bf0[j][0], acc[i][j]);
        MFMA16(Af[i][1], Bf0[j][1], acc[i][j]);
      }
    __builtin_amdgcn_s_setprio(0);
    if (t + 1 < T) { VMCNT(6); } else { VMCNT(2); }
    SBAR();
    // q2: (mh0,nh1); stage Bh(t+1)
    if (t + 1 < T) { STB8(nb, 0, 1, t + 1); STB8(nb, 1, 1, t + 1); }
    #pragma unroll
    for (int j = 0; j < 2; ++j) {
      Bf1[j][0] = *(const short8*)&Bb[2048 + j * 1024 + csw0];
      Bf1[j][1] = *(const short8*)&Bb[2048 + j * 1024 + csw1];
    }
    __builtin_amdgcn_s_setprio(1);
    #pragma unroll
    for (int i = 0; i < 4; ++i)
      #pragma unroll
      for (int j = 0; j < 2; ++j) {
        MFMA16(Af[i][0], Bf1[j][0], acc[i][2 + j]);
        MFMA16(Af[i][1], Bf1[j][1], acc[i][2 + j]);
      }
    __builtin_amdgcn_s_setprio(0);
    if (t + 1 < T) { VMCNT(6); } else { VMCNT(0); }
    SBAR();
    // q3: (mh1,nh1); stage Ah(t+1)
    if (t + 1 < T) { STA8(nb, 0, 1, t + 1); STA8(nb, 1, 1, t + 1); }
    #pragma unroll
    for (int i = 0; i < 4; ++i) {
      Af[i][0] = *(const short8*)&Ab[4096 + i * 1024 + csw0];
      Af[i][1] = *(const short8*)&Ab[4096 + i * 1024 + csw1];
    }
    __builtin_amdgcn_s_setprio(1);
    #pragma unroll
    for (int i = 0; i < 4; ++i)
      #pragma unroll
      for (int j = 0; j < 2; ++j) {
        MFMA16(Af[i][0], Bf1[j][0], acc[4 + i][2 + j]);
        MFMA16(Af[i][1], Bf1[j][1], acc[4 + i][2 + j]);
      }
    __builtin_amdgcn_s_setprio(0);
    if (t + 1 < T) { VMCNT(6); } else { VMCNT(0); }
    SBAR();
    // q4: (mh1,nh0); stage Al(t+2) into cur buf
    if (t + 2 < T) { STA8(buf, 0, 0, t + 2); STA8(buf, 1, 0, t + 2); }
    __builtin_amdgcn_s_setprio(1);
    #pragma unroll
    for (int i = 0; i < 4; ++i)
      #pragma unroll
      for (int j = 0; j < 2; ++j) {
        MFMA16(Af[i][0], Bf0[j][0], acc[4 + i][j]);
        MFMA16(Af[i][1], Bf0[j][1], acc[4 + i][j]);
      }
    __builtin_amdgcn_s_setprio(0);
    if (t + 2 < T) { VMCNT(6); } else if (t + 1 < T) { VMCNT(4); } else { VMCNT(0); }
    SBAR();
    __builtin_amdgcn_sched_barrier(0);
  }
  #undef STA8
  #undef STB8
}

// ---------------- GEMM1: 8-phase 256x256; y==8 is the q/k strip tile ----------------
__global__ __launch_bounds__(512, 2) void guv8_kernel(
    const short* __restrict__ xn, const short* __restrict__ W_uvT,
    const float* __restrict__ b_uv,
    const float* __restrict__ gamma, const float* __restrict__ beta,
    short* __restrict__ u_out, short* __restrict__ vT_out,
    short* __restrict__ q_out, short* __restrict__ k_out)
{
  extern __shared__ __align__(16) short sm[];
  const size_t m0 = (size_t)blockIdx.x * 256;
  const size_t n0 = (size_t)blockIdx.y * 256;
  const int tid = threadIdx.x, w = tid >> 6, l = tid & 63;
  const int lr = l & 15;
  f32x4 acc[8][4];
  core8<DIMD, DIMD / 64>(xn, W_uvT, m0, n0, tid, sm, acc);
  const int rowb0 = (int)m0 + (w >> 2) * 128 + (l >> 4) * 4;
  const int colb0 = (int)n0 + (w & 3) * 64 + lr;
  if (n0 < 1024) {
    #pragma unroll
    for (int mf = 0; mf < 8; ++mf) {
      #pragma unroll
      for (int nf = 0; nf < 4; ++nf) {
        int col = colb0 + nf * 16;
        float bias = b_uv[col];
        #pragma unroll
        for (int r = 0; r < 4; ++r)
          u_out[(size_t)(rowb0 + mf * 16 + r) * EE + col] = f2bf(silu_f(acc[mf][nf][r] + bias));
      }
    }
  } else if (n0 < 2048) {
    #pragma unroll
    for (int mf = 0; mf < 8; ++mf) {
      int row = rowb0 + mf * 16;
      int bb = row >> 12, lb = row & (LLL - 1);
      #pragma unroll
      for (int nf = 0; nf < 4; ++nf) {
        int e = colb0 + nf * 16 - 1024;
        float bias = b_uv[e + 1024];
        short4 o;
        o.x = f2bf(silu_f(acc[mf][nf][0] + bias));
        o.y = f2bf(silu_f(acc[mf][nf][1] + bias));
        o.z = f2bf(silu_f(acc[mf][nf][2] + bias));
        o.w = f2bf(silu_f(acc[mf][nf][3] + bias));
        *(short4*)&vT_out[((size_t)bb * EE + e) * LLL + lb] = o;
      }
    }
  } else {
    if ((w & 3) < 2) {
      const float scale = 0.08838834764831845f;
      #pragma unroll
      for (int mf = 0; mf < 8; ++mf) {
        int rowb = rowb0 + mf * 16;
        #pragma unroll
        for (int nf = 0; nf < 4; ++nf) {
          int s = (w & 3) * 64 + nf * 16 + lr;
          float bias = b_uv[2048 + s];
          float g0 = gamma[s] * scale, g1 = gamma[SSS + s];
          float be0 = beta[s] * scale, be1 = beta[SSS + s];
          #pragma unroll
          for (int r = 0; r < 4; ++r) {
            float val = acc[mf][nf][r] + bias;
            q_out[(size_t)(rowb + r) * SSS + s] = f2bf(val * g0 + be0);
            k_out[(size_t)(rowb + r) * SSS + s] = f2bf(val * g1 + be1);
          }
        }
      }
    }
  }
}

// ---------------- QK^T 256x256 single-stage: whole K=128 resident in LDS ----------------
__global__ __launch_bounds__(512, 2) void gqk4_kernel(
    const short* __restrict__ q, const short* __restrict__ k, short* __restrict__ P)
{
  extern __shared__ __align__(16) short sm[];
  const int b = blockIdx.z;
  const size_t m0 = (size_t)blockIdx.x * 256;
  const size_t n0 = (size_t)blockIdx.y * 256;
  const short* qz = q + (size_t)b * LLL * SSS;
  const short* kz = k + (size_t)b * LLL * SSS;
  short* Pz = P + (size_t)b * LLL * LLL;
  const int tid = threadIdx.x, w = tid >> 6, l = tid & 63;
  const int lr = l & 15;
  const int srow4 = w * 4 + (l >> 4);
  #pragma unroll
  for (int u = 0; u < 8; ++u) {
    int row = u * 32 + srow4;
    int scol = ((l & 15) * 8) ^ ((row & 7) << 3);
    gld16(qz + (m0 + row) * SSS + scol, &sm[(u * 32 + w * 4) * 128]);
    gld16(kz + (n0 + row) * SSS + scol, &sm[32768 + (u * 32 + w * 4) * 128]);
  }
  f32x4 acc[8][4];
  #pragma unroll
  for (int m = 0; m < 8; m++)
    #pragma unroll
    for (int n = 0; n < 4; n++) acc[m][n] = (f32x4){0.f, 0.f, 0.f, 0.f};
  VMCNT(0);
  __syncthreads();
  const int wr = (w >> 2) * 128, wc = (w & 3) * 64;
  #pragma unroll
  for (int ks = 0; ks < 4; ++ks) {
    const int csw = (ks * 32 + (l >> 4) * 8) ^ ((l & 7) << 3);
    short8 af[8], bf[4];
    #pragma unroll
    for (int m = 0; m < 8; m++) af[m] = *(const short8*)&sm[(wr + m * 16 + lr) * 128 + csw];
    #pragma unroll
    for (int n = 0; n < 4; n++) bf[n] = *(const short8*)&sm[32768 + (wc + n * 16 + lr) * 128 + csw];
    #pragma unroll
    for (int m = 0; m < 8; m++)
      #pragma unroll
      for (int n = 0; n < 4; n++)
        MFMA16(af[m], bf[n], acc[m][n]);
  }
  const int rowb0 = (int)m0 + wr + (l >> 4) * 4;
  const int colb0 = (int)n0 + wc + lr;
  #pragma unroll
  for (int mf = 0; mf < 8; mf++) {
    #pragma unroll
    for (int nf = 0; nf < 4; nf++) {
      int col = colb0 + nf * 16;
      #pragma unroll
      for (int r = 0; r < 4; r++) {
        float v = fmaxf(acc[mf][nf][r], 0.f);
        Pz[(size_t)(rowb0 + mf * 16 + r) * LLL + col] = f2bf(v * v);
      }
    }
  }
}

// ---------------- legacy QK (fallback tiers; q pre-scaled; row-major P) ----------------
__global__ __launch_bounds__(256) void gqk_kernel(
    const short* __restrict__ q, const short* __restrict__ k, short* __restrict__ P,
    long sq, long sk, long sp)
{
  __shared__ __align__(16) short sm[8192];
  int tid = threadIdx.x;
  const short* qz = q + (size_t)blockIdx.z * sq;
  const short* kz = k + (size_t)blockIdx.z * sk;
  short* Pz = P + (size_t)blockIdx.z * sp;
  size_t m0 = (size_t)blockIdx.x * 128, n0 = (size_t)blockIdx.y * 128;
  f32x4 acc[4][4];
  gemm_core(qz, kz, SSS, SSS, SSS, m0, n0, tid, sm, acc);
  int wid = tid >> 6, lane = tid & 63;
  int wr = (wid >> 1) * 64, wc = (wid & 1) * 64;
  int lr = lane & 15;
  #pragma unroll
  for (int m = 0; m < 4; m++) {
    #pragma unroll
    for (int n = 0; n < 4; n++) {
      int col = (int)n0 + wc + n * 16 + lr;
      int rowb = (int)m0 + wr + m * 16 + (lane >> 4) * 4;
      #pragma unroll
      for (int r = 0; r < 4; r++) {
        float v = fmaxf(acc[m][n][r], 0.f);
        Pz[(size_t)(rowb + r) * LLL + col] = f2bf(v * v);
      }
    }
  }
}

// ---------------- legacy PV (fallback tiers): m97 core, row-major P ----------------
__global__ __launch_bounds__(256) void gpv_kernel(
    const short* __restrict__ P, const short* __restrict__ vT,
    const short* __restrict__ u, short* __restrict__ g,
    long sp, long sv, long su)
{
  __shared__ __align__(16) short sm[8192];
  int tid = threadIdx.x;
  const short* Pz = P + (size_t)blockIdx.z * sp;
  const short* vz = vT + (size_t)blockIdx.z * sv;
  const short* uz = u + (size_t)blockIdx.z * su;
  short* gz = g + (size_t)blockIdx.z * su;
  size_t m0 = (size_t)blockIdx.x * 128, n0 = (size_t)blockIdx.y * 128;
  f32x4 acc[4][4];
  gemm_core(Pz, vz, LLL, LLL, LLL, m0, n0, tid, sm, acc);
  int wid = tid >> 6, lane = tid & 63;
  int wr = (wid >> 1) * 64, wc = (wid & 1) * 64;
  int lr = lane & 15;
  #pragma unroll
  for (int m = 0; m < 4; m++) {
    #pragma unroll
    for (int n = 0; n < 4; n++) {
      int col = (int)n0 + wc + n * 16 + lr;
      int rowb = (int)m0 + wr + m * 16 + (lane >> 4) * 4;
      #pragma unroll
      for (int r = 0; r < 4; r++) {
        size_t idx = (size_t)(rowb + r) * EE + col;
        gz[idx] = f2bf(bf2f(uz[idx]) * acc[m][n][r]);
      }
    }
  }
}

// ---------------- PV, 256x256 (core8) ----------------
__global__ __launch_bounds__(512, 2) void gpv8_kernel(
    const short* __restrict__ Pg, const short* __restrict__ vTg,
    const short* __restrict__ ug, short* __restrict__ gg)
{
  extern __shared__ __align__(16) short sm[];
  const int b = blockIdx.z;
  const size_t m0 = (size_t)blockIdx.x * 256;
  const size_t n0 = (size_t)blockIdx.y * 256;
  const short* A  = Pg  + (size_t)b * LLL * LLL;
  const short* Bv = vTg + (size_t)b * EE * LLL;
  const int tid = threadIdx.x, w = tid >> 6, l = tid & 63;
  const int lr = l & 15;
  f32x4 acc[8][4];
  core8<LLL, LLL / 64>(A, Bv, m0, n0, tid, sm, acc);
  const short* ub_ = ug + (size_t)b * LLL * EE;
  short* gb_ = gg + (size_t)b * LLL * EE;
  const int rowb0 = (int)m0 + (w >> 2) * 128 + (l >> 4) * 4;
  const int colb0 = (int)n0 + (w & 3) * 64 + lr;
  #pragma unroll
  for (int mf = 0; mf < 8; ++mf) {
    #pragma unroll
    for (int nf = 0; nf < 4; ++nf) {
      int col = colb0 + nf * 16;
      #pragma unroll
      for (int r = 0; r < 4; ++r) {
        size_t idx = (size_t)(rowb0 + mf * 16 + r) * EE + col;
        gb_[idx] = f2bf(bf2f(ub_[idx]) * acc[mf][nf][r]);
      }
    }
  }
}

// ---------------- GEMM2 (m97, 512 blocks): g x W_outT + bias + residual ----------------
__global__ __launch_bounds__(256) void gout_kernel(
    const short* __restrict__ A, const short* __restrict__ Bw,
    const float* __restrict__ b_out, const float* __restrict__ x,
    float* __restrict__ out)
{
  __shared__ __align__(16) short sm[8192];
  int tid = threadIdx.x;
  size_t m0 = (size_t)blockIdx.x * 128, n0 = (size_t)blockIdx.y * 128;
  f32x4 acc[4][4];
  gemm_core(A, Bw, EE, EE, EE, m0, n0, tid, sm, acc);
  int wid = tid >> 6, lane = tid & 63;
  int wr = (wid >> 1) * 64, wc = (wid & 1) * 64;
  int lr = lane & 15;
  #pragma unroll
  for (int m = 0; m < 4; m++) {
    #pragma unroll
    for (int n = 0; n < 4; n++) {
      int col = (int)n0 + wc + n * 16 + lr;
      float bias = b_out[col];
      int rowb = (int)m0 + wr + m * 16 + (lane >> 4) * 4;
      #pragma unroll
      for (int r = 0; r < 4; r++) {
        size_t idx = (size_t)(rowb + r) * DIMD + col;
        out[idx] = acc[m][n][r] + bias + x[idx];
      }
    }
  }
}

extern "C" void kernel_launch(void* const* d_in, const int* in_sizes, int n_in,
                              void* d_out, int out_size, void* d_ws, size_t ws_size,
                              hipStream_t stream) {
  const float* x     = (const float*)d_in[0];
  const float* W_uv  = (const float*)d_in[1];
  const float* b_uv  = (const float*)d_in[2];
  const float* gamma = (const float*)d_in[3];
  const float* beta  = (const float*)d_in[4];
  const float* W_out = (const float*)d_in[5];
  const float* b_out = (const float*)d_in[6];
  const float* ln_w  = (const float*)d_in[7];
  const float* ln_b  = (const float*)d_in[8];
  float* out = (float*)d_out;

  char* ws = (char*)d_ws;
  short* W_uvT  = (short*)(ws);
  short* W_outT = (short*)(ws + 2228224);
  short* xn     = (short*)(ws + 3276800);
  short* qb     = (short*)(ws + 20054016);
  short* kb     = (short*)(ws + 24248320);
  short* ub     = (short*)(ws + 28442624);
  short* vTb    = (short*)(ws + 61997056);
  short* gb     = (short*)(ws + 95551488);
  short* Pb     = (short*)(ws + 129105920);

  prepln_kernel<<<dim3(NROW + 400), 256, 0, stream>>>(
      x, ln_w, ln_b, xn, W_uv, W_out, W_uvT, W_outT);
  guv8_kernel<<<dim3(NROW / 256, 9), 512, 131072, stream>>>(
      xn, W_uvT, b_uv, gamma, beta, ub, vTb, qb, kb);

  const long SQ = (long)LLL * SSS;
  const long SP = (long)LLL * LLL;
  const long SV = (long)EE * LLL;
  const long SU = (long)LLL * EE;

  if (ws_size >= 129105920ull + 134217728ull) {
    gqk4_kernel<<<dim3(16, 16, 4), 512, 131072, stream>>>(qb, kb, Pb);
    gpv8_kernel<<<dim3(16, 4, 4), 512, 131072, stream>>>(Pb, vTb, ub, gb);
  } else if (ws_size >= 129105920ull + 33554432ull) {
    for (int b = 0; b < 4; b++) {
      gqk_kernel<<<dim3(32, 32, 1), 256, 0, stream>>>(qb + (size_t)b * SQ, kb + (size_t)b * SQ, Pb, 0, 0, 0);
      gpv_kernel<<<dim3(32, 8, 1), 256, 0, stream>>>(Pb, vTb + (size_t)b * SV, ub + (size_t)b * SU, gb + (size_t)b * SU, 0, 0, 0);
    }
  } else {
    short* Pc = xn;
    for (int b = 0; b < 4; b++) {
      for (int h = 0; h < 2; h++) {
        size_t rowoff = (size_t)b * LLL + (size_t)h * 2048;
        gqk_kernel<<<dim3(16, 32, 1), 256, 0, stream>>>(qb + rowoff * SSS, kb + (size_t)b * SQ, Pc, 0, 0, 0);
        gpv_kernel<<<dim3(16, 8, 1), 256, 0, stream>>>(Pc, vTb + (size_t)b * SV, ub + rowoff * EE, gb + rowoff * EE, 0, 0, 0);
      }
    }
  }

  gout_kernel<<<dim3(NROW / 128, DIMD / 128), 256, 0, stream>>>(gb, W_outT, b_out, x, out);
}

// Round 15
// 271.964 us; speedup vs baseline: 1.1776x; 1.0052x over previous
//
#include <hip/hip_runtime.h>

typedef __attribute__((ext_vector_type(8))) short short8;
typedef __attribute__((ext_vector_type(4))) float f32x4;

#define DIMD 512
#define EE 1024
#define SSS 128
#define LLL 4096
#define NROW 16384   // B*L
#define NUV 2176     // 2E+S

__device__ __forceinline__ short f2bf(float f) {
  union { float f; unsigned u; } un; un.f = f;
  unsigned r = un.u + 0x7FFFu + ((un.u >> 16) & 1u);
  return (short)(r >> 16);
}
__device__ __forceinline__ float bf2f(short s) {
  union { unsigned u; float f; } un;
  un.u = ((unsigned)(unsigned short)s) << 16;
  return un.f;
}
__device__ __forceinline__ float silu_f(float x) {
  return x / (1.0f + __expf(-x));
}

__device__ __forceinline__ void gld16(const short* g, short* l) {
  __builtin_amdgcn_global_load_lds(
      (const __attribute__((address_space(1))) unsigned int*)g,
      (__attribute__((address_space(3))) unsigned int*)l, 16, 0, 0);
}

#define MFMA16(a, b, c) c = __builtin_amdgcn_mfma_f32_16x16x32_bf16(a, b, c, 0, 0, 0)
#define SBAR() asm volatile("s_barrier" ::: "memory")
#define VMCNT(n) asm volatile("s_waitcnt vmcnt(" #n ")" ::: "memory")

// ---------------- fused prep+layernorm ----------------
__global__ __launch_bounds__(256) void prepln_kernel(
    const float* __restrict__ x, const float* __restrict__ w, const float* __restrict__ bb,
    short* __restrict__ xn,
    const float* __restrict__ W_uv, const float* __restrict__ W_out,
    short* __restrict__ W_uvT, short* __restrict__ W_outT) {
  int tid = threadIdx.x;
  int bx = blockIdx.x;
  if (bx >= NROW) {
    __shared__ float tile[64][65];
    int wb = bx - NROW;
    const float* src; short* dst; int s0, c0, ldS, ldD;
    if (wb < 272) {
      int dt = wb / 34, ct = wb - dt * 34;
      s0 = dt * 64; c0 = ct * 64; ldS = NUV; ldD = DIMD;
      src = W_uv; dst = W_uvT;
    } else {
      int wb2 = wb - 272;
      int et = wb2 >> 3, dt = wb2 & 7;
      s0 = et * 64; c0 = dt * 64; ldS = DIMD; ldD = EE;
      src = W_out; dst = W_outT;
    }
    int r0 = tid >> 6, c = tid & 63;
    #pragma unroll
    for (int rr = 0; rr < 16; ++rr) {
      int row = rr * 4 + r0;
      tile[row][c] = src[(size_t)(s0 + row) * ldS + c0 + c];
    }
    __syncthreads();
    #pragma unroll
    for (int rr = 0; rr < 16; ++rr) {
      int row = rr * 4 + r0;
      dst[(size_t)(c0 + row) * ldD + s0 + c] = f2bf(tile[c][row]);
    }
    return;
  }
  int row = bx;
  const float2* xr = (const float2*)(x + (size_t)row * DIMD);
  float2 v = xr[tid];
  float s = v.x + v.y, ss = v.x * v.x + v.y * v.y;
  #pragma unroll
  for (int off = 32; off >= 1; off >>= 1) {
    s += __shfl_down(s, off);
    ss += __shfl_down(ss, off);
  }
  __shared__ float ps[8];
  if ((tid & 63) == 0) { ps[tid >> 6] = s; ps[4 + (tid >> 6)] = ss; }
  __syncthreads();
  s = ps[0] + ps[1] + ps[2] + ps[3];
  ss = ps[4] + ps[5] + ps[6] + ps[7];
  float mu = s * (1.0f / DIMD);
  float var = ss * (1.0f / DIMD) - mu * mu;
  float inv = rsqrtf(var + 1e-5f);
  float2 wv = ((const float2*)w)[tid];
  float2 bv = ((const float2*)bb)[tid];
  short2 o;
  o.x = f2bf((v.x - mu) * inv * wv.x + bv.x);
  o.y = f2bf((v.y - mu) * inv * wv.y + bv.y);
  *(short2*)&xn[(size_t)row * DIMD + tid * 2] = o;
}

// ---------------- m97-style GEMM core (swizzled): 128x128 tile, 4 waves, BK=32 ----------------
__device__ __forceinline__ void gemm_core(const short* __restrict__ A, const short* __restrict__ B,
                                          int lda, int ldb, int K, size_t m0, size_t n0,
                                          int tid, short* sm, f32x4 acc[4][4]) {
  short* As = sm;
  short* Bs = sm + 4096;
  int wid = tid >> 6, lane = tid & 63;
  int wr = (wid >> 1) * 64, wc = (wid & 1) * 64;
  int lr = lane & 15;
  int lk = ((lane >> 4) ^ (lane & 3)) * 8;
  int r0 = tid >> 2;
  int c0 = (((tid & 3) ^ ((tid >> 2) & 3)) & 3) * 8;
  #pragma unroll
  for (int m = 0; m < 4; m++)
    #pragma unroll
    for (int n = 0; n < 4; n++) acc[m][n] = (f32x4){0.f, 0.f, 0.f, 0.f};
  for (int k0 = 0; k0 < K; k0 += 32) {
    gld16(&A[(m0 + r0) * lda + k0 + c0],      &As[wid * 512]);
    gld16(&A[(m0 + 64 + r0) * lda + k0 + c0], &As[2048 + wid * 512]);
    gld16(&B[(n0 + r0) * ldb + k0 + c0],      &Bs[wid * 512]);
    gld16(&B[(n0 + 64 + r0) * ldb + k0 + c0], &Bs[2048 + wid * 512]);
    __syncthreads();
    short8 af[4], bf[4];
    #pragma unroll
    for (int m = 0; m < 4; m++) af[m] = *(short8*)&As[(wr + m * 16 + lr) * 32 + lk];
    #pragma unroll
    for (int n = 0; n < 4; n++) bf[n] = *(short8*)&Bs[(wc + n * 16 + lr) * 32 + lk];
    #pragma unroll
    for (int m = 0; m < 4; m++)
      #pragma unroll
      for (int n = 0; n < 4; n++)
        MFMA16(af[m], bf[n], acc[m][n]);
    __syncthreads();
  }
}

// ============ 256x256 8-phase pipelined GEMM core — R5 schedule, 3 barriers/tile ============
// q3-end vmcnt+SBAR removed (FIFO audit: q4 has no LDS reads; q1(t+1)'s reads are
// drained by q4-end vmcnt(6); all write-after-read hazards keep >=2 barriers).
template<int LD, int T>
__device__ __forceinline__ void core8(const short* __restrict__ A, const short* __restrict__ Bv,
                                      size_t m0, size_t n0, int tid, short* sm,
                                      f32x4 (&acc)[8][4]) {
  const int w = tid >> 6, l = tid & 63;
  const int lr = l & 15;
  const int colsrc = ((l & 7) * 8) ^ ((l >> 3) << 3);
  const short* srcA = A  + (m0 + w * 8 + (l >> 3)) * (size_t)LD + colsrc;
  const short* srcB = Bv + (n0 + w * 8 + (l >> 3)) * (size_t)LD + colsrc;
  const int csw0 = ((l >> 4) * 8) ^ ((l & 7) << 3);
  const int csw1 = (32 + (l >> 4) * 8) ^ ((l & 7) << 3);
  const int AhalfOff = (w >> 2) * 8192 + lr * 64;
  const int BhalfOff = 16384 + ((w & 3) >> 1) * 8192 + ((w & 1) * 64 + lr) * 64;

  #define STA8(bf_, h_, q_, kt_) gld16(srcA + ((h_) * 128 + (q_) * 64) * (size_t)LD + (kt_) * 64, \
                                       &sm[(bf_) * 32768 + (h_) * 8192 + (q_) * 4096 + w * 512])
  #define STB8(bf_, h_, q_, kt_) gld16(srcB + ((h_) * 128 + (q_) * 64) * (size_t)LD + (kt_) * 64, \
                                       &sm[(bf_) * 32768 + 16384 + (h_) * 8192 + (q_) * 4096 + w * 512])

  #pragma unroll
  for (int m = 0; m < 8; m++)
    #pragma unroll
    for (int n = 0; n < 4; n++) acc[m][n] = (f32x4){0.f, 0.f, 0.f, 0.f};
  short8 Af[4][2], Bf0[2][2], Bf1[2][2];

  STA8(0, 0, 0, 0); STA8(0, 1, 0, 0);
  STB8(0, 0, 0, 0); STB8(0, 1, 0, 0);
  STB8(0, 0, 1, 0); STB8(0, 1, 1, 0);
  STA8(0, 0, 1, 0); STA8(0, 1, 1, 0);
  STA8(1, 0, 0, 1); STA8(1, 1, 0, 1);
  VMCNT(2);
  SBAR();
  __builtin_amdgcn_sched_barrier(0);

  for (int t = 0; t < T; ++t) {
    const int buf = t & 1, nb = buf ^ 1;
    short* Ab = sm + buf * 32768 + AhalfOff;
    short* Bb = sm + buf * 32768 + BhalfOff;
    // q1: (mh0,nh0); stage Bl(t+1)
    if (t + 1 < T) { STB8(nb, 0, 0, t + 1); STB8(nb, 1, 0, t + 1); }
    #pragma unroll
    for (int i = 0; i < 4; ++i) {
      Af[i][0] = *(const short8*)&Ab[i * 1024 + csw0];
      Af[i][1] = *(const short8*)&Ab[i * 1024 + csw1];
    }
    #pragma unroll
    for (int j = 0; j < 2; ++j) {
      Bf0[j][0] = *(const short8*)&Bb[j * 1024 + csw0];
      Bf0[j][1] = *(const short8*)&Bb[j * 1024 + csw1];
    }
    __builtin_amdgcn_s_setprio(1);
    #pragma unroll
    for (int i = 0; i < 4; ++i)
      #pragma unroll
      for (int j = 0; j < 2; ++j) {
        MFMA16(Af[i][0], Bf0[j][0], acc[i][j]);
        MFMA16(Af[i][1], Bf0[j][1], acc[i][j]);
      }
    __builtin_amdgcn_s_setprio(0);
    if (t + 1 < T) { VMCNT(6); } else { VMCNT(2); }
    SBAR();
    // q2: (mh0,nh1); stage Bh(t+1)
    if (t + 1 < T) { STB8(nb, 0, 1, t + 1); STB8(nb, 1, 1, t + 1); }
    #pragma unroll
    for (int j = 0; j < 2; ++j) {
      Bf1[j][0] = *(const short8*)&Bb[2048 + j * 1024 + csw0];
      Bf1[j][1] = *(const short8*)&Bb[2048 + j * 1024 + csw1];
    }
    __builtin_amdgcn_s_setprio(1);
    #pragma unroll
    for (int i = 0; i < 4; ++i)
      #pragma unroll
      for (int j = 0; j < 2; ++j) {
        MFMA16(Af[i][0], Bf1[j][0], acc[i][2 + j]);
        MFMA16(Af[i][1], Bf1[j][1], acc[i][2 + j]);
      }
    __builtin_amdgcn_s_setprio(0);
    if (t + 1 < T) { VMCNT(6); } else { VMCNT(0); }
    SBAR();
    // q3: (mh1,nh1); stage Ah(t+1)  [no phase-end barrier]
    if (t + 1 < T) { STA8(nb, 0, 1, t + 1); STA8(nb, 1, 1, t + 1); }
    #pragma unroll
    for (int i = 0; i < 4; ++i) {
      Af[i][0] = *(const short8*)&Ab[4096 + i * 1024 + csw0];
      Af[i][1] = *(const short8*)&Ab[4096 + i * 1024 + csw1];
    }
    __builtin_amdgcn_s_setprio(1);
    #pragma unroll
    for (int i = 0; i < 4; ++i)
      #pragma unroll
      for (int j = 0; j < 2; ++j) {
        MFMA16(Af[i][0], Bf1[j][0], acc[4 + i][2 + j]);
        MFMA16(Af[i][1], Bf1[j][1], acc[4 + i][2 + j]);
      }
    __builtin_amdgcn_s_setprio(0);
    // q4: (mh1,nh0); stage Al(t+2) into cur buf
    if (t + 2 < T) { STA8(buf, 0, 0, t + 2); STA8(buf, 1, 0, t + 2); }
    __builtin_amdgcn_s_setprio(1);
    #pragma unroll
    for (int i = 0; i < 4; ++i)
      #pragma unroll
      for (int j = 0; j < 2; ++j) {
        MFMA16(Af[i][0], Bf0[j][0], acc[4 + i][j]);
        MFMA16(Af[i][1], Bf0[j][1], acc[4 + i][j]);
      }
    __builtin_amdgcn_s_setprio(0);
    if (t + 2 < T) { VMCNT(6); } else if (t + 1 < T) { VMCNT(4); } else { VMCNT(0); }
    SBAR();
    __builtin_amdgcn_sched_barrier(0);
  }
  #undef STA8
  #undef STB8
}

// ---------------- GEMM1: 8-phase 256x256; y==8 is the q/k strip tile ----------------
__global__ __launch_bounds__(512, 2) void guv8_kernel(
    const short* __restrict__ xn, const short* __restrict__ W_uvT,
    const float* __restrict__ b_uv,
    const float* __restrict__ gamma, const float* __restrict__ beta,
    short* __restrict__ u_out, short* __restrict__ vT_out,
    short* __restrict__ q_out, short* __restrict__ k_out)
{
  extern __shared__ __align__(16) short sm[];
  const size_t m0 = (size_t)blockIdx.x * 256;
  const size_t n0 = (size_t)blockIdx.y * 256;
  const int tid = threadIdx.x, w = tid >> 6, l = tid & 63;
  const int lr = l & 15;
  f32x4 acc[8][4];
  core8<DIMD, DIMD / 64>(xn, W_uvT, m0, n0, tid, sm, acc);
  const int rowb0 = (int)m0 + (w >> 2) * 128 + (l >> 4) * 4;
  const int colb0 = (int)n0 + (w & 3) * 64 + lr;
  if (n0 < 1024) {
    #pragma unroll
    for (int mf = 0; mf < 8; ++mf) {
      #pragma unroll
      for (int nf = 0; nf < 4; ++nf) {
        int col = colb0 + nf * 16;
        float bias = b_uv[col];
        #pragma unroll
        for (int r = 0; r < 4; ++r)
          u_out[(size_t)(rowb0 + mf * 16 + r) * EE + col] = f2bf(silu_f(acc[mf][nf][r] + bias));
      }
    }
  } else if (n0 < 2048) {
    #pragma unroll
    for (int mf = 0; mf < 8; ++mf) {
      int row = rowb0 + mf * 16;
      int bb = row >> 12, lb = row & (LLL - 1);
      #pragma unroll
      for (int nf = 0; nf < 4; ++nf) {
        int e = colb0 + nf * 16 - 1024;
        float bias = b_uv[e + 1024];
        short4 o;
        o.x = f2bf(silu_f(acc[mf][nf][0] + bias));
        o.y = f2bf(silu_f(acc[mf][nf][1] + bias));
        o.z = f2bf(silu_f(acc[mf][nf][2] + bias));
        o.w = f2bf(silu_f(acc[mf][nf][3] + bias));
        *(short4*)&vT_out[((size_t)bb * EE + e) * LLL + lb] = o;
      }
    }
  } else {
    if ((w & 3) < 2) {
      const float scale = 0.08838834764831845f;
      #pragma unroll
      for (int mf = 0; mf < 8; ++mf) {
        int rowb = rowb0 + mf * 16;
        #pragma unroll
        for (int nf = 0; nf < 4; ++nf) {
          int s = (w & 3) * 64 + nf * 16 + lr;
          float bias = b_uv[2048 + s];
          float g0 = gamma[s] * scale, g1 = gamma[SSS + s];
          float be0 = beta[s] * scale, be1 = beta[SSS + s];
          #pragma unroll
          for (int r = 0; r < 4; ++r) {
            float val = acc[mf][nf][r] + bias;
            q_out[(size_t)(rowb + r) * SSS + s] = f2bf(val * g0 + be0);
            k_out[(size_t)(rowb + r) * SSS + s] = f2bf(val * g1 + be1);
          }
        }
      }
    }
  }
}

// ---------------- QK^T 256x256 single-stage: whole K=128 resident in LDS ----------------
__global__ __launch_bounds__(512, 2) void gqk4_kernel(
    const short* __restrict__ q, const short* __restrict__ k, short* __restrict__ P)
{
  extern __shared__ __align__(16) short sm[];
  const int b = blockIdx.z;
  const size_t m0 = (size_t)blockIdx.x * 256;
  const size_t n0 = (size_t)blockIdx.y * 256;
  const short* qz = q + (size_t)b * LLL * SSS;
  const short* kz = k + (size_t)b * LLL * SSS;
  short* Pz = P + (size_t)b * LLL * LLL;
  const int tid = threadIdx.x, w = tid >> 6, l = tid & 63;
  const int lr = l & 15;
  const int srow4 = w * 4 + (l >> 4);
  #pragma unroll
  for (int u = 0; u < 8; ++u) {
    int row = u * 32 + srow4;
    int scol = ((l & 15) * 8) ^ ((row & 7) << 3);
    gld16(qz + (m0 + row) * SSS + scol, &sm[(u * 32 + w * 4) * 128]);
    gld16(kz + (n0 + row) * SSS + scol, &sm[32768 + (u * 32 + w * 4) * 128]);
  }
  f32x4 acc[8][4];
  #pragma unroll
  for (int m = 0; m < 8; m++)
    #pragma unroll
    for (int n = 0; n < 4; n++) acc[m][n] = (f32x4){0.f, 0.f, 0.f, 0.f};
  VMCNT(0);
  __syncthreads();
  const int wr = (w >> 2) * 128, wc = (w & 3) * 64;
  #pragma unroll
  for (int ks = 0; ks < 4; ++ks) {
    const int csw = (ks * 32 + (l >> 4) * 8) ^ ((l & 7) << 3);
    short8 af[8], bf[4];
    #pragma unroll
    for (int m = 0; m < 8; m++) af[m] = *(const short8*)&sm[(wr + m * 16 + lr) * 128 + csw];
    #pragma unroll
    for (int n = 0; n < 4; n++) bf[n] = *(const short8*)&sm[32768 + (wc + n * 16 + lr) * 128 + csw];
    #pragma unroll
    for (int m = 0; m < 8; m++)
      #pragma unroll
      for (int n = 0; n < 4; n++)
        MFMA16(af[m], bf[n], acc[m][n]);
  }
  const int rowb0 = (int)m0 + wr + (l >> 4) * 4;
  const int colb0 = (int)n0 + wc + lr;
  #pragma unroll
  for (int mf = 0; mf < 8; mf++) {
    #pragma unroll
    for (int nf = 0; nf < 4; nf++) {
      int col = colb0 + nf * 16;
      #pragma unroll
      for (int r = 0; r < 4; r++) {
        float v = fmaxf(acc[mf][nf][r], 0.f);
        Pz[(size_t)(rowb0 + mf * 16 + r) * LLL + col] = f2bf(v * v);
      }
    }
  }
}

// ---------------- legacy QK (fallback tiers; q pre-scaled; row-major P) ----------------
__global__ __launch_bounds__(256) void gqk_kernel(
    const short* __restrict__ q, const short* __restrict__ k, short* __restrict__ P,
    long sq, long sk, long sp)
{
  __shared__ __align__(16) short sm[8192];
  int tid = threadIdx.x;
  const short* qz = q + (size_t)blockIdx.z * sq;
  const short* kz = k + (size_t)blockIdx.z * sk;
  short* Pz = P + (size_t)blockIdx.z * sp;
  size_t m0 = (size_t)blockIdx.x * 128, n0 = (size_t)blockIdx.y * 128;
  f32x4 acc[4][4];
  gemm_core(qz, kz, SSS, SSS, SSS, m0, n0, tid, sm, acc);
  int wid = tid >> 6, lane = tid & 63;
  int wr = (wid >> 1) * 64, wc = (wid & 1) * 64;
  int lr = lane & 15;
  #pragma unroll
  for (int m = 0; m < 4; m++) {
    #pragma unroll
    for (int n = 0; n < 4; n++) {
      int col = (int)n0 + wc + n * 16 + lr;
      int rowb = (int)m0 + wr + m * 16 + (lane >> 4) * 4;
      #pragma unroll
      for (int r = 0; r < 4; r++) {
        float v = fmaxf(acc[m][n][r], 0.f);
        Pz[(size_t)(rowb + r) * LLL + col] = f2bf(v * v);
      }
    }
  }
}

// ---------------- legacy PV (fallback tiers): m97 core, row-major P ----------------
__global__ __launch_bounds__(256) void gpv_kernel(
    const short* __restrict__ P, const short* __restrict__ vT,
    const short* __restrict__ u, short* __restrict__ g,
    long sp, long sv, long su)
{
  __shared__ __align__(16) short sm[8192];
  int tid = threadIdx.x;
  const short* Pz = P + (size_t)blockIdx.z * sp;
  const short* vz = vT + (size_t)blockIdx.z * sv;
  const short* uz = u + (size_t)blockIdx.z * su;
  short* gz = g + (size_t)blockIdx.z * su;
  size_t m0 = (size_t)blockIdx.x * 128, n0 = (size_t)blockIdx.y * 128;
  f32x4 acc[4][4];
  gemm_core(Pz, vz, LLL, LLL, LLL, m0, n0, tid, sm, acc);
  int wid = tid >> 6, lane = tid & 63;
  int wr = (wid >> 1) * 64, wc = (wid & 1) * 64;
  int lr = lane & 15;
  #pragma unroll
  for (int m = 0; m < 4; m++) {
    #pragma unroll
    for (int n = 0; n < 4; n++) {
      int col = (int)n0 + wc + n * 16 + lr;
      int rowb = (int)m0 + wr + m * 16 + (lane >> 4) * 4;
      #pragma unroll
      for (int r = 0; r < 4; r++) {
        size_t idx = (size_t)(rowb + r) * EE + col;
        gz[idx] = f2bf(bf2f(uz[idx]) * acc[m][n][r]);
      }
    }
  }
}

// ---------------- PV, 256x256 (core8) ----------------
__global__ __launch_bounds__(512, 2) void gpv8_kernel(
    const short* __restrict__ Pg, const short* __restrict__ vTg,
    const short* __restrict__ ug, short* __restrict__ gg)
{
  extern __shared__ __align__(16) short sm[];
  const int b = blockIdx.z;
  const size_t m0 = (size_t)blockIdx.x * 256;
  const size_t n0 = (size_t)blockIdx.y * 256;
  const short* A  = Pg  + (size_t)b * LLL * LLL;
  const short* Bv = vTg + (size_t)b * EE * LLL;
  const int tid = threadIdx.x, w = tid >> 6, l = tid & 63;
  const int lr = l & 15;
  f32x4 acc[8][4];
  core8<LLL, LLL / 64>(A, Bv, m0, n0, tid, sm, acc);
  const short* ub_ = ug + (size_t)b * LLL * EE;
  short* gb_ = gg + (size_t)b * LLL * EE;
  const int rowb0 = (int)m0 + (w >> 2) * 128 + (l >> 4) * 4;
  const int colb0 = (int)n0 + (w & 3) * 64 + lr;
  #pragma unroll
  for (int mf = 0; mf < 8; ++mf) {
    #pragma unroll
    for (int nf = 0; nf < 4; ++nf) {
      int col = colb0 + nf * 16;
      #pragma unroll
      for (int r = 0; r < 4; ++r) {
        size_t idx = (size_t)(rowb0 + mf * 16 + r) * EE + col;
        gb_[idx] = f2bf(bf2f(ub_[idx]) * acc[mf][nf][r]);
      }
    }
  }
}

// ---------------- GEMM2 v2: 256x128 tile, 3-buf rotation, 1 barrier/K-tile ----------------
// Grid (64,4)=256 blocks = 1/CU. 8 waves 4Mx2N (per-wave 64x64, acc[4][4]).
// LDS 3 x (A 256x64 + B 128x64) = 144KB. Stage tile t+2 into buf (t+2)%3 while
// reading buf t%3 (never aliases); prior reads of that buf are 1 barrier back.
__global__ __launch_bounds__(512, 1) void gout2_kernel(
    const short* __restrict__ A, const short* __restrict__ Bw,
    const float* __restrict__ b_out, const float* __restrict__ x,
    float* __restrict__ out)
{
  extern __shared__ __align__(16) short sm[];
  const size_t m0 = (size_t)blockIdx.x * 256;
  const size_t n0 = (size_t)blockIdx.y * 128;
  const int tid = threadIdx.x, w = tid >> 6, l = tid & 63;
  const int lr = l & 15;
  const int colsrc = ((l & 7) * 8) ^ ((l >> 3) << 3);
  const short* srcA = A  + (m0 + w * 8 + (l >> 3)) * (size_t)EE + colsrc;
  const short* srcB = Bw + (n0 + w * 8 + (l >> 3)) * (size_t)EE + colsrc;
  const int csw0 = ((l >> 4) * 8) ^ ((l & 7) << 3);
  const int csw1 = (32 + (l >> 4) * 8) ^ ((l & 7) << 3);
  const int mq = w >> 1, nh = w & 1;
  const int ARd = (mq * 64 + lr) * 64;
  const int BRd = 16384 + (nh * 64 + lr) * 64;

  #define GSTA(r_, u_, kt_) gld16(srcA + (u_) * 64 * (size_t)EE + (kt_) * 64, \
                                  &sm[(r_) * 24576 + (u_) * 4096 + w * 512])
  #define GSTB(r_, u_, kt_) gld16(srcB + (u_) * 64 * (size_t)EE + (kt_) * 64, \
                                  &sm[(r_) * 24576 + 16384 + (u_) * 4096 + w * 512])

  f32x4 acc[4][4];
  #pragma unroll
  for (int m = 0; m < 4; m++)
    #pragma unroll
    for (int n = 0; n < 4; n++) acc[m][n] = (f32x4){0.f, 0.f, 0.f, 0.f};

  // prologue: tile0 -> buf0, tile1 -> buf1 (6 loads each); keep t1 in flight
  GSTA(0, 0, 0); GSTA(0, 1, 0); GSTA(0, 2, 0); GSTA(0, 3, 0); GSTB(0, 0, 0); GSTB(0, 1, 0);
  GSTA(1, 0, 1); GSTA(1, 1, 1); GSTA(1, 2, 1); GSTA(1, 3, 1); GSTB(1, 0, 1); GSTB(1, 1, 1);
  VMCNT(6);
  SBAR();
  __builtin_amdgcn_sched_barrier(0);

  const int T = EE / 64;   // 16
  for (int t = 0; t < T; ++t) {
    const int r = t % 3, n2 = (t + 2) % 3;
    const short* Ab = sm + r * 24576 + ARd;
    const short* Bb = sm + r * 24576 + BRd;
    short8 af[4], bf[4];
    // phase 1 (ksub0): stage first half of t+2
    if (t + 2 < T) { GSTA(n2, 0, t + 2); GSTA(n2, 1, t + 2); GSTB(n2, 0, t + 2); }
    #pragma unroll
    for (int i = 0; i < 4; ++i) af[i] = *(const short8*)&Ab[i * 1024 + csw0];
    #pragma unroll
    for (int j = 0; j < 4; ++j) bf[j] = *(const short8*)&Bb[j * 1024 + csw0];
    __builtin_amdgcn_s_setprio(1);
    #pragma unroll
    for (int i = 0; i < 4; ++i)
      #pragma unroll
      for (int j = 0; j < 4; ++j)
        MFMA16(af[i], bf[j], acc[i][j]);
    __builtin_amdgcn_s_setprio(0);
    // phase 2 (ksub1): stage second half of t+2
    if (t + 2 < T) { GSTA(n2, 2, t + 2); GSTA(n2, 3, t + 2); GSTB(n2, 1, t + 2); }
    #pragma unroll
    for (int i = 0; i < 4; ++i) af[i] = *(const short8*)&Ab[i * 1024 + csw1];
    #pragma unroll
    for (int j = 0; j < 4; ++j) bf[j] = *(const short8*)&Bb[j * 1024 + csw1];
    __builtin_amdgcn_s_setprio(1);
    #pragma unroll
    for (int i = 0; i < 4; ++i)
      #pragma unroll
      for (int j = 0; j < 4; ++j)
        MFMA16(af[i], bf[j], acc[i][j]);
    __builtin_amdgcn_s_setprio(0);
    if (t + 2 < T) { VMCNT(6); } else if (t + 1 < T) { VMCNT(0); } else { VMCNT(0); }
    SBAR();
    __builtin_amdgcn_sched_barrier(0);
  }
  #undef GSTA
  #undef GSTB

  const int rowb0 = (int)m0 + mq * 64 + (l >> 4) * 4;
  const int colb0 = (int)n0 + nh * 64 + lr;
  #pragma unroll
  for (int i = 0; i < 4; ++i) {
    #pragma unroll
    for (int j = 0; j < 4; ++j) {
      int col = colb0 + j * 16;
      float bias = b_out[col];
      #pragma unroll
      for (int r = 0; r < 4; ++r) {
        size_t idx = (size_t)(rowb0 + i * 16 + r) * DIMD + col;
        out[idx] = acc[i][j][r] + bias + x[idx];
      }
    }
  }
}

extern "C" void kernel_launch(void* const* d_in, const int* in_sizes, int n_in,
                              void* d_out, int out_size, void* d_ws, size_t ws_size,
                              hipStream_t stream) {
  const float* x     = (const float*)d_in[0];
  const float* W_uv  = (const float*)d_in[1];
  const float* b_uv  = (const float*)d_in[2];
  const float* gamma = (const float*)d_in[3];
  const float* beta  = (const float*)d_in[4];
  const float* W_out = (const float*)d_in[5];
  const float* b_out = (const float*)d_in[6];
  const float* ln_w  = (const float*)d_in[7];
  const float* ln_b  = (const float*)d_in[8];
  float* out = (float*)d_out;

  char* ws = (char*)d_ws;
  short* W_uvT  = (short*)(ws);
  short* W_outT = (short*)(ws + 2228224);
  short* xn     = (short*)(ws + 3276800);
  short* qb     = (short*)(ws + 20054016);
  short* kb     = (short*)(ws + 24248320);
  short* ub     = (short*)(ws + 28442624);
  short* vTb    = (short*)(ws + 61997056);
  short* gb     = (short*)(ws + 95551488);
  short* Pb     = (short*)(ws + 129105920);

  prepln_kernel<<<dim3(NROW + 400), 256, 0, stream>>>(
      x, ln_w, ln_b, xn, W_uv, W_out, W_uvT, W_outT);
  guv8_kernel<<<dim3(NROW / 256, 9), 512, 131072, stream>>>(
      xn, W_uvT, b_uv, gamma, beta, ub, vTb, qb, kb);

  const long SQ = (long)LLL * SSS;
  const long SP = (long)LLL * LLL;
  const long SV = (long)EE * LLL;
  const long SU = (long)LLL * EE;

  if (ws_size >= 129105920ull + 134217728ull) {
    gqk4_kernel<<<dim3(16, 16, 4), 512, 131072, stream>>>(qb, kb, Pb);
    gpv8_kernel<<<dim3(16, 4, 4), 512, 131072, stream>>>(Pb, vTb, ub, gb);
  } else if (ws_size >= 129105920ull + 33554432ull) {
    for (int b = 0; b < 4; b++) {
      gqk_kernel<<<dim3(32, 32, 1), 256, 0, stream>>>(qb + (size_t)b * SQ, kb + (size_t)b * SQ, Pb, 0, 0, 0);
      gpv_kernel<<<dim3(32, 8, 1), 256, 0, stream>>>(Pb, vTb + (size_t)b * SV, ub + (size_t)b * SU, gb + (size_t)b * SU, 0, 0, 0);
    }
  } else {
    short* Pc = xn;
    for (int b = 0; b < 4; b++) {
      for (int h = 0; h < 2; h++) {
        size_t rowoff = (size_t)b * LLL + (size_t)h * 2048;
        gqk_kernel<<<dim3(16, 32, 1), 256, 0, stream>>>(qb + rowoff * SSS, kb + (size_t)b * SQ, Pc, 0, 0, 0);
        gpv_kernel<<<dim3(16, 8, 1), 256, 0, stream>>>(Pc, vTb + (size_t)b * SV, ub + rowoff * EE, gb + rowoff * EE, 0, 0, 0);
      }
    }
  }

  gout2_kernel<<<dim3(NROW / 256, DIMD / 128), 512, 147456, stream>>>(gb, W_outT, b_out, x, out);
}